// Round 5
// baseline (3505.275 us; speedup 1.0000x reference)
//
#include <hip/hip_runtime.h>
#include <hip/hip_bf16.h>
#include <math.h>

#define H_ 16
#define HIDDEN_ 1024
#define BATCH_ 4
#define T_ 2048
#define M_ (BATCH_ * T_)   // 8192

typedef __attribute__((ext_vector_type(8))) __bf16 bf16x8;
typedef __attribute__((ext_vector_type(4))) float f32x4;

__device__ __forceinline__ float wave_sum64(float v) {
  #pragma unroll
  for (int m = 32; m >= 1; m >>= 1) v += __shfl_xor(v, m, 64);
  return v;
}
__device__ __forceinline__ float sigmoidf_(float x) { return 1.f / (1.f + expf(-x)); }
__device__ __forceinline__ float siluf_(float x) { return x / (1.f + expf(-x)); }
__device__ __forceinline__ float bf2f(ushort u) {
  unsigned int x = ((unsigned int)u) << 16;
  return __builtin_bit_cast(float, x);
}
__device__ __forceinline__ ushort f2bf(float f) {   // RNE
  unsigned int x = __builtin_bit_cast(unsigned int, f);
  unsigned int r = (x + 0x7fffu + ((x >> 16) & 1u)) >> 16;
  return (ushort)r;
}

// ---------------------------------------------------------------------------
// Split-pack A: f32 [M,K] -> bf16 [M,3K] as [hi | lo | hi].
// ---------------------------------------------------------------------------
__global__ __launch_bounds__(256) void split_pack_A(
    const float* __restrict__ in, int inStride, int K, int M,
    ushort* __restrict__ out) {
  size_t tid = (size_t)blockIdx.x * 256 + threadIdx.x;
  if (tid >= (size_t)M * K) return;
  int k = (int)(tid % K);
  size_t m = tid / K;
  float x = in[m * inStride + k];
  ushort hi = f2bf(x);
  float rem = x - bf2f(hi);
  ushort lo = f2bf(rem);
  size_t o = m * (size_t)(3 * K);
  out[o + k] = hi;
  out[o + K + k] = lo;
  out[o + 2 * K + k] = hi;
}

// ---------------------------------------------------------------------------
// Pack weight W [K,N] f32 -> transposed split bf16 [n][hi|hi|lo].
// ---------------------------------------------------------------------------
__global__ __launch_bounds__(256) void pack_w3t(
    const float* __restrict__ W, int K, int N,
    ushort* __restrict__ out, int rowStride) {
  size_t tid = (size_t)blockIdx.x * 256 + threadIdx.x;
  if (tid >= (size_t)K * N) return;
  int k = (int)(tid % K);
  size_t n = tid / K;
  float x = W[(size_t)k * N + n];
  ushort hi = f2bf(x);
  float rem = x - bf2f(hi);
  ushort lo = f2bf(rem);
  size_t o = n * (size_t)rowStride;
  out[o + k] = hi;
  out[o + K + k] = hi;
  out[o + 2 * K + k] = lo;
}

// ---------------------------------------------------------------------------
// bf16 MFMA GEMM: C[M,N] = A[M,K] @ Bt[N,K]^T (+bias). 128x128 tile, 4 waves.
// ---------------------------------------------------------------------------
template <typename OutT>
__global__ __launch_bounds__(256) void gemm_split(
    const ushort* __restrict__ A, const ushort* __restrict__ Bt,
    const float* __restrict__ bias, OutT* __restrict__ C,
    int M, int N, int K) {
  __shared__ ushort As[128][40];
  __shared__ ushort Bs[128][40];
  const int tid = threadIdx.x;
  const int bm = blockIdx.x * 128, bn = blockIdx.y * 128;
  const int wid = tid >> 6, lane = tid & 63;
  const int wm = (wid >> 1) * 64, wn = (wid & 1) * 64;
  const int fr = lane & 15, fq = lane >> 4;
  const int sm = tid >> 1, skk = (tid & 1) * 16;

  f32x4 acc[4][4] = {};

  for (int k0 = 0; k0 < K; k0 += 32) {
    const ushort* ga = A + (size_t)(bm + sm) * K + k0 + skk;
    const ushort* gb = Bt + (size_t)(bn + sm) * K + k0 + skk;
    uint4 a0 = *(const uint4*)ga;
    uint4 a1 = *(const uint4*)(ga + 8);
    uint4 b0 = *(const uint4*)gb;
    uint4 b1 = *(const uint4*)(gb + 8);
    *(uint4*)&As[sm][skk] = a0;
    *(uint4*)&As[sm][skk + 8] = a1;
    *(uint4*)&Bs[sm][skk] = b0;
    *(uint4*)&Bs[sm][skk + 8] = b1;
    __syncthreads();

    bf16x8 af[4], bfr[4];
    #pragma unroll
    for (int i = 0; i < 4; i++) af[i] = *(const bf16x8*)&As[wm + i * 16 + fr][fq * 8];
    #pragma unroll
    for (int j = 0; j < 4; j++) bfr[j] = *(const bf16x8*)&Bs[wn + j * 16 + fr][fq * 8];
    #pragma unroll
    for (int i = 0; i < 4; i++)
      #pragma unroll
      for (int j = 0; j < 4; j++)
        acc[i][j] = __builtin_amdgcn_mfma_f32_16x16x32_bf16(af[i], bfr[j], acc[i][j], 0, 0, 0);
    __syncthreads();
  }

  #pragma unroll
  for (int i = 0; i < 4; i++) {
    #pragma unroll
    for (int j = 0; j < 4; j++) {
      int col = bn + wn + j * 16 + fr;
      float bv = bias ? bias[col] : 0.f;
      #pragma unroll
      for (int r = 0; r < 4; r++) {
        int row = bm + wm + i * 16 + fq * 4 + r;
        float v = acc[i][j][r] + bv;
        if constexpr (sizeof(OutT) == 2) {
          ((ushort*)C)[(size_t)row * N + col] = f2bf(v);
        } else {
          ((float*)C)[(size_t)row * N + col] = v;
        }
      }
    }
  }
}

// ---------------------------------------------------------------------------
// Frontend: conv(K=4)+SiLU on q,k; L2-normalize (q also *0.125); per-channel
// log-decay g = -A*softplus(graw+dtb). Outputs in [B,H,T,64] layout.
// Grid: M_ blocks x 256 thr; wave handles 4 heads, lane = k.
// ---------------------------------------------------------------------------
__global__ __launch_bounds__(256) void frontend(
    const ushort* __restrict__ qkv, const ushort* __restrict__ grawB,
    const float* __restrict__ qcw, const float* __restrict__ qcb,
    const float* __restrict__ kcw, const float* __restrict__ kcb,
    const float* __restrict__ A_log, const float* __restrict__ dtb,
    float* __restrict__ knG, ushort* __restrict__ qnG, float* __restrict__ gG) {
  const int bt = blockIdx.x;
  const int b = bt >> 11, t = bt & 2047;
  const int w = threadIdx.x >> 6, lane = threadIdx.x & 63;
  #pragma unroll
  for (int hh = 0; hh < 4; hh++) {
    int h = w * 4 + hh;
    int cq = h * 64 + lane;
    float qa = qcb[cq], ka = kcb[cq];
    #pragma unroll
    for (int tap = 0; tap < 4; tap++) {
      int tr = t - 3 + tap;
      if (tr >= 0) {
        size_t r = (size_t)(b * T_ + tr) * 3072;
        qa += bf2f(qkv[r + cq]) * qcw[cq * 4 + tap];
        ka += bf2f(qkv[r + 1024 + cq]) * kcw[cq * 4 + tap];
      }
    }
    qa = siluf_(qa); ka = siluf_(ka);
    float sq = wave_sum64(qa * qa);
    float sk = wave_sum64(ka * ka);
    float qn = qa / (sqrtf(sq) + 1e-6f) * 0.125f;
    float kn = ka / (sqrtf(sk) + 1e-6f);
    float gr = bf2f(grawB[(size_t)(b * T_ + t) * 1024 + cq]) + dtb[cq];
    float sp = (gr > 20.f) ? gr : log1pf(expf(gr));
    float g = -expf(A_log[h]) * sp;
    size_t o = ((size_t)(b * 16 + h) * T_ + t) * 64 + lane;
    knG[o] = kn;
    qnG[o] = f2bf(qn);
    gG[o] = g;
  }
}

// ---------------------------------------------------------------------------
// Chunked gated delta rule. Grid (64 bh, 4 vq), 256 threads, per-block state
// slice S[64k][16v] in LDS, 32 sequential chunks of 64 steps.
// All exponents are <= 0 by construction (incremental PZ panel).
// ---------------------------------------------------------------------------
__global__ __launch_bounds__(256) void chunk_kernel(
    const float* __restrict__ knG, const ushort* __restrict__ qnG,
    float* __restrict__ gO,            // g in / O out, [B,H,T,64] f32
    const ushort* __restrict__ qkv,    // [M,3072] bf16 (v section used)
    const float* __restrict__ f1g1b,   // [M,256] f32 (braw at col 128+h)
    const float* __restrict__ vcw, const float* __restrict__ vcb) {
  const int bh = blockIdx.x, vq = blockIdx.y;
  const int b = bh >> 4, h = bh & 15;
  const int tid = threadIdx.x;
  const int tA = tid & 63, wA = tid >> 6;

  __shared__ float Sb[64][17];
  __shared__ float cC[64][65];
  __shared__ float knL[64][65];
  __shared__ float qnL[64][65];
  __shared__ float scrK[64][65];
  __shared__ float rhsL[64][17];
  __shared__ float UL[64][17];
  __shared__ float PZ[64][17];
  __shared__ float OL[64][17];
  __shared__ float segT[4][65];
  __shared__ float bdeL[16][64];
  __shared__ float KtL[4][65], QtL[4][65];
  __shared__ float accL[4][17];
  __shared__ float pd[16][5];
  __shared__ float TinvL[16];
  __shared__ float bqL[16];
  __shared__ float betaL[64];

  #pragma unroll
  for (int j = 0; j < 4; j++) Sb[tA][wA * 4 + j] = 0.f;

  const size_t slab = (size_t)bh * (size_t)(T_ * 64);
  const int chv = h * 64 + vq * 16;

  for (int ch = 0; ch < 32; ch++) {
    const int t0 = ch * 64;
    // ---- L1: loads ----
    {
      const size_t off = slab + (size_t)t0 * 64;
      #pragma unroll
      for (int i = 0; i < 16; i++) {
        int idx = tid + i * 256;
        int t = idx >> 6, k = idx & 63;
        cC[t][k] = gO[off + idx];
        knL[t][k] = knG[off + idx];
        qnL[t][k] = bf2f(qnG[off + idx]);
      }
      #pragma unroll
      for (int j = 0; j < 4; j++) {
        int vi = wA * 4 + j;
        int cv = chv + vi;
        float acc = vcb[cv];
        #pragma unroll
        for (int tap = 0; tap < 4; tap++) {
          int tr = t0 + tA - 3 + tap;
          float xv = 0.f;
          if (tr >= 0) xv = bf2f(qkv[(size_t)(b * T_ + tr) * 3072 + 2048 + cv]);
          acc += xv * vcw[cv * 4 + tap];
        }
        rhsL[tA][vi] = siluf_(acc);   // holds vconv until L5
      }
      if (tid < 64)
        betaL[tid] = sigmoidf_(f1g1b[(size_t)(b * T_ + t0 + tid) * 256 + 128 + h]);
    }
    __syncthreads();
    // ---- L2: per-16 cumsum partials (inclusive) ----
    {
      int k = tA, q = wA;
      float run = 0.f;
      #pragma unroll
      for (int i = 0; i < 16; i++) {
        run += cC[q * 16 + i][k];
        cC[q * 16 + i][k] = run;
      }
      segT[q][k] = run;
    }
    __syncthreads();
    // ---- L3: apply segment offsets ----
    {
      int k = tA, q = wA;
      if (q > 0) {
        float off = segT[0][k];
        if (q > 1) off += segT[1][k];
        if (q > 2) off += segT[2][k];
        #pragma unroll
        for (int i = 0; i < 16; i++) cC[q * 16 + i][k] += off;
      }
    }
    __syncthreads();
    // ---- L4: block decays + scrK = W = kn*e^c ----
    {
      #pragma unroll
      for (int i = 0; i < 4; i++) {
        int idx = tid + i * 256;
        int P = idx >> 6, k = idx & 63;
        float lo = P ? cC[4 * P - 1][k] : 0.f;
        bdeL[P][k] = expf(cC[4 * P + 3][k] - lo);
      }
      #pragma unroll
      for (int i = 0; i < 16; i++) {
        int idx = tid + i * 256;
        int t = idx >> 6, k = idx & 63;
        scrK[t][k] = knL[t][k] * expf(cC[t][k]);
      }
    }
    __syncthreads();
    // ---- L5: rhs = beta*(vconv - W@S); zero PZ/OL ----
    {
      float a0 = 0.f, a1 = 0.f, a2 = 0.f, a3 = 0.f;
      for (int k = 0; k < 64; k++) {
        float wv = scrK[tA][k];
        a0 += wv * Sb[k][wA * 4 + 0];
        a1 += wv * Sb[k][wA * 4 + 1];
        a2 += wv * Sb[k][wA * 4 + 2];
        a3 += wv * Sb[k][wA * 4 + 3];
      }
      float bt = betaL[tA];
      rhsL[tA][wA * 4 + 0] = bt * (rhsL[tA][wA * 4 + 0] - a0);
      rhsL[tA][wA * 4 + 1] = bt * (rhsL[tA][wA * 4 + 1] - a1);
      rhsL[tA][wA * 4 + 2] = bt * (rhsL[tA][wA * 4 + 2] - a2);
      rhsL[tA][wA * 4 + 3] = bt * (rhsL[tA][wA * 4 + 3] - a3);
      #pragma unroll
      for (int j = 0; j < 4; j++) { PZ[tA][wA * 4 + j] = 0.f; OL[tA][wA * 4 + j] = 0.f; }
    }
    __syncthreads();
    // ---- P loop: 16 x 4-wide blocks ----
    for (int P = 0; P < 16; P++) {
      // phase a
      if (P > 0) {
        int k = tA;
        float z0 = knL[4 * P - 4][k] * expf(cC[4 * P - 1][k] - cC[4 * P - 4][k]);
        float z1 = knL[4 * P - 3][k] * expf(cC[4 * P - 1][k] - cC[4 * P - 3][k]);
        float z2 = knL[4 * P - 2][k] * expf(cC[4 * P - 1][k] - cC[4 * P - 2][k]);
        float z3 = knL[4 * P - 1][k];
        float bd = bdeL[P - 1][k];
        #pragma unroll
        for (int j = 0; j < 4; j++) {
          int vi = wA * 4 + j;
          float p = PZ[k][vi] * bd;
          p += z0 * UL[4 * P - 4][vi];
          p += z1 * UL[4 * P - 3][vi];
          p += z2 * UL[4 * P - 2][vi];
          p += z3 * UL[4 * P - 1][vi];
          PZ[k][vi] = p;
        }
      }
      {
        int th = wA, k = tA;
        float base = P ? cC[4 * P - 1][k] : 0.f;
        float el = expf(cC[4 * P + th][k] - base);
        KtL[th][k] = knL[4 * P + th][k] * el;
        QtL[th][k] = qnL[4 * P + th][k] * el;
      }
      if (tid < 64) {
        int pr = tid >> 2, kq = tid & 3;
        int pt = (int)((0xFFA94FE9u >> (2 * pr)) & 3u);
        int ps = (int)((0xE4910910u >> (2 * pr)) & 3u);
        bool isA = pr < 6;
        int tg = 4 * P + pt, sg = 4 * P + ps;
        float acc = 0.f;
        for (int kk = kq * 16; kk < kq * 16 + 16; kk++) {
          float e = expf(cC[tg][kk] - cC[sg][kk]);
          float xt = isA ? knL[tg][kk] : qnL[tg][kk];
          acc += xt * knL[sg][kk] * e;
        }
        pd[pr][kq] = acc;
      }
      __syncthreads();
      // phase b
      if (wA == 0) {
        int th = (tid >> 4) & 3, vi = tid & 15;
        float a = 0.f;
        for (int k = 0; k < 64; k++) a += KtL[th][k] * PZ[k][vi];
        accL[th][vi] = betaL[4 * P + th] * a;
      } else if (wA == 1) {
        int th = (tid >> 4) & 3, vi = tid & 15;
        float a = 0.f;
        for (int k = 0; k < 64; k++) a += QtL[th][k] * PZ[k][vi];
        OL[4 * P + th][vi] += a;
      } else if (tid == 128) {
        float m10 = betaL[4 * P + 1] * (pd[0][0] + pd[0][1] + pd[0][2] + pd[0][3]);
        float m20 = betaL[4 * P + 2] * (pd[1][0] + pd[1][1] + pd[1][2] + pd[1][3]);
        float m21 = betaL[4 * P + 2] * (pd[2][0] + pd[2][1] + pd[2][2] + pd[2][3]);
        float m30 = betaL[4 * P + 3] * (pd[3][0] + pd[3][1] + pd[3][2] + pd[3][3]);
        float m31 = betaL[4 * P + 3] * (pd[4][0] + pd[4][1] + pd[4][2] + pd[4][3]);
        float m32 = betaL[4 * P + 3] * (pd[5][0] + pd[5][1] + pd[5][2] + pd[5][3]);
        TinvL[0] = 1.f; TinvL[5] = 1.f; TinvL[10] = 1.f; TinvL[15] = 1.f;
        TinvL[4] = -m10;
        TinvL[8] = -m20 + m21 * m10;
        TinvL[9] = -m21;
        TinvL[12] = -m30 + m31 * m10 + m32 * m20 - m32 * m21 * m10;
        TinvL[13] = -m31 + m32 * m21;
        TinvL[14] = -m32;
      } else if (tid == 192) {
        #pragma unroll
        for (int pr = 6; pr < 16; pr++) {
          int pt = (int)((0xFFA94FE9u >> (2 * pr)) & 3u);
          int ps = (int)((0xE4910910u >> (2 * pr)) & 3u);
          bqL[pt * 4 + ps] = pd[pr][0] + pd[pr][1] + pd[pr][2] + pd[pr][3];
        }
      }
      __syncthreads();
      // phase d: solve u block + in-block O
      if (tid < 64) {
        int th = tid >> 4, vi = tid & 15;
        float rp0 = rhsL[4 * P + 0][vi] - accL[0][vi];
        float rp1 = (th >= 1) ? (rhsL[4 * P + 1][vi] - accL[1][vi]) : 0.f;
        float rp2 = (th >= 2) ? (rhsL[4 * P + 2][vi] - accL[2][vi]) : 0.f;
        float rp3 = (th >= 3) ? (rhsL[4 * P + 3][vi] - accL[3][vi]) : 0.f;
        float u0 = rp0;
        float u1 = TinvL[4] * rp0 + rp1;
        float u2 = TinvL[8] * rp0 + TinvL[9] * rp1 + rp2;
        float u3 = TinvL[12] * rp0 + TinvL[13] * rp1 + TinvL[14] * rp2 + rp3;
        float uth = (th == 0) ? u0 : (th == 1) ? u1 : (th == 2) ? u2 : u3;
        UL[4 * P + th][vi] = uth;
        float os = bqL[th * 4 + 0] * u0;
        if (th >= 1) os += bqL[th * 4 + 1] * u1;
        if (th >= 2) os += bqL[th * 4 + 2] * u2;
        if (th >= 3) os += bqL[th * 4 + 3] * u3;
        OL[4 * P + th][vi] += os;
      }
      __syncthreads();
    }
    // ---- O final: O = OL + (qn*e^c) @ S ----
    #pragma unroll
    for (int i = 0; i < 16; i++) {
      int idx = tid + i * 256;
      int t = idx >> 6, k = idx & 63;
      scrK[t][k] = qnL[t][k] * expf(cC[t][k]);
    }
    __syncthreads();
    {
      float a0 = OL[tA][wA * 4 + 0], a1 = OL[tA][wA * 4 + 1];
      float a2 = OL[tA][wA * 4 + 2], a3 = OL[tA][wA * 4 + 3];
      for (int k = 0; k < 64; k++) {
        float qv = scrK[tA][k];
        a0 += qv * Sb[k][wA * 4 + 0];
        a1 += qv * Sb[k][wA * 4 + 1];
        a2 += qv * Sb[k][wA * 4 + 2];
        a3 += qv * Sb[k][wA * 4 + 3];
      }
      size_t ob = slab + (size_t)(t0 + tA) * 64 + vq * 16 + wA * 4;
      gO[ob + 0] = a0; gO[ob + 1] = a1; gO[ob + 2] = a2; gO[ob + 3] = a3;
    }
    __syncthreads();
    // ---- S update: S = e^{c63}*S + K2^T @ U ----
    #pragma unroll
    for (int i = 0; i < 16; i++) {
      int idx = tid + i * 256;
      int s = idx >> 6, k = idx & 63;
      scrK[s][k] = knL[s][k] * expf(cC[63][k] - cC[s][k]);
    }
    __syncthreads();
    {
      int k = tA;
      float ge = expf(cC[63][k]);
      float s0 = ge * Sb[k][wA * 4 + 0], s1 = ge * Sb[k][wA * 4 + 1];
      float s2 = ge * Sb[k][wA * 4 + 2], s3 = ge * Sb[k][wA * 4 + 3];
      for (int ss = 0; ss < 64; ss++) {
        float kv = scrK[ss][k];
        s0 += kv * UL[ss][wA * 4 + 0];
        s1 += kv * UL[ss][wA * 4 + 1];
        s2 += kv * UL[ss][wA * 4 + 2];
        s3 += kv * UL[ss][wA * 4 + 3];
      }
      Sb[k][wA * 4 + 0] = s0; Sb[k][wA * 4 + 1] = s1;
      Sb[k][wA * 4 + 2] = s2; Sb[k][wA * 4 + 3] = s3;
    }
    __syncthreads();
  }
}

// ---------------------------------------------------------------------------
// RMS-norm + gate + split-pack into [hi|lo|hi] bf16 GEMM operand.
// o layout [B,H,T,64]; out3 [M,3072].
// ---------------------------------------------------------------------------
__global__ __launch_bounds__(256) void onorm_pack(
    const float* __restrict__ o, const float* __restrict__ gate,
    const float* __restrict__ onw, ushort* __restrict__ out3) {
  int gi = blockIdx.x * 4 + (threadIdx.x >> 6);
  int lane = threadIdx.x & 63;
  int b = gi >> 15, h = (gi >> 11) & 15, t = gi & 2047;
  float ov = o[(size_t)gi * 64 + lane];
  float ms = wave_sum64(ov * ov) * (1.f / 64.f);
  float r = rsqrtf(ms + 1e-5f);
  float gv = gate[(size_t)(b * T_ + t) * 1024 + h * 64 + lane];
  float val = ov * r * onw[lane] * sigmoidf_(gv);
  ushort hi = f2bf(val);
  float rem = val - bf2f(hi);
  ushort lo = f2bf(rem);
  size_t m = (size_t)(b * T_ + t);
  int c = h * 64 + lane;
  out3[m * 3072 + c] = hi;
  out3[m * 3072 + 1024 + c] = lo;
  out3[m * 3072 + 2048 + c] = hi;
}

extern "C" void kernel_launch(void* const* d_in, const int* in_sizes, int n_in,
                              void* d_out, int out_size, void* d_ws, size_t ws_size,
                              hipStream_t stream) {
  const float* hs    = (const float*)d_in[0];
  const float* Wq    = (const float*)d_in[1];
  const float* Wk    = (const float*)d_in[2];
  const float* Wv    = (const float*)d_in[3];
  const float* qcw   = (const float*)d_in[4];
  const float* qcb   = (const float*)d_in[5];
  const float* kcw   = (const float*)d_in[6];
  const float* kcb   = (const float*)d_in[7];
  const float* vcw   = (const float*)d_in[8];
  const float* vcb   = (const float*)d_in[9];
  const float* Wf1   = (const float*)d_in[10];
  const float* Wf2   = (const float*)d_in[11];
  const float* Wb    = (const float*)d_in[12];
  const float* A_log = (const float*)d_in[13];
  const float* dtb   = (const float*)d_in[14];
  const float* Wg1   = (const float*)d_in[15];
  const float* Wg2   = (const float*)d_in[16];
  const float* bg2   = (const float*)d_in[17];
  const float* onw   = (const float*)d_in[18];
  const float* Wo    = (const float*)d_in[19];
  float* out = (float*)d_out;

  char* ws = (char*)d_ws;
  ushort* hs3    = (ushort*)(ws);                 // [8192,3072] bf16, 48MiB
  float*  knG    = (float*)(ws);                  // [B,H,T,64] f32, 32MiB (after hs3 dead)
  ushort* qnG    = (ushort*)(ws + 33554432);      // [B,H,T,64] bf16, 16MiB
  ushort* obuf3  = hs3;                           // [8192,3072] bf16 (after kn/qn dead)
  ushort* qkvhat = (ushort*)(ws + 50331648);      // [8192,3072] bf16, 48MiB
  float*  gate   = (float*)qkvhat;                // [8192,1024] f32 (after chunk)
  ushort* grawB  = (ushort*)(ws + 100663296);     // [8192,1024] bf16, 16MiB
  float*  gObuf  = (float*)(ws + 117440512);      // [B,H,T,64] f32, 32MiB: g then O
  char*   R4     = ws + 150994944;                // 18MiB pool
  ushort* Wqkv3  = (ushort*)R4;                   // [3072,3072] bf16
  ushort* Wfgb3  = (ushort*)R4;                   // [256,3072] bf16
  float*  f1g1b  = (float*)(R4 + 1572864);        // [8192,256] f32
  ushort* f1_3   = (ushort*)(R4 + 9961472);
  ushort* g1_3   = (ushort*)(R4 + 13107200);
  ushort* Wf2_3  = (ushort*)(R4 + 16252928);
  ushort* Wg2_3  = (ushort*)(R4 + 16646144);
  ushort* Wo3    = (ushort*)R4;                   // [1024,3072] bf16 (after gate GEMM)

  dim3 blk(256);
  const int PK = 1024 * 1024;

  // 1-4: projection GEMMs (bf16 3-term split MFMA)
  split_pack_A<<<dim3((M_ * 1024) / 256), blk, 0, stream>>>(hs, 1024, 1024, M_, hs3);
  pack_w3t<<<dim3(PK / 256), blk, 0, stream>>>(Wq, 1024, 1024, Wqkv3, 3072);
  pack_w3t<<<dim3(PK / 256), blk, 0, stream>>>(Wk, 1024, 1024, Wqkv3 + (size_t)1024 * 3072, 3072);
  pack_w3t<<<dim3(PK / 256), blk, 0, stream>>>(Wv, 1024, 1024, Wqkv3 + (size_t)2048 * 3072, 3072);
  gemm_split<ushort><<<dim3(M_ / 128, 3072 / 128), blk, 0, stream>>>(
      hs3, Wqkv3, nullptr, qkvhat, M_, 3072, 3072);
  hipMemsetAsync(Wfgb3, 0, (size_t)256 * 3072 * 2, stream);
  pack_w3t<<<dim3((1024 * 64) / 256), blk, 0, stream>>>(Wf1, 1024, 64, Wfgb3, 3072);
  pack_w3t<<<dim3((1024 * 64) / 256), blk, 0, stream>>>(Wg1, 1024, 64, Wfgb3 + (size_t)64 * 3072, 3072);
  pack_w3t<<<dim3((1024 * 16) / 256), blk, 0, stream>>>(Wb, 1024, 16, Wfgb3 + (size_t)128 * 3072, 3072);
  gemm_split<float><<<dim3(M_ / 128, 2), blk, 0, stream>>>(
      hs3, Wfgb3, nullptr, f1g1b, M_, 256, 3072);
  split_pack_A<<<dim3((M_ * 64) / 256), blk, 0, stream>>>(f1g1b, 256, 64, M_, f1_3);
  split_pack_A<<<dim3((M_ * 64) / 256), blk, 0, stream>>>(f1g1b + 64, 256, 64, M_, g1_3);
  pack_w3t<<<dim3((64 * 1024) / 256), blk, 0, stream>>>(Wf2, 64, 1024, Wf2_3, 192);
  gemm_split<ushort><<<dim3(M_ / 128, 1024 / 128), blk, 0, stream>>>(
      f1_3, Wf2_3, nullptr, grawB, M_, 1024, 192);

  // 5: frontend (writes knG/qnG over hs3, g into gObuf)
  frontend<<<dim3(M_), blk, 0, stream>>>(qkvhat, grawB, qcw, qcb, kcw, kcb,
                                         A_log, dtb, knG, qnG, gObuf);
  // 6: chunked delta-rule recurrence (O overwrites g in gObuf)
  chunk_kernel<<<dim3(64, 4), blk, 0, stream>>>(knG, qnG, gObuf, qkvhat, f1g1b, vcw, vcb);
  // 7: gate GEMM (into qkvhat region, dead after chunk)
  pack_w3t<<<dim3((64 * 1024) / 256), blk, 0, stream>>>(Wg2, 64, 1024, Wg2_3, 192);
  gemm_split<float><<<dim3(M_ / 128, 1024 / 128), blk, 0, stream>>>(
      g1_3, Wg2_3, bg2, gate, M_, 1024, 192);
  // 8: RMS-norm + gate + pack (into hs3 region, kn/qn dead)
  onorm_pack<<<dim3((M_ * H_) / 4), blk, 0, stream>>>(gObuf, gate, onw, obuf3);
  // 9: final projection
  pack_w3t<<<dim3(PK / 256), blk, 0, stream>>>(Wo, 1024, 1024, Wo3, 3072);
  gemm_split<float><<<dim3(M_ / 128, 1024 / 128), blk, 0, stream>>>(
      obuf3, Wo3, nullptr, out, M_, 1024, 3072);
}

// Round 6
// 1601.899 us; speedup vs baseline: 2.1882x; 2.1882x over previous
//
#include <hip/hip_runtime.h>
#include <hip/hip_bf16.h>
#include <math.h>

#define H_ 16
#define HIDDEN_ 1024
#define BATCH_ 4
#define T_ 2048
#define M_ (BATCH_ * T_)   // 8192

typedef __attribute__((ext_vector_type(8))) __bf16 bf16x8;
typedef __attribute__((ext_vector_type(4))) float f32x4;

__device__ __forceinline__ float wave_sum64(float v) {
  #pragma unroll
  for (int m = 32; m >= 1; m >>= 1) v += __shfl_xor(v, m, 64);
  return v;
}
__device__ __forceinline__ float sigmoidf_(float x) { return 1.f / (1.f + expf(-x)); }
__device__ __forceinline__ float siluf_(float x) { return x / (1.f + expf(-x)); }
__device__ __forceinline__ float bf2f(ushort u) {
  unsigned int x = ((unsigned int)u) << 16;
  return __builtin_bit_cast(float, x);
}
__device__ __forceinline__ ushort f2bf(float f) {   // RNE
  unsigned int x = __builtin_bit_cast(unsigned int, f);
  unsigned int r = (x + 0x7fffu + ((x >> 16) & 1u)) >> 16;
  return (ushort)r;
}

// ---------------------------------------------------------------------------
// Split-pack A: f32 [M,K] -> bf16 [M,3K] as [hi | lo | hi].
// ---------------------------------------------------------------------------
__global__ __launch_bounds__(256) void split_pack_A(
    const float* __restrict__ in, int inStride, int K, int M,
    ushort* __restrict__ out) {
  size_t tid = (size_t)blockIdx.x * 256 + threadIdx.x;
  if (tid >= (size_t)M * K) return;
  int k = (int)(tid % K);
  size_t m = tid / K;
  float x = in[m * inStride + k];
  ushort hi = f2bf(x);
  float rem = x - bf2f(hi);
  ushort lo = f2bf(rem);
  size_t o = m * (size_t)(3 * K);
  out[o + k] = hi;
  out[o + K + k] = lo;
  out[o + 2 * K + k] = hi;
}

// ---------------------------------------------------------------------------
// Pack weight W [K,N] f32 -> transposed split bf16 [n][hi|hi|lo].
// ---------------------------------------------------------------------------
__global__ __launch_bounds__(256) void pack_w3t(
    const float* __restrict__ W, int K, int N,
    ushort* __restrict__ out, int rowStride) {
  size_t tid = (size_t)blockIdx.x * 256 + threadIdx.x;
  if (tid >= (size_t)K * N) return;
  int k = (int)(tid % K);
  size_t n = tid / K;
  float x = W[(size_t)k * N + n];
  ushort hi = f2bf(x);
  float rem = x - bf2f(hi);
  ushort lo = f2bf(rem);
  size_t o = n * (size_t)rowStride;
  out[o + k] = hi;
  out[o + K + k] = hi;
  out[o + 2 * K + k] = lo;
}

// ---------------------------------------------------------------------------
// bf16 MFMA GEMM: C[M,N] = A[M,K] @ Bt[N,K]^T (+bias). 128x128 tile, 4 waves.
// ---------------------------------------------------------------------------
template <typename OutT>
__global__ __launch_bounds__(256) void gemm_split(
    const ushort* __restrict__ A, const ushort* __restrict__ Bt,
    const float* __restrict__ bias, OutT* __restrict__ C,
    int M, int N, int K) {
  __shared__ ushort As[128][40];
  __shared__ ushort Bs[128][40];
  const int tid = threadIdx.x;
  const int bm = blockIdx.x * 128, bn = blockIdx.y * 128;
  const int wid = tid >> 6, lane = tid & 63;
  const int wm = (wid >> 1) * 64, wn = (wid & 1) * 64;
  const int fr = lane & 15, fq = lane >> 4;
  const int sm = tid >> 1, skk = (tid & 1) * 16;

  f32x4 acc[4][4] = {};

  for (int k0 = 0; k0 < K; k0 += 32) {
    const ushort* ga = A + (size_t)(bm + sm) * K + k0 + skk;
    const ushort* gb = Bt + (size_t)(bn + sm) * K + k0 + skk;
    uint4 a0 = *(const uint4*)ga;
    uint4 a1 = *(const uint4*)(ga + 8);
    uint4 b0 = *(const uint4*)gb;
    uint4 b1 = *(const uint4*)(gb + 8);
    *(uint4*)&As[sm][skk] = a0;
    *(uint4*)&As[sm][skk + 8] = a1;
    *(uint4*)&Bs[sm][skk] = b0;
    *(uint4*)&Bs[sm][skk + 8] = b1;
    __syncthreads();

    bf16x8 af[4], bfr[4];
    #pragma unroll
    for (int i = 0; i < 4; i++) af[i] = *(const bf16x8*)&As[wm + i * 16 + fr][fq * 8];
    #pragma unroll
    for (int j = 0; j < 4; j++) bfr[j] = *(const bf16x8*)&Bs[wn + j * 16 + fr][fq * 8];
    #pragma unroll
    for (int i = 0; i < 4; i++)
      #pragma unroll
      for (int j = 0; j < 4; j++)
        acc[i][j] = __builtin_amdgcn_mfma_f32_16x16x32_bf16(af[i], bfr[j], acc[i][j], 0, 0, 0);
    __syncthreads();
  }

  #pragma unroll
  for (int i = 0; i < 4; i++) {
    #pragma unroll
    for (int j = 0; j < 4; j++) {
      int col = bn + wn + j * 16 + fr;
      float bv = bias ? bias[col] : 0.f;
      #pragma unroll
      for (int r = 0; r < 4; r++) {
        int row = bm + wm + i * 16 + fq * 4 + r;
        float v = acc[i][j][r] + bv;
        if constexpr (sizeof(OutT) == 2) {
          ((ushort*)C)[(size_t)row * N + col] = f2bf(v);
        } else {
          ((float*)C)[(size_t)row * N + col] = v;
        }
      }
    }
  }
}

// ---------------------------------------------------------------------------
// Frontend: conv(K=4)+SiLU on q,k; L2-normalize (q also *0.125); per-channel
// log-decay g = -A*softplus(graw+dtb). Outputs in [B,H,T,64] layout.
// ---------------------------------------------------------------------------
__global__ __launch_bounds__(256) void frontend(
    const ushort* __restrict__ qkv, const ushort* __restrict__ grawB,
    const float* __restrict__ qcw, const float* __restrict__ qcb,
    const float* __restrict__ kcw, const float* __restrict__ kcb,
    const float* __restrict__ A_log, const float* __restrict__ dtb,
    float* __restrict__ knG, ushort* __restrict__ qnG, float* __restrict__ gG) {
  const int bt = blockIdx.x;
  const int b = bt >> 11, t = bt & 2047;
  const int w = threadIdx.x >> 6, lane = threadIdx.x & 63;
  #pragma unroll
  for (int hh = 0; hh < 4; hh++) {
    int h = w * 4 + hh;
    int cq = h * 64 + lane;
    float qa = qcb[cq], ka = kcb[cq];
    #pragma unroll
    for (int tap = 0; tap < 4; tap++) {
      int tr = t - 3 + tap;
      if (tr >= 0) {
        size_t r = (size_t)(b * T_ + tr) * 3072;
        qa += bf2f(qkv[r + cq]) * qcw[cq * 4 + tap];
        ka += bf2f(qkv[r + 1024 + cq]) * kcw[cq * 4 + tap];
      }
    }
    qa = siluf_(qa); ka = siluf_(ka);
    float sq = wave_sum64(qa * qa);
    float sk = wave_sum64(ka * ka);
    float qn = qa / (sqrtf(sq) + 1e-6f) * 0.125f;
    float kn = ka / (sqrtf(sk) + 1e-6f);
    float gr = bf2f(grawB[(size_t)(b * T_ + t) * 1024 + cq]) + dtb[cq];
    float sp = (gr > 20.f) ? gr : log1pf(expf(gr));
    float g = -expf(A_log[h]) * sp;
    size_t o = ((size_t)(b * 16 + h) * T_ + t) * 64 + lane;
    knG[o] = kn;
    qnG[o] = f2bf(qn);
    gG[o] = g;
  }
}

// ---------------------------------------------------------------------------
// Chunked gated delta rule v2 — parallel-M formulation.
// Grid (64 bh, 4 vq), 256 threads. Per chunk (64 steps):
//   cumsum c; block bases d_P; ratios R[P,J]=e^{d_P-d_J}<=1 (all 136 pairs);
//   K~[t]=kn e^{c-d}, K^[t]=kn e^{d-c}, Q~[t]=qn e^{c-d};
//   M[t][s] = sum_k X~[t] R[blk(t),blk(s)] K^[s]  (one dense parallel phase,
//   all exponents overflow-safe by construction);
//   solve (I+beta*tril(Mkk))u = rhs via 16x {rank-4 ACC update; 4x4 Tinv} —
//   2 tiny barriers per block, no single-thread serial sections;
//   O = tril(Mqk)@U + (Q~ e^c)@S;  S = e^{c63} S + K2^T U.
// O written to a SEPARATE bf16 buffer (fixes g-read/O-write cross-block race).
// ---------------------------------------------------------------------------
__global__ __launch_bounds__(256, 1) void chunk2(
    const float* __restrict__ knG, const ushort* __restrict__ qnG,
    const float* __restrict__ gG, ushort* __restrict__ oBH,
    const ushort* __restrict__ qkv, const float* __restrict__ f1g1b,
    const float* __restrict__ vcw, const float* __restrict__ vcb) {
  const int bh = blockIdx.x, vq = blockIdx.y;
  const int b = bh >> 4, h = bh & 15;
  const int tid = threadIdx.x;
  const int wA = tid >> 6, tA = tid & 63;

  __shared__ __align__(16) float Kt[64][68];    // kn, then K~ = kn*e^{c-d}
  __shared__ __align__(16) float Kh[64][68];    // K^ = kn*e^{d-c}
  __shared__ __align__(16) float Qt[64][68];    // qn, then Q~ = qn*e^{c-d}
  __shared__ __align__(16) float cM[64][68];    // g -> cumsum c; later MqkT[s][t]
  __shared__ __align__(16) float MkkT[64][68];  // MkkT[s][t]
  __shared__ __align__(16) float Rt[136][66];   // R[f][k], f = P(P+1)/2+J
  __shared__ __align__(16) float Sb[64][20];
  __shared__ __align__(16) float Ub[64][20];
  __shared__ __align__(16) float rhsL[64][20];
  __shared__ __align__(16) float AccL[64][20];
  __shared__ __align__(16) float dlog[17][68];  // rows 0-3 reused as cumsum segT
  __shared__ __align__(16) float Eab[17][68];   // e^{dlog}
  __shared__ float betaL[64];

  const size_t slab = (size_t)bh * (size_t)(T_ * 64);
  const int tTh = tid >> 2;          // 0..63 (row index for most phases)
  const int c4 = tid & 3;
  const int lvi = c4 * 4;            // local vi within 16-slice
  const int kb = c4 * 16;            // k-chunk base for load phases

  // zero state
  #pragma unroll
  for (int j = 0; j < 4; j++) Sb[tTh][lvi + j] = 0.f;
  __syncthreads();

  for (int ch = 0; ch < 32; ch++) {
    const int t0 = ch * 64;

    // ---- PH1: loads: kn->Kt, qn->Qt, g->cM (contiguous 16/thread), beta ----
    {
      const size_t base = slab + (size_t)t0 * 64 + (size_t)tid * 16;
      #pragma unroll
      for (int i2 = 0; i2 < 4; i2++) {
        *(float4*)&Kt[tTh][kb + i2 * 4] = *(const float4*)&knG[base + i2 * 4];
        *(float4*)&cM[tTh][kb + i2 * 4] = *(const float4*)&gG[base + i2 * 4];
      }
      uint4 ua = *(const uint4*)&qnG[base];
      uint4 ub = *(const uint4*)&qnG[base + 8];
      *(float4*)&Qt[tTh][kb + 0] = make_float4(
          bf2f((ushort)ua.x), bf2f((ushort)(ua.x >> 16)),
          bf2f((ushort)ua.y), bf2f((ushort)(ua.y >> 16)));
      *(float4*)&Qt[tTh][kb + 4] = make_float4(
          bf2f((ushort)ua.z), bf2f((ushort)(ua.z >> 16)),
          bf2f((ushort)ua.w), bf2f((ushort)(ua.w >> 16)));
      *(float4*)&Qt[tTh][kb + 8] = make_float4(
          bf2f((ushort)ub.x), bf2f((ushort)(ub.x >> 16)),
          bf2f((ushort)ub.y), bf2f((ushort)(ub.y >> 16)));
      *(float4*)&Qt[tTh][kb + 12] = make_float4(
          bf2f((ushort)ub.z), bf2f((ushort)(ub.z >> 16)),
          bf2f((ushort)ub.w), bf2f((ushort)(ub.w >> 16)));
      if (tid < 64)
        betaL[tid] = sigmoidf_(f1g1b[(size_t)(b * T_ + t0 + tid) * 256 + 128 + h]);
    }
    __syncthreads();

    // ---- PH2: cumsum within 16-quarters (lane=k), segment totals -> dlog[q] ----
    {
      const int q = wA, k = tA;
      float run = 0.f;
      #pragma unroll
      for (int i = 0; i < 16; i++) { run += cM[q * 16 + i][k]; cM[q * 16 + i][k] = run; }
      dlog[q][k] = run;
    }
    __syncthreads();
    // ---- PH3: apply segment offsets ----
    {
      const int q = wA, k = tA;
      if (q > 0) {
        float off = dlog[0][k];
        if (q > 1) off += dlog[1][k];
        if (q > 2) off += dlog[2][k];
        #pragma unroll
        for (int i = 0; i < 16; i++) cM[q * 16 + i][k] += off;
      }
    }
    __syncthreads();
    // ---- PH4: block-boundary log decays dlog[P][k], Eab = exp(dlog) ----
    for (int i = tid; i < 17 * 64; i += 256) {
      int P = i >> 6, k = i & 63;
      float d = (P == 0) ? 0.f : cM[4 * P - 1][k];
      dlog[P][k] = d;
      Eab[P][k] = expf(d);
    }
    __syncthreads();
    // ---- PH5: build K~/K^/Q~ (in place) + R table ----
    {
      const int P5 = tTh >> 2;
      #pragma unroll
      for (int i = 0; i < 16; i++) {
        int k = kb + i;
        float kn = Kt[tTh][k], qn = Qt[tTh][k];
        float c = cM[tTh][k], d = dlog[P5][k];
        float e1 = expf(c - d);        // <= 1
        float e2 = expf(d - c);        // <= e^{+44}
        Kt[tTh][k] = kn * e1;
        Kh[tTh][k] = kn * e2;
        Qt[tTh][k] = qn * e1;
      }
      for (int task = tid; task < 272; task += 256) {
        int f = task >> 1, kh = (task & 1) * 32;
        int rem = f, P = 0;
        while (rem >= P + 1) { rem -= P + 1; ++P; }
        int J = rem;
        for (int k = kh; k < kh + 32; k++)
          Rt[f][k] = expf(dlog[P][k] - dlog[J][k]);   // <= 1
      }
    }
    __syncthreads();
    // ---- PH6+7: rhs = beta*(vconv - W@S), Acc=0; then M-build ----
    {
      // v-conv + silu
      float vv[4];
      #pragma unroll
      for (int j = 0; j < 4; j++) {
        int cv = h * 64 + vq * 16 + lvi + j;
        float acc = vcb[cv];
        #pragma unroll
        for (int tap = 0; tap < 4; tap++) {
          int tr = t0 + tTh - 3 + tap;
          float xv = (tr >= 0) ? bf2f(qkv[(size_t)(b * T_ + tr) * 3072 + 2048 + cv]) : 0.f;
          acc += xv * vcw[cv * 4 + tap];
        }
        vv[j] = siluf_(acc);
      }
      // W@S where W = Kt * Eab[blk]
      const int btb = tTh >> 2;
      float a0 = 0.f, a1 = 0.f, a2 = 0.f, a3 = 0.f;
      for (int kc = 0; kc < 16; kc++) {
        float4 kv = *(const float4*)&Kt[tTh][kc * 4];
        float4 ev = *(const float4*)&Eab[btb][kc * 4];
        kv.x *= ev.x; kv.y *= ev.y; kv.z *= ev.z; kv.w *= ev.w;
        #pragma unroll
        for (int j = 0; j < 4; j++) {
          float4 sv = *(const float4*)&Sb[kc * 4 + j][lvi];
          float q = (j == 0) ? kv.x : (j == 1) ? kv.y : (j == 2) ? kv.z : kv.w;
          a0 += q * sv.x; a1 += q * sv.y; a2 += q * sv.z; a3 += q * sv.w;
        }
      }
      float btv = betaL[tTh];
      *(float4*)&rhsL[tTh][lvi] = make_float4(
          btv * (vv[0] - a0), btv * (vv[1] - a1), btv * (vv[2] - a2), btv * (vv[3] - a3));
      *(float4*)&AccL[tTh][lvi] = make_float4(0.f, 0.f, 0.f, 0.f);

      // M-build: 272 4x4 tiles (136 kk + 136 qk)
      for (int tile = tid; tile < 272; tile += 256) {
        int mq = (tile >= 136) ? 1 : 0;
        int f = tile - mq * 136;
        int rem = f, P = 0;
        while (rem >= P + 1) { rem -= P + 1; ++P; }
        int J = rem;
        const float (*Xr)[68] = mq ? Qt : Kt;
        float acc[4][4] = {};
        for (int kc = 0; kc < 16; kc++) {
          float4 av[4];
          #pragma unroll
          for (int r = 0; r < 4; r++) av[r] = *(const float4*)&Xr[4 * P + r][kc * 4];
          const float* rp = &Rt[f][kc * 4];
          float4 rv = make_float4(rp[0], rp[1], rp[2], rp[3]);
          #pragma unroll
          for (int c = 0; c < 4; c++) {
            float4 kvv = *(const float4*)&Kh[4 * J + c][kc * 4];
            float bx = kvv.x * rv.x, by = kvv.y * rv.y, bz = kvv.z * rv.z, bw = kvv.w * rv.w;
            #pragma unroll
            for (int r = 0; r < 4; r++)
              acc[r][c] += av[r].x * bx + av[r].y * by + av[r].z * bz + av[r].w * bw;
          }
        }
        float (*MT)[68] = mq ? cM : MkkT;
        #pragma unroll
        for (int c = 0; c < 4; c++)
          *(float4*)&MT[4 * J + c][4 * P] =
              make_float4(acc[0][c], acc[1][c], acc[2][c], acc[3][c]);
      }
    }
    __syncthreads();

    // ---- P-chain: 16 x {rank-4 Acc update; 4x4 solve} ----
    for (int P = 0; P < 16; P++) {
      if (P > 0) {
        const int s0 = 4 * (P - 1);
        float a0 = 0.f, a1 = 0.f, a2 = 0.f, a3 = 0.f;
        #pragma unroll
        for (int j = 0; j < 4; j++) {
          float m = MkkT[s0 + j][tTh];
          float4 uv = *(const float4*)&Ub[s0 + j][lvi];
          a0 += m * uv.x; a1 += m * uv.y; a2 += m * uv.z; a3 += m * uv.w;
        }
        float bt = betaL[tTh];
        float4 av = *(const float4*)&AccL[tTh][lvi];
        av.x += bt * a0; av.y += bt * a1; av.z += bt * a2; av.w += bt * a3;
        *(float4*)&AccL[tTh][lvi] = av;
      }
      __syncthreads();
      if (tid < 64) {
        const int th = tid >> 4, vi = tid & 15;
        const int r0 = 4 * P;
        float b1 = betaL[r0 + 1], b2 = betaL[r0 + 2], b3 = betaL[r0 + 3];
        float m10 = b1 * MkkT[r0 + 0][r0 + 1];
        float m20 = b2 * MkkT[r0 + 0][r0 + 2], m21 = b2 * MkkT[r0 + 1][r0 + 2];
        float m30 = b3 * MkkT[r0 + 0][r0 + 3], m31 = b3 * MkkT[r0 + 1][r0 + 3];
        float m32 = b3 * MkkT[r0 + 2][r0 + 3];
        float t10 = -m10;
        float t20 = -m20 + m21 * m10, t21 = -m21;
        float t30 = -m30 + m31 * m10 + m32 * m20 - m32 * m21 * m10;
        float t31 = -m31 + m32 * m21, t32 = -m32;
        float rp0 = rhsL[r0 + 0][vi] - AccL[r0 + 0][vi];
        float rp1 = rhsL[r0 + 1][vi] - AccL[r0 + 1][vi];
        float rp2 = rhsL[r0 + 2][vi] - AccL[r0 + 2][vi];
        float rp3 = rhsL[r0 + 3][vi] - AccL[r0 + 3][vi];
        float u0 = rp0;
        float u1 = t10 * rp0 + rp1;
        float u2 = t20 * rp0 + t21 * rp1 + rp2;
        float u3 = t30 * rp0 + t31 * rp1 + t32 * rp2 + rp3;
        Ub[r0 + th][vi] = (th == 0) ? u0 : (th == 1) ? u1 : (th == 2) ? u2 : u3;
      }
      __syncthreads();
    }

    // ---- O: tril(Mqk)@U + (Q~ e^d)@S, store bf16 ----
    {
      const int btb = tTh >> 2;
      float o0 = 0.f, o1 = 0.f, o2 = 0.f, o3 = 0.f;
      for (int kc = 0; kc < 16; kc++) {
        float4 qv = *(const float4*)&Qt[tTh][kc * 4];
        float4 ev = *(const float4*)&Eab[btb][kc * 4];
        qv.x *= ev.x; qv.y *= ev.y; qv.z *= ev.z; qv.w *= ev.w;
        #pragma unroll
        for (int j = 0; j < 4; j++) {
          float4 sv = *(const float4*)&Sb[kc * 4 + j][lvi];
          float q = (j == 0) ? qv.x : (j == 1) ? qv.y : (j == 2) ? qv.z : qv.w;
          o0 += q * sv.x; o1 += q * sv.y; o2 += q * sv.z; o3 += q * sv.w;
        }
      }
      for (int s = 0; s < 64; s++) {
        float m = cM[s][tTh];                 // MqkT[s][t]
        m = (s <= tTh) ? m : 0.f;
        float4 uv = *(const float4*)&Ub[s][lvi];
        o0 += m * uv.x; o1 += m * uv.y; o2 += m * uv.z; o3 += m * uv.w;
      }
      size_t ob = slab + (size_t)(t0 + tTh) * 64 + vq * 16 + lvi;
      uint lo = (uint)f2bf(o0) | ((uint)f2bf(o1) << 16);
      uint hi = (uint)f2bf(o2) | ((uint)f2bf(o3) << 16);
      *(uint2*)&oBH[ob] = make_uint2(lo, hi);
    }
    __syncthreads();

    // ---- S-update: S = e^{c63} S + sum_s (K^[s] e^{d16-d_blk(s)}) U[s] ----
    {
      const int k = tTh;
      float dl16 = dlog[16][k];
      float e16[16];
      #pragma unroll
      for (int J = 0; J < 16; J++) e16[J] = expf(dl16 - dlog[J][k]);
      float4 sv = *(const float4*)&Sb[k][lvi];
      float ge = Eab[16][k];
      sv.x *= ge; sv.y *= ge; sv.z *= ge; sv.w *= ge;
      for (int s = 0; s < 64; s++) {
        float kv = Kh[s][k] * e16[s >> 2];
        float4 uv = *(const float4*)&Ub[s][lvi];
        sv.x += kv * uv.x; sv.y += kv * uv.y; sv.z += kv * uv.z; sv.w += kv * uv.w;
      }
      *(float4*)&Sb[k][lvi] = sv;
    }
    __syncthreads();
  }
}

// ---------------------------------------------------------------------------
// RMS-norm + gate + split-pack into [hi|lo|hi] bf16 GEMM operand.
// o (bf16) layout [B,H,T,64]; out3 [M,3072].
// ---------------------------------------------------------------------------
__global__ __launch_bounds__(256) void onorm_pack(
    const ushort* __restrict__ o, const float* __restrict__ gate,
    const float* __restrict__ onw, ushort* __restrict__ out3) {
  int gi = blockIdx.x * 4 + (threadIdx.x >> 6);
  int lane = threadIdx.x & 63;
  int b = gi >> 15, h = (gi >> 11) & 15, t = gi & 2047;
  float ov = bf2f(o[(size_t)gi * 64 + lane]);
  float ms = wave_sum64(ov * ov) * (1.f / 64.f);
  float r = rsqrtf(ms + 1e-5f);
  float gv = gate[(size_t)(b * T_ + t) * 1024 + h * 64 + lane];
  float val = ov * r * onw[lane] * sigmoidf_(gv);
  ushort hi = f2bf(val);
  float rem = val - bf2f(hi);
  ushort lo = f2bf(rem);
  size_t m = (size_t)(b * T_ + t);
  int c = h * 64 + lane;
  out3[m * 3072 + c] = hi;
  out3[m * 3072 + 1024 + c] = lo;
  out3[m * 3072 + 2048 + c] = hi;
}

extern "C" void kernel_launch(void* const* d_in, const int* in_sizes, int n_in,
                              void* d_out, int out_size, void* d_ws, size_t ws_size,
                              hipStream_t stream) {
  const float* hs    = (const float*)d_in[0];
  const float* Wq    = (const float*)d_in[1];
  const float* Wk    = (const float*)d_in[2];
  const float* Wv    = (const float*)d_in[3];
  const float* qcw   = (const float*)d_in[4];
  const float* qcb   = (const float*)d_in[5];
  const float* kcw   = (const float*)d_in[6];
  const float* kcb   = (const float*)d_in[7];
  const float* vcw   = (const float*)d_in[8];
  const float* vcb   = (const float*)d_in[9];
  const float* Wf1   = (const float*)d_in[10];
  const float* Wf2   = (const float*)d_in[11];
  const float* Wb    = (const float*)d_in[12];
  const float* A_log = (const float*)d_in[13];
  const float* dtb   = (const float*)d_in[14];
  const float* Wg1   = (const float*)d_in[15];
  const float* Wg2   = (const float*)d_in[16];
  const float* bg2   = (const float*)d_in[17];
  const float* onw   = (const float*)d_in[18];
  const float* Wo    = (const float*)d_in[19];
  float* out = (float*)d_out;

  char* ws = (char*)d_ws;
  ushort* hs3    = (ushort*)(ws);                 // [8192,3072] bf16, 48MiB
  float*  knG    = (float*)(ws);                  // [B,H,T,64] f32, 32MiB (hs3 dead)
  ushort* qnG    = (ushort*)(ws + 33554432);      // [B,H,T,64] bf16, 16MiB
  ushort* obuf3  = hs3;                           // [8192,3072] bf16 (kn/qn dead)
  ushort* qkvhat = (ushort*)(ws + 50331648);      // [8192,3072] bf16, 48MiB
  float*  gate   = (float*)qkvhat;                // [8192,1024] f32 (after chunk)
  ushort* grawB  = (ushort*)(ws + 100663296);     // [8192,1024] bf16, 16MiB
  ushort* obh    = (ushort*)(ws + 100663296);     // [B,H,T,64] bf16 O (grawB dead)
  float*  gObuf  = (float*)(ws + 117440512);      // [B,H,T,64] f32 g (read-only in chunk)
  char*   R4     = ws + 150994944;                // 18MiB pool
  ushort* Wqkv3  = (ushort*)R4;                   // [3072,3072] bf16
  ushort* Wfgb3  = (ushort*)R4;                   // [256,3072] bf16
  float*  f1g1b  = (float*)(R4 + 1572864);        // [8192,256] f32
  ushort* f1_3   = (ushort*)(R4 + 9961472);
  ushort* g1_3   = (ushort*)(R4 + 13107200);
  ushort* Wf2_3  = (ushort*)(R4 + 16252928);
  ushort* Wg2_3  = (ushort*)(R4 + 16646144);
  ushort* Wo3    = (ushort*)R4;                   // [1024,3072] bf16 (after gate GEMM)

  dim3 blk(256);
  const int PK = 1024 * 1024;

  split_pack_A<<<dim3((M_ * 1024) / 256), blk, 0, stream>>>(hs, 1024, 1024, M_, hs3);
  pack_w3t<<<dim3(PK / 256), blk, 0, stream>>>(Wq, 1024, 1024, Wqkv3, 3072);
  pack_w3t<<<dim3(PK / 256), blk, 0, stream>>>(Wk, 1024, 1024, Wqkv3 + (size_t)1024 * 3072, 3072);
  pack_w3t<<<dim3(PK / 256), blk, 0, stream>>>(Wv, 1024, 1024, Wqkv3 + (size_t)2048 * 3072, 3072);
  gemm_split<ushort><<<dim3(M_ / 128, 3072 / 128), blk, 0, stream>>>(
      hs3, Wqkv3, nullptr, qkvhat, M_, 3072, 3072);
  hipMemsetAsync(Wfgb3, 0, (size_t)256 * 3072 * 2, stream);
  pack_w3t<<<dim3((1024 * 64) / 256), blk, 0, stream>>>(Wf1, 1024, 64, Wfgb3, 3072);
  pack_w3t<<<dim3((1024 * 64) / 256), blk, 0, stream>>>(Wg1, 1024, 64, Wfgb3 + (size_t)64 * 3072, 3072);
  pack_w3t<<<dim3((1024 * 16) / 256), blk, 0, stream>>>(Wb, 1024, 16, Wfgb3 + (size_t)128 * 3072, 3072);
  gemm_split<float><<<dim3(M_ / 128, 2), blk, 0, stream>>>(
      hs3, Wfgb3, nullptr, f1g1b, M_, 256, 3072);
  split_pack_A<<<dim3((M_ * 64) / 256), blk, 0, stream>>>(f1g1b, 256, 64, M_, f1_3);
  split_pack_A<<<dim3((M_ * 64) / 256), blk, 0, stream>>>(f1g1b + 64, 256, 64, M_, g1_3);
  pack_w3t<<<dim3((64 * 1024) / 256), blk, 0, stream>>>(Wf2, 64, 1024, Wf2_3, 192);
  gemm_split<ushort><<<dim3(M_ / 128, 1024 / 128), blk, 0, stream>>>(
      f1_3, Wf2_3, nullptr, grawB, M_, 1024, 192);

  frontend<<<dim3(M_), blk, 0, stream>>>(qkvhat, grawB, qcw, qcb, kcw, kcb,
                                         A_log, dtb, knG, qnG, gObuf);
  chunk2<<<dim3(64, 4), blk, 0, stream>>>(knG, qnG, gObuf, obh, qkvhat, f1g1b, vcw, vcb);

  pack_w3t<<<dim3((64 * 1024) / 256), blk, 0, stream>>>(Wg2, 64, 1024, Wg2_3, 192);
  gemm_split<float><<<dim3(M_ / 128, 1024 / 128), blk, 0, stream>>>(
      g1_3, Wg2_3, bg2, gate, M_, 1024, 192);
  onorm_pack<<<dim3((M_ * H_) / 4), blk, 0, stream>>>(obh, gate, onw, obuf3);
  pack_w3t<<<dim3(PK / 256), blk, 0, stream>>>(Wo, 1024, 1024, Wo3, 3072);
  gemm_split<float><<<dim3(M_ / 128, 1024 / 128), blk, 0, stream>>>(
      obuf3, Wo3, nullptr, out, M_, 1024, 3072);
}

// Round 7
// 1025.314 us; speedup vs baseline: 3.4187x; 1.5623x over previous
//
#include <hip/hip_runtime.h>
#include <hip/hip_bf16.h>
#include <math.h>

#define H_ 16
#define HIDDEN_ 1024
#define BATCH_ 4
#define T_ 2048
#define M_ (BATCH_ * T_)   // 8192

typedef __attribute__((ext_vector_type(8))) __bf16 bf16x8;
typedef __attribute__((ext_vector_type(4))) float f32x4;

__device__ __forceinline__ float wave_sum64(float v) {
  #pragma unroll
  for (int m = 32; m >= 1; m >>= 1) v += __shfl_xor(v, m, 64);
  return v;
}
__device__ __forceinline__ float sigmoidf_(float x) { return 1.f / (1.f + expf(-x)); }
__device__ __forceinline__ float siluf_(float x) { return x / (1.f + expf(-x)); }
__device__ __forceinline__ float bf2f(ushort u) {
  unsigned int x = ((unsigned int)u) << 16;
  return __builtin_bit_cast(float, x);
}
__device__ __forceinline__ ushort f2bf(float f) {   // RNE
  unsigned int x = __builtin_bit_cast(unsigned int, f);
  unsigned int r = (x + 0x7fffu + ((x >> 16) & 1u)) >> 16;
  return (ushort)r;
}
__device__ __forceinline__ void ub4_(uint2 u, float f[4]) {
  f[0] = bf2f((ushort)u.x); f[1] = bf2f((ushort)(u.x >> 16));
  f[2] = bf2f((ushort)u.y); f[3] = bf2f((ushort)(u.y >> 16));
}
__device__ __forceinline__ uint2 pk4_(float a, float b, float c, float d) {
  return make_uint2((uint)f2bf(a) | ((uint)f2bf(b) << 16),
                    (uint)f2bf(c) | ((uint)f2bf(d) << 16));
}
__device__ __forceinline__ uint4 pk8_(const float* t) {
  uint4 r;
  r.x = (uint)f2bf(t[0]) | ((uint)f2bf(t[1]) << 16);
  r.y = (uint)f2bf(t[2]) | ((uint)f2bf(t[3]) << 16);
  r.z = (uint)f2bf(t[4]) | ((uint)f2bf(t[5]) << 16);
  r.w = (uint)f2bf(t[6]) | ((uint)f2bf(t[7]) << 16);
  return r;
}

// ---------------------------------------------------------------------------
// Split-pack A: f32 [M,K] -> bf16 [M,3K] as [hi | lo | hi].
// ---------------------------------------------------------------------------
__global__ __launch_bounds__(256) void split_pack_A(
    const float* __restrict__ in, int inStride, int K, int M,
    ushort* __restrict__ out) {
  size_t tid = (size_t)blockIdx.x * 256 + threadIdx.x;
  if (tid >= (size_t)M * K) return;
  int k = (int)(tid % K);
  size_t m = tid / K;
  float x = in[m * inStride + k];
  ushort hi = f2bf(x);
  float rem = x - bf2f(hi);
  ushort lo = f2bf(rem);
  size_t o = m * (size_t)(3 * K);
  out[o + k] = hi;
  out[o + K + k] = lo;
  out[o + 2 * K + k] = hi;
}

// ---------------------------------------------------------------------------
// Pack weight W [K,N] f32 -> transposed split bf16 [n][hi|hi|lo].
// ---------------------------------------------------------------------------
__global__ __launch_bounds__(256) void pack_w3t(
    const float* __restrict__ W, int K, int N,
    ushort* __restrict__ out, int rowStride) {
  size_t tid = (size_t)blockIdx.x * 256 + threadIdx.x;
  if (tid >= (size_t)K * N) return;
  int k = (int)(tid % K);
  size_t n = tid / K;
  float x = W[(size_t)k * N + n];
  ushort hi = f2bf(x);
  float rem = x - bf2f(hi);
  ushort lo = f2bf(rem);
  size_t o = n * (size_t)rowStride;
  out[o + k] = hi;
  out[o + K + k] = hi;
  out[o + 2 * K + k] = lo;
}

// ---------------------------------------------------------------------------
// bf16 MFMA GEMM: C[M,N] = A[M,K] @ Bt[N,K]^T (+bias). 128x128 tile, 4 waves.
// ---------------------------------------------------------------------------
template <typename OutT>
__global__ __launch_bounds__(256) void gemm_split(
    const ushort* __restrict__ A, const ushort* __restrict__ Bt,
    const float* __restrict__ bias, OutT* __restrict__ C,
    int M, int N, int K) {
  __shared__ ushort As[128][40];
  __shared__ ushort Bs[128][40];
  const int tid = threadIdx.x;
  const int bm = blockIdx.x * 128, bn = blockIdx.y * 128;
  const int wid = tid >> 6, lane = tid & 63;
  const int wm = (wid >> 1) * 64, wn = (wid & 1) * 64;
  const int fr = lane & 15, fq = lane >> 4;
  const int sm = tid >> 1, skk = (tid & 1) * 16;

  f32x4 acc[4][4] = {};

  for (int k0 = 0; k0 < K; k0 += 32) {
    const ushort* ga = A + (size_t)(bm + sm) * K + k0 + skk;
    const ushort* gb = Bt + (size_t)(bn + sm) * K + k0 + skk;
    uint4 a0 = *(const uint4*)ga;
    uint4 a1 = *(const uint4*)(ga + 8);
    uint4 b0 = *(const uint4*)gb;
    uint4 b1 = *(const uint4*)(gb + 8);
    *(uint4*)&As[sm][skk] = a0;
    *(uint4*)&As[sm][skk + 8] = a1;
    *(uint4*)&Bs[sm][skk] = b0;
    *(uint4*)&Bs[sm][skk + 8] = b1;
    __syncthreads();

    bf16x8 af[4], bfr[4];
    #pragma unroll
    for (int i = 0; i < 4; i++) af[i] = *(const bf16x8*)&As[wm + i * 16 + fr][fq * 8];
    #pragma unroll
    for (int j = 0; j < 4; j++) bfr[j] = *(const bf16x8*)&Bs[wn + j * 16 + fr][fq * 8];
    #pragma unroll
    for (int i = 0; i < 4; i++)
      #pragma unroll
      for (int j = 0; j < 4; j++)
        acc[i][j] = __builtin_amdgcn_mfma_f32_16x16x32_bf16(af[i], bfr[j], acc[i][j], 0, 0, 0);
    __syncthreads();
  }

  #pragma unroll
  for (int i = 0; i < 4; i++) {
    #pragma unroll
    for (int j = 0; j < 4; j++) {
      int col = bn + wn + j * 16 + fr;
      float bv = bias ? bias[col] : 0.f;
      #pragma unroll
      for (int r = 0; r < 4; r++) {
        int row = bm + wm + i * 16 + fq * 4 + r;
        float v = acc[i][j][r] + bv;
        if constexpr (sizeof(OutT) == 2) {
          ((ushort*)C)[(size_t)row * N + col] = f2bf(v);
        } else {
          ((float*)C)[(size_t)row * N + col] = v;
        }
      }
    }
  }
}

// ---------------------------------------------------------------------------
// Frontend: conv(K=4)+SiLU on q,k; L2-normalize (q also *0.125); per-channel
// log-decay g = -A*softplus(graw+dtb). Outputs in [B,H,T,64] layout.
// ---------------------------------------------------------------------------
__global__ __launch_bounds__(256) void frontend(
    const ushort* __restrict__ qkv, const ushort* __restrict__ grawB,
    const float* __restrict__ qcw, const float* __restrict__ qcb,
    const float* __restrict__ kcw, const float* __restrict__ kcb,
    const float* __restrict__ A_log, const float* __restrict__ dtb,
    float* __restrict__ knG, ushort* __restrict__ qnG, float* __restrict__ gG) {
  const int bt = blockIdx.x;
  const int b = bt >> 11, t = bt & 2047;
  const int w = threadIdx.x >> 6, lane = threadIdx.x & 63;
  #pragma unroll
  for (int hh = 0; hh < 4; hh++) {
    int h = w * 4 + hh;
    int cq = h * 64 + lane;
    float qa = qcb[cq], ka = kcb[cq];
    #pragma unroll
    for (int tap = 0; tap < 4; tap++) {
      int tr = t - 3 + tap;
      if (tr >= 0) {
        size_t r = (size_t)(b * T_ + tr) * 3072;
        qa += bf2f(qkv[r + cq]) * qcw[cq * 4 + tap];
        ka += bf2f(qkv[r + 1024 + cq]) * kcw[cq * 4 + tap];
      }
    }
    qa = siluf_(qa); ka = siluf_(ka);
    float sq = wave_sum64(qa * qa);
    float sk = wave_sum64(ka * ka);
    float qn = qa / (sqrtf(sq) + 1e-6f) * 0.125f;
    float kn = ka / (sqrtf(sk) + 1e-6f);
    float gr = bf2f(grawB[(size_t)(b * T_ + t) * 1024 + cq]) + dtb[cq];
    float sp = (gr > 20.f) ? gr : log1pf(expf(gr));
    float g = -expf(A_log[h]) * sp;
    size_t o = ((size_t)(b * 16 + h) * T_ + t) * 64 + lane;
    knG[o] = kn;
    qnG[o] = f2bf(qn);
    gG[o] = g;
  }
}

// ---------------------------------------------------------------------------
// prep: per (bh, chunk) fully-parallel precompute (grid 64 x 32).
// Computes cumsum c, block decays, K~/K^/Q~/R, Mkk/Mqk (UT transform),
// G = (I + beta*strict_tril(Mkk))^{-1} (column-parallel forward elim),
// then MG = tril(Mqk)@G, SG = KhE^T@G, WkB = beta*kn*e^c, Wq = qn*e^c,
// bv = beta*silu(conv(v)), ge = e^{c63}. All outputs bf16 (ge f32), written
// IN PLACE over this block's own kn/qn/g slabs (no cross-block races).
// ---------------------------------------------------------------------------
__global__ __launch_bounds__(256, 1) void prep(
    const float* __restrict__ knG, const ushort* __restrict__ qnG,
    const float* __restrict__ gG, const ushort* __restrict__ qkv,
    const float* __restrict__ f1g1b,
    const float* __restrict__ vcw, const float* __restrict__ vcb,
    ushort* __restrict__ mMGSG, ushort* __restrict__ mWkB,
    ushort* __restrict__ mWqBv, float* __restrict__ geG) {
  const int bh = blockIdx.x, ch = blockIdx.y;
  const int b = bh >> 4, h = bh & 15;
  const int i = bh * 32 + ch;
  const int t0 = ch * 64;
  const int tid = threadIdx.x;
  const int wA = tid >> 6, tA = tid & 63;
  const int tTh = tid >> 2, c4 = tid & 3, kb = c4 * 16;

  __shared__ __align__(16) float Kt[64][68];    // kn -> K~ = kn e^{c-d}
  __shared__ __align__(16) float Kh[64][68];    // K^ = kn e^{d-c}
  __shared__ __align__(16) float Qt[64][68];    // qn -> Q~ ; later KhE
  __shared__ __align__(16) float cM[64][68];    // g -> cumsum c ; later MqkT
  __shared__ __align__(16) float MkkT[64][68];
  __shared__ __align__(16) float Rt[136][66];   // ratio table; later G overlay
  __shared__ __align__(16) float dlog[17][68];
  __shared__ __align__(16) float Eab[17][68];
  __shared__ float betaL[64];
  float (*Gl)[68] = (float(*)[68])&Rt[0][0];

  // ---- PH1: loads ----
  {
    const size_t base = (size_t)i * 4096 + (size_t)tid * 16;
    #pragma unroll
    for (int u = 0; u < 4; u++) {
      *(float4*)&Kt[tTh][kb + u * 4] = *(const float4*)&knG[base + u * 4];
      *(float4*)&cM[tTh][kb + u * 4] = *(const float4*)&gG[base + u * 4];
    }
    uint4 ua = *(const uint4*)&qnG[base];
    uint4 ub = *(const uint4*)&qnG[base + 8];
    *(float4*)&Qt[tTh][kb + 0] = make_float4(
        bf2f((ushort)ua.x), bf2f((ushort)(ua.x >> 16)),
        bf2f((ushort)ua.y), bf2f((ushort)(ua.y >> 16)));
    *(float4*)&Qt[tTh][kb + 4] = make_float4(
        bf2f((ushort)ua.z), bf2f((ushort)(ua.z >> 16)),
        bf2f((ushort)ua.w), bf2f((ushort)(ua.w >> 16)));
    *(float4*)&Qt[tTh][kb + 8] = make_float4(
        bf2f((ushort)ub.x), bf2f((ushort)(ub.x >> 16)),
        bf2f((ushort)ub.y), bf2f((ushort)(ub.y >> 16)));
    *(float4*)&Qt[tTh][kb + 12] = make_float4(
        bf2f((ushort)ub.z), bf2f((ushort)(ub.z >> 16)),
        bf2f((ushort)ub.w), bf2f((ushort)(ub.w >> 16)));
    if (tid < 64)
      betaL[tid] = sigmoidf_(f1g1b[(size_t)(b * T_ + t0 + tid) * 256 + 128 + h]);
  }
  __syncthreads();
  // ---- PH2: cumsum within quarters ----
  {
    const int q = wA, k = tA;
    float run = 0.f;
    #pragma unroll
    for (int u = 0; u < 16; u++) { run += cM[q * 16 + u][k]; cM[q * 16 + u][k] = run; }
    dlog[q][k] = run;
  }
  __syncthreads();
  // ---- PH3: apply segment offsets ----
  {
    const int q = wA, k = tA;
    if (q > 0) {
      float off = dlog[0][k];
      if (q > 1) off += dlog[1][k];
      if (q > 2) off += dlog[2][k];
      #pragma unroll
      for (int u = 0; u < 16; u++) cM[q * 16 + u][k] += off;
    }
  }
  __syncthreads();
  // ---- PH4: block-base log decays + exps ----
  for (int idx = tid; idx < 17 * 64; idx += 256) {
    int P = idx >> 6, k = idx & 63;
    float d = (P == 0) ? 0.f : cM[4 * P - 1][k];
    dlog[P][k] = d;
    Eab[P][k] = expf(d);
  }
  __syncthreads();
  // ---- PH5: K~/K^/Q~ in place + R table ----
  {
    const int P5 = tTh >> 2;
    #pragma unroll
    for (int u = 0; u < 16; u++) {
      int k = kb + u;
      float kn = Kt[tTh][k], qn = Qt[tTh][k];
      float c = cM[tTh][k], d = dlog[P5][k];
      float e1 = expf(c - d);
      float e2 = expf(d - c);
      Kt[tTh][k] = kn * e1;
      Kh[tTh][k] = kn * e2;
      Qt[tTh][k] = qn * e1;
    }
    for (int task = tid; task < 272; task += 256) {
      int f = task >> 1, kh = (task & 1) * 32;
      int rem = f, P = 0;
      while (rem >= P + 1) { rem -= P + 1; ++P; }
      int J = rem;
      for (int k = kh; k < kh + 32; k++)
        Rt[f][k] = expf(dlog[P][k] - dlog[J][k]);
    }
  }
  __syncthreads();
  // ---- PH6: Wq/WkB/bv/ge writes + M-build ----
  {
    const int P = tTh >> 2;
    float bt = betaL[tTh];
    float tq[16], tk[16];
    #pragma unroll
    for (int u = 0; u < 16; u++) {
      int k = kb + u;
      float e = Eab[P][k];
      tq[u] = Qt[tTh][k] * e;
      tk[u] = bt * Kt[tTh][k] * e;
    }
    ushort* pq = mWqBv + (size_t)i * 8192 + tTh * 64 + kb;
    ushort* pk = mWkB + (size_t)i * 4096 + tTh * 64 + kb;
    *(uint4*)&pq[0] = pk8_(&tq[0]);
    *(uint4*)&pq[8] = pk8_(&tq[8]);
    *(uint4*)&pk[0] = pk8_(&tk[0]);
    *(uint4*)&pk[8] = pk8_(&tk[8]);

    // bv = beta * silu(conv(v))
    float av[16];
    #pragma unroll
    for (int u = 0; u < 16; u++) av[u] = vcb[h * 64 + kb + u];
    #pragma unroll
    for (int tap = 0; tap < 4; tap++) {
      int tr = t0 + tTh - 3 + tap;
      if (tr >= 0) {
        const ushort* vp = qkv + (size_t)(b * T_ + tr) * 3072 + 2048 + h * 64 + kb;
        uint4 va = *(const uint4*)vp;
        uint4 vb2 = *(const uint4*)(vp + 8);
        float xv[16];
        xv[0] = bf2f((ushort)va.x); xv[1] = bf2f((ushort)(va.x >> 16));
        xv[2] = bf2f((ushort)va.y); xv[3] = bf2f((ushort)(va.y >> 16));
        xv[4] = bf2f((ushort)va.z); xv[5] = bf2f((ushort)(va.z >> 16));
        xv[6] = bf2f((ushort)va.w); xv[7] = bf2f((ushort)(va.w >> 16));
        xv[8] = bf2f((ushort)vb2.x); xv[9] = bf2f((ushort)(vb2.x >> 16));
        xv[10] = bf2f((ushort)vb2.y); xv[11] = bf2f((ushort)(vb2.y >> 16));
        xv[12] = bf2f((ushort)vb2.z); xv[13] = bf2f((ushort)(vb2.z >> 16));
        xv[14] = bf2f((ushort)vb2.w); xv[15] = bf2f((ushort)(vb2.w >> 16));
        #pragma unroll
        for (int u = 0; u < 16; u++)
          av[u] += xv[u] * vcw[(h * 64 + kb + u) * 4 + tap];
      }
    }
    #pragma unroll
    for (int u = 0; u < 16; u++) av[u] = bt * siluf_(av[u]);
    ushort* pb = mWqBv + (size_t)i * 8192 + 4096 + tTh * 64 + kb;
    *(uint4*)&pb[0] = pk8_(&av[0]);
    *(uint4*)&pb[8] = pk8_(&av[8]);

    if (tid < 64) geG[(size_t)i * 64 + tid] = Eab[16][tid];

    // M-build: 272 4x4 tiles (136 kk + 136 qk), R-factorized (overflow-safe)
    for (int tile = tid; tile < 272; tile += 256) {
      int mq = (tile >= 136) ? 1 : 0;
      int f = tile - mq * 136;
      int rem = f, P2 = 0;
      while (rem >= P2 + 1) { rem -= P2 + 1; ++P2; }
      int J = rem;
      const float (*Xr)[68] = mq ? Qt : Kt;
      float acc[4][4] = {};
      for (int kc = 0; kc < 16; kc++) {
        float4 avv[4];
        #pragma unroll
        for (int r = 0; r < 4; r++) avv[r] = *(const float4*)&Xr[4 * P2 + r][kc * 4];
        const float* rp = &Rt[f][kc * 4];
        float4 rv = make_float4(rp[0], rp[1], rp[2], rp[3]);
        #pragma unroll
        for (int c = 0; c < 4; c++) {
          float4 kvv = *(const float4*)&Kh[4 * J + c][kc * 4];
          float bx = kvv.x * rv.x, by = kvv.y * rv.y, bz = kvv.z * rv.z, bw = kvv.w * rv.w;
          #pragma unroll
          for (int r = 0; r < 4; r++)
            acc[r][c] += avv[r].x * bx + avv[r].y * by + avv[r].z * bz + avv[r].w * bw;
        }
      }
      if (mq && P2 == J) {   // inclusive-tril mask on diagonal tile
        #pragma unroll
        for (int c = 0; c < 4; c++)
          #pragma unroll
          for (int r = 0; r < 4; r++)
            if (c > r) acc[r][c] = 0.f;
      }
      float (*MT)[68] = mq ? cM : MkkT;
      #pragma unroll
      for (int c = 0; c < 4; c++)
        *(float4*)&MT[4 * J + c][4 * P2] =
            make_float4(acc[0][c], acc[1][c], acc[2][c], acc[3][c]);
    }
  }
  __syncthreads();
  // ---- PH7: KhE into Qt + G-solve (column-parallel forward elimination) ----
  for (int idx = tid; idx < 4096; idx += 256) {
    int s = idx >> 6, k = idx & 63;
    Qt[s][k] = Kh[s][k] * expf(dlog[16][k] - dlog[s >> 2][k]);
  }
  {
    const int j = tTh, q = c4;
    float acc[16], gsv[16];
    #pragma unroll
    for (int u = 0; u < 16; u++) { acc[u] = 0.f; gsv[u] = 0.f; }
    for (int s = 0; s < 64; s++) {
      int q0 = s >> 4;
      float g = 0.f;
      if (q == q0) {
        g = ((s == j) ? 1.f : 0.f) - betaL[s] * acc[s & 15];
        gsv[s & 15] = g;
      }
      g = __shfl(g, 4 * (j & 15) + q0, 64);
      #pragma unroll
      for (int u = 0; u < 4; u++) {
        float4 m4 = *(const float4*)&MkkT[s][q * 16 + u * 4];
        acc[u * 4 + 0] += m4.x * g;
        acc[u * 4 + 1] += m4.y * g;
        acc[u * 4 + 2] += m4.z * g;
        acc[u * 4 + 3] += m4.w * g;
      }
    }
    #pragma unroll
    for (int u = 0; u < 16; u++) Gl[q * 16 + u][j] = gsv[u];
  }
  __syncthreads();
  // ---- PH8: MG = tril(Mqk)@G, SG = KhE^T@G, write bf16 ----
  {
    float o[16];
    #pragma unroll
    for (int u = 0; u < 16; u++) o[u] = 0.f;
    for (int s = 0; s < 64; s++) {
      float m = (s <= tTh) ? cM[s][tTh] : 0.f;
      #pragma unroll
      for (int u = 0; u < 4; u++) {
        float4 g4 = *(const float4*)&Gl[s][kb + u * 4];
        o[u * 4 + 0] += m * g4.x; o[u * 4 + 1] += m * g4.y;
        o[u * 4 + 2] += m * g4.z; o[u * 4 + 3] += m * g4.w;
      }
    }
    ushort* pm = mMGSG + (size_t)i * 8192 + tTh * 64 + kb;
    *(uint4*)&pm[0] = pk8_(&o[0]);
    *(uint4*)&pm[8] = pk8_(&o[8]);

    #pragma unroll
    for (int u = 0; u < 16; u++) o[u] = 0.f;
    for (int s = 0; s < 64; s++) {
      float m = Qt[s][tTh];
      #pragma unroll
      for (int u = 0; u < 4; u++) {
        float4 g4 = *(const float4*)&Gl[s][kb + u * 4];
        o[u * 4 + 0] += m * g4.x; o[u * 4 + 1] += m * g4.y;
        o[u * 4 + 2] += m * g4.z; o[u * 4 + 3] += m * g4.w;
      }
    }
    ushort* ps = mMGSG + (size_t)i * 8192 + 4096 + tTh * 64 + kb;
    *(uint4*)&ps[0] = pk8_(&o[0]);
    *(uint4*)&ps[8] = pk8_(&o[8]);
  }
}

// ---------------------------------------------------------------------------
// scan: sequential-over-chunks state propagation. Grid (64 bh, 4 vq).
// Per chunk: r = bv - WkB@S; O = MG@r + Wq@S; S = ge*S + SG@r.
// 4 barriers/chunk; next-chunk matrices prefetched into registers.
// ---------------------------------------------------------------------------
__global__ __launch_bounds__(256) void scan(
    const ushort* __restrict__ mMGSG, const ushort* __restrict__ mWkB,
    const ushort* __restrict__ mWqBv, const float* __restrict__ geG,
    ushort* __restrict__ oG) {
  const int bh = blockIdx.x, vq = blockIdx.y;
  const int tid = threadIdx.x;
  const int tTh = tid >> 2, c4 = tid & 3, lvi = c4 * 4;
  const int r0 = tid >> 2, cc = (tid & 3) * 16;   // staging dest

  __shared__ ushort MGs[64][72], SGs[64][72], WkBs[64][72], Wqs[64][72];
  __shared__ __align__(16) float Sl[64][20], rl[64][20];
  __shared__ float geL[64];

  *(float4*)&Sl[tTh][lvi] = make_float4(0.f, 0.f, 0.f, 0.f);

  const size_t i0 = (size_t)bh * 32;
  // stage chunk 0
  {
    uint4 a0 = *(const uint4*)&mMGSG[i0 * 8192 + tid * 16];
    uint4 a1 = *(const uint4*)&mMGSG[i0 * 8192 + tid * 16 + 8];
    uint4 b0 = *(const uint4*)&mMGSG[i0 * 8192 + 4096 + tid * 16];
    uint4 b1 = *(const uint4*)&mMGSG[i0 * 8192 + 4096 + tid * 16 + 8];
    uint4 c0 = *(const uint4*)&mWkB[i0 * 4096 + tid * 16];
    uint4 c1 = *(const uint4*)&mWkB[i0 * 4096 + tid * 16 + 8];
    uint4 d0 = *(const uint4*)&mWqBv[i0 * 8192 + tid * 16];
    uint4 d1 = *(const uint4*)&mWqBv[i0 * 8192 + tid * 16 + 8];
    *(uint4*)&MGs[r0][cc] = a0;  *(uint4*)&MGs[r0][cc + 8] = a1;
    *(uint4*)&SGs[r0][cc] = b0;  *(uint4*)&SGs[r0][cc + 8] = b1;
    *(uint4*)&WkBs[r0][cc] = c0; *(uint4*)&WkBs[r0][cc + 8] = c1;
    *(uint4*)&Wqs[r0][cc] = d0;  *(uint4*)&Wqs[r0][cc + 8] = d1;
    if (tid < 64) geL[tid] = geG[i0 * 64 + tid];
  }
  uint2 bvCur = *(const uint2*)&mWqBv[i0 * 8192 + 4096 + tTh * 64 + vq * 16 + lvi];
  __syncthreads();

  for (int ch = 0; ch < 32; ch++) {
    const size_t i = i0 + ch;
    uint4 p0, p1, p2, p3, p4, p5, p6, p7;
    uint2 pbv;
    float pge = 0.f;
    if (ch < 31) {
      const size_t i2 = i + 1;
      p0 = *(const uint4*)&mMGSG[i2 * 8192 + tid * 16];
      p1 = *(const uint4*)&mMGSG[i2 * 8192 + tid * 16 + 8];
      p2 = *(const uint4*)&mMGSG[i2 * 8192 + 4096 + tid * 16];
      p3 = *(const uint4*)&mMGSG[i2 * 8192 + 4096 + tid * 16 + 8];
      p4 = *(const uint4*)&mWkB[i2 * 4096 + tid * 16];
      p5 = *(const uint4*)&mWkB[i2 * 4096 + tid * 16 + 8];
      p6 = *(const uint4*)&mWqBv[i2 * 8192 + tid * 16];
      p7 = *(const uint4*)&mWqBv[i2 * 8192 + tid * 16 + 8];
      pbv = *(const uint2*)&mWqBv[i2 * 8192 + 4096 + tTh * 64 + vq * 16 + lvi];
      if (tid < 64) pge = geG[i2 * 64 + tid];
    }
    // P1: r = bv - WkB@S
    float rv[4];
    ub4_(bvCur, rv);
    #pragma unroll
    for (int kc = 0; kc < 16; kc++) {
      float w4[4];
      ub4_(*(const uint2*)&WkBs[tTh][kc * 4], w4);
      #pragma unroll
      for (int jj = 0; jj < 4; jj++) {
        float4 s4 = *(const float4*)&Sl[kc * 4 + jj][lvi];
        rv[0] -= w4[jj] * s4.x; rv[1] -= w4[jj] * s4.y;
        rv[2] -= w4[jj] * s4.z; rv[3] -= w4[jj] * s4.w;
      }
    }
    *(float4*)&rl[tTh][lvi] = make_float4(rv[0], rv[1], rv[2], rv[3]);
    __syncthreads();
    // P2: O = MG@r + Wq@S
    {
      float ov[4] = {0.f, 0.f, 0.f, 0.f};
      #pragma unroll
      for (int sc = 0; sc < 16; sc++) {
        float m4[4];
        ub4_(*(const uint2*)&MGs[tTh][sc * 4], m4);
        #pragma unroll
        for (int jj = 0; jj < 4; jj++) {
          float4 r4 = *(const float4*)&rl[sc * 4 + jj][lvi];
          ov[0] += m4[jj] * r4.x; ov[1] += m4[jj] * r4.y;
          ov[2] += m4[jj] * r4.z; ov[3] += m4[jj] * r4.w;
        }
      }
      #pragma unroll
      for (int kc = 0; kc < 16; kc++) {
        float q4[4];
        ub4_(*(const uint2*)&Wqs[tTh][kc * 4], q4);
        #pragma unroll
        for (int jj = 0; jj < 4; jj++) {
          float4 s4 = *(const float4*)&Sl[kc * 4 + jj][lvi];
          ov[0] += q4[jj] * s4.x; ov[1] += q4[jj] * s4.y;
          ov[2] += q4[jj] * s4.z; ov[3] += q4[jj] * s4.w;
        }
      }
      *(uint2*)&oG[i * 4096 + tTh * 64 + vq * 16 + lvi] =
          pk4_(ov[0], ov[1], ov[2], ov[3]);
    }
    __syncthreads();
    // P3: S = ge*S + SG@r
    {
      float4 s4 = *(const float4*)&Sl[tTh][lvi];
      float ge = geL[tTh];
      float sv[4] = {ge * s4.x, ge * s4.y, ge * s4.z, ge * s4.w};
      #pragma unroll
      for (int sc = 0; sc < 16; sc++) {
        float g4[4];
        ub4_(*(const uint2*)&SGs[tTh][sc * 4], g4);
        #pragma unroll
        for (int jj = 0; jj < 4; jj++) {
          float4 r4 = *(const float4*)&rl[sc * 4 + jj][lvi];
          sv[0] += g4[jj] * r4.x; sv[1] += g4[jj] * r4.y;
          sv[2] += g4[jj] * r4.z; sv[3] += g4[jj] * r4.w;
        }
      }
      *(float4*)&Sl[tTh][lvi] = make_float4(sv[0], sv[1], sv[2], sv[3]);
    }
    __syncthreads();
    // stage next chunk
    if (ch < 31) {
      *(uint4*)&MGs[r0][cc] = p0;  *(uint4*)&MGs[r0][cc + 8] = p1;
      *(uint4*)&SGs[r0][cc] = p2;  *(uint4*)&SGs[r0][cc + 8] = p3;
      *(uint4*)&WkBs[r0][cc] = p4; *(uint4*)&WkBs[r0][cc + 8] = p5;
      *(uint4*)&Wqs[r0][cc] = p6;  *(uint4*)&Wqs[r0][cc + 8] = p7;
      if (tid < 64) geL[tid] = pge;
      bvCur = pbv;
      __syncthreads();
    }
  }
}

// ---------------------------------------------------------------------------
// RMS-norm + gate + split-pack into [hi|lo|hi] bf16 GEMM operand.
// ---------------------------------------------------------------------------
__global__ __launch_bounds__(256) void onorm_pack(
    const ushort* __restrict__ o, const float* __restrict__ gate,
    const float* __restrict__ onw, ushort* __restrict__ out3) {
  int gi = blockIdx.x * 4 + (threadIdx.x >> 6);
  int lane = threadIdx.x & 63;
  int b = gi >> 15, h = (gi >> 11) & 15, t = gi & 2047;
  float ov = bf2f(o[(size_t)gi * 64 + lane]);
  float ms = wave_sum64(ov * ov) * (1.f / 64.f);
  float r = rsqrtf(ms + 1e-5f);
  float gv = gate[(size_t)(b * T_ + t) * 1024 + h * 64 + lane];
  float val = ov * r * onw[lane] * sigmoidf_(gv);
  ushort hi = f2bf(val);
  float rem = val - bf2f(hi);
  ushort lo = f2bf(rem);
  size_t m = (size_t)(b * T_ + t);
  int c = h * 64 + lane;
  out3[m * 3072 + c] = hi;
  out3[m * 3072 + 1024 + c] = lo;
  out3[m * 3072 + 2048 + c] = hi;
}

extern "C" void kernel_launch(void* const* d_in, const int* in_sizes, int n_in,
                              void* d_out, int out_size, void* d_ws, size_t ws_size,
                              hipStream_t stream) {
  const float* hs    = (const float*)d_in[0];
  const float* Wq    = (const float*)d_in[1];
  const float* Wk    = (const float*)d_in[2];
  const float* Wv    = (const float*)d_in[3];
  const float* qcw   = (const float*)d_in[4];
  const float* qcb   = (const float*)d_in[5];
  const float* kcw   = (const float*)d_in[6];
  const float* kcb   = (const float*)d_in[7];
  const float* vcw   = (const float*)d_in[8];
  const float* vcb   = (const float*)d_in[9];
  const float* Wf1   = (const float*)d_in[10];
  const float* Wf2   = (const float*)d_in[11];
  const float* Wb    = (const float*)d_in[12];
  const float* A_log = (const float*)d_in[13];
  const float* dtb   = (const float*)d_in[14];
  const float* Wg1   = (const float*)d_in[15];
  const float* Wg2   = (const float*)d_in[16];
  const float* bg2   = (const float*)d_in[17];
  const float* onw   = (const float*)d_in[18];
  const float* Wo    = (const float*)d_in[19];
  float* out = (float*)d_out;

  char* ws = (char*)d_ws;
  // [0,48M):   hs3 -> knG[0,32)+qnG[32,48) -> MG/SG (over kn slabs) + WkB (over qn slabs) -> obuf3
  // [48,96M):  qkvhat -> gate f32 [48,80) ; O bf16 [80,96)
  // [96,112M): grawB -> ge (prep)
  // [112,144M): gObuf (g) -> Wq+bv (prep, self-slab overwrite)
  // [144,162M): R4 pool (weights packs, f1g1b, f1_3/g1_3, later Wo3)
  ushort* hs3    = (ushort*)(ws);
  float*  knG    = (float*)(ws);
  ushort* qnG    = (ushort*)(ws + 33554432);
  ushort* obuf3  = hs3;
  ushort* mMGSG  = (ushort*)(ws);
  ushort* mWkB   = (ushort*)(ws + 33554432);
  ushort* qkvhat = (ushort*)(ws + 50331648);
  float*  gate   = (float*)qkvhat;
  ushort* oG     = (ushort*)(ws + 50331648 + 33554432);   // ws+80MiB
  ushort* grawB  = (ushort*)(ws + 100663296);
  float*  geG    = (float*)(ws + 100663296);
  float*  gObuf  = (float*)(ws + 117440512);
  ushort* mWqBv  = (ushort*)(ws + 117440512);
  char*   R4     = ws + 150994944;
  ushort* Wqkv3  = (ushort*)R4;
  ushort* Wfgb3  = (ushort*)R4;
  float*  f1g1b  = (float*)(R4 + 1572864);
  ushort* f1_3   = (ushort*)(R4 + 9961472);
  ushort* g1_3   = (ushort*)(R4 + 13107200);
  ushort* Wf2_3  = (ushort*)(R4 + 16252928);
  ushort* Wg2_3  = (ushort*)(R4 + 16646144);
  ushort* Wo3    = (ushort*)R4;

  dim3 blk(256);
  const int PK = 1024 * 1024;

  split_pack_A<<<dim3((M_ * 1024) / 256), blk, 0, stream>>>(hs, 1024, 1024, M_, hs3);
  pack_w3t<<<dim3(PK / 256), blk, 0, stream>>>(Wq, 1024, 1024, Wqkv3, 3072);
  pack_w3t<<<dim3(PK / 256), blk, 0, stream>>>(Wk, 1024, 1024, Wqkv3 + (size_t)1024 * 3072, 3072);
  pack_w3t<<<dim3(PK / 256), blk, 0, stream>>>(Wv, 1024, 1024, Wqkv3 + (size_t)2048 * 3072, 3072);
  gemm_split<ushort><<<dim3(M_ / 128, 3072 / 128), blk, 0, stream>>>(
      hs3, Wqkv3, nullptr, qkvhat, M_, 3072, 3072);
  hipMemsetAsync(Wfgb3, 0, (size_t)256 * 3072 * 2, stream);
  pack_w3t<<<dim3((1024 * 64) / 256), blk, 0, stream>>>(Wf1, 1024, 64, Wfgb3, 3072);
  pack_w3t<<<dim3((1024 * 64) / 256), blk, 0, stream>>>(Wg1, 1024, 64, Wfgb3 + (size_t)64 * 3072, 3072);
  pack_w3t<<<dim3((1024 * 16) / 256), blk, 0, stream>>>(Wb, 1024, 16, Wfgb3 + (size_t)128 * 3072, 3072);
  gemm_split<float><<<dim3(M_ / 128, 2), blk, 0, stream>>>(
      hs3, Wfgb3, nullptr, f1g1b, M_, 256, 3072);
  split_pack_A<<<dim3((M_ * 64) / 256), blk, 0, stream>>>(f1g1b, 256, 64, M_, f1_3);
  split_pack_A<<<dim3((M_ * 64) / 256), blk, 0, stream>>>(f1g1b + 64, 256, 64, M_, g1_3);
  pack_w3t<<<dim3((64 * 1024) / 256), blk, 0, stream>>>(Wf2, 64, 1024, Wf2_3, 192);
  gemm_split<ushort><<<dim3(M_ / 128, 1024 / 128), blk, 0, stream>>>(
      f1_3, Wf2_3, nullptr, grawB, M_, 1024, 192);

  frontend<<<dim3(M_), blk, 0, stream>>>(qkvhat, grawB, qcw, qcb, kcw, kcb,
                                         A_log, dtb, knG, qnG, gObuf);
  prep<<<dim3(64, 32), blk, 0, stream>>>(knG, qnG, gObuf, qkvhat, f1g1b,
                                         vcw, vcb, mMGSG, mWkB, mWqBv, geG);
  // gate GEMM (writes qkvhat region — must be after prep, which reads v there)
  pack_w3t<<<dim3((64 * 1024) / 256), blk, 0, stream>>>(Wg2, 64, 1024, Wg2_3, 192);
  gemm_split<float><<<dim3(M_ / 128, 1024 / 128), blk, 0, stream>>>(
      g1_3, Wg2_3, bg2, gate, M_, 1024, 192);

  scan<<<dim3(64, 4), blk, 0, stream>>>(mMGSG, mWkB, mWqBv, geG, oG);

  onorm_pack<<<dim3((M_ * H_) / 4), blk, 0, stream>>>(oG, gate, onw, obuf3);
  pack_w3t<<<dim3(PK / 256), blk, 0, stream>>>(Wo, 1024, 1024, Wo3, 3072);
  gemm_split<float><<<dim3(M_ / 128, 1024 / 128), blk, 0, stream>>>(
      obuf3, Wo3, nullptr, out, M_, 1024, 3072);
}

// Round 8
// 782.602 us; speedup vs baseline: 4.4790x; 1.3101x over previous
//
#include <hip/hip_runtime.h>
#include <hip/hip_bf16.h>
#include <math.h>

#define H_ 16
#define HIDDEN_ 1024
#define BATCH_ 4
#define T_ 2048
#define M_ (BATCH_ * T_)   // 8192

typedef __attribute__((ext_vector_type(8))) __bf16 bf16x8;
typedef __attribute__((ext_vector_type(4))) float f32x4;

__device__ __forceinline__ float wave_sum64(float v) {
  #pragma unroll
  for (int m = 32; m >= 1; m >>= 1) v += __shfl_xor(v, m, 64);
  return v;
}
__device__ __forceinline__ float sigmoidf_(float x) { return 1.f / (1.f + expf(-x)); }
__device__ __forceinline__ float siluf_(float x) { return x / (1.f + expf(-x)); }
__device__ __forceinline__ float bf2f(ushort u) {
  unsigned int x = ((unsigned int)u) << 16;
  return __builtin_bit_cast(float, x);
}
__device__ __forceinline__ ushort f2bf(float f) {   // RNE
  unsigned int x = __builtin_bit_cast(unsigned int, f);
  unsigned int r = (x + 0x7fffu + ((x >> 16) & 1u)) >> 16;
  return (ushort)r;
}
__device__ __forceinline__ void ub4_(uint2 u, float f[4]) {
  f[0] = bf2f((ushort)u.x); f[1] = bf2f((ushort)(u.x >> 16));
  f[2] = bf2f((ushort)u.y); f[3] = bf2f((ushort)(u.y >> 16));
}
__device__ __forceinline__ uint2 pk4_(float a, float b, float c, float d) {
  return make_uint2((uint)f2bf(a) | ((uint)f2bf(b) << 16),
                    (uint)f2bf(c) | ((uint)f2bf(d) << 16));
}
__device__ __forceinline__ uint4 pk8_(const float* t) {
  uint4 r;
  r.x = (uint)f2bf(t[0]) | ((uint)f2bf(t[1]) << 16);
  r.y = (uint)f2bf(t[2]) | ((uint)f2bf(t[3]) << 16);
  r.z = (uint)f2bf(t[4]) | ((uint)f2bf(t[5]) << 16);
  r.w = (uint)f2bf(t[6]) | ((uint)f2bf(t[7]) << 16);
  return r;
}

// ---------------------------------------------------------------------------
// Split-pack A: f32 [M,K] -> bf16 [M,2K] as [hi | lo]  (2-term split).
// ---------------------------------------------------------------------------
__global__ __launch_bounds__(256) void split_pack_A(
    const float* __restrict__ in, int inStride, int K, int M,
    ushort* __restrict__ out) {
  size_t tid = (size_t)blockIdx.x * 256 + threadIdx.x;
  if (tid >= (size_t)M * K) return;
  int k = (int)(tid % K);
  size_t m = tid / K;
  float x = in[m * inStride + k];
  ushort hi = f2bf(x);
  float rem = x - bf2f(hi);
  ushort lo = f2bf(rem);
  size_t o = m * (size_t)(2 * K);
  out[o + k] = hi;
  out[o + K + k] = lo;
}

// ---------------------------------------------------------------------------
// Pack weight W [K,N] f32 -> transposed bf16 [n][hi|hi] (2-term: B repeated).
// ---------------------------------------------------------------------------
__global__ __launch_bounds__(256) void pack_w3t(
    const float* __restrict__ W, int K, int N,
    ushort* __restrict__ out, int rowStride) {
  size_t tid = (size_t)blockIdx.x * 256 + threadIdx.x;
  if (tid >= (size_t)K * N) return;
  int k = (int)(tid % K);
  size_t n = tid / K;
  float x = W[(size_t)k * N + n];
  ushort hi = f2bf(x);
  size_t o = n * (size_t)rowStride;
  out[o + k] = hi;
  out[o + K + k] = hi;
}

// ---------------------------------------------------------------------------
// bf16 MFMA GEMM: C[M,N] = A[M,K] @ Bt[N,K]^T (+bias). 128x128 tile, 4 waves.
// ---------------------------------------------------------------------------
template <typename OutT>
__global__ __launch_bounds__(256) void gemm_split(
    const ushort* __restrict__ A, const ushort* __restrict__ Bt,
    const float* __restrict__ bias, OutT* __restrict__ C,
    int M, int N, int K) {
  __shared__ ushort As[128][40];
  __shared__ ushort Bs[128][40];
  const int tid = threadIdx.x;
  const int bm = blockIdx.x * 128, bn = blockIdx.y * 128;
  const int wid = tid >> 6, lane = tid & 63;
  const int wm = (wid >> 1) * 64, wn = (wid & 1) * 64;
  const int fr = lane & 15, fq = lane >> 4;
  const int sm = tid >> 1, skk = (tid & 1) * 16;

  f32x4 acc[4][4] = {};

  for (int k0 = 0; k0 < K; k0 += 32) {
    const ushort* ga = A + (size_t)(bm + sm) * K + k0 + skk;
    const ushort* gb = Bt + (size_t)(bn + sm) * K + k0 + skk;
    uint4 a0 = *(const uint4*)ga;
    uint4 a1 = *(const uint4*)(ga + 8);
    uint4 b0 = *(const uint4*)gb;
    uint4 b1 = *(const uint4*)(gb + 8);
    *(uint4*)&As[sm][skk] = a0;
    *(uint4*)&As[sm][skk + 8] = a1;
    *(uint4*)&Bs[sm][skk] = b0;
    *(uint4*)&Bs[sm][skk + 8] = b1;
    __syncthreads();

    bf16x8 af[4], bfr[4];
    #pragma unroll
    for (int i = 0; i < 4; i++) af[i] = *(const bf16x8*)&As[wm + i * 16 + fr][fq * 8];
    #pragma unroll
    for (int j = 0; j < 4; j++) bfr[j] = *(const bf16x8*)&Bs[wn + j * 16 + fr][fq * 8];
    #pragma unroll
    for (int i = 0; i < 4; i++)
      #pragma unroll
      for (int j = 0; j < 4; j++)
        acc[i][j] = __builtin_amdgcn_mfma_f32_16x16x32_bf16(af[i], bfr[j], acc[i][j], 0, 0, 0);
    __syncthreads();
  }

  #pragma unroll
  for (int i = 0; i < 4; i++) {
    #pragma unroll
    for (int j = 0; j < 4; j++) {
      int col = bn + wn + j * 16 + fr;
      float bv = bias ? bias[col] : 0.f;
      #pragma unroll
      for (int r = 0; r < 4; r++) {
        int row = bm + wm + i * 16 + fq * 4 + r;
        float v = acc[i][j][r] + bv;
        if constexpr (sizeof(OutT) == 2) {
          ((ushort*)C)[(size_t)row * N + col] = f2bf(v);
        } else {
          ((float*)C)[(size_t)row * N + col] = v;
        }
      }
    }
  }
}

// ---------------------------------------------------------------------------
// Frontend: conv(K=4)+SiLU on q,k; L2-normalize (q also *0.125); per-channel
// log-decay g = -A*softplus(graw+dtb). Outputs in [B,H,T,64] layout.
// ---------------------------------------------------------------------------
__global__ __launch_bounds__(256) void frontend(
    const ushort* __restrict__ qkv, const ushort* __restrict__ grawB,
    const float* __restrict__ qcw, const float* __restrict__ qcb,
    const float* __restrict__ kcw, const float* __restrict__ kcb,
    const float* __restrict__ A_log, const float* __restrict__ dtb,
    float* __restrict__ knG, ushort* __restrict__ qnG, float* __restrict__ gG) {
  const int bt = blockIdx.x;
  const int b = bt >> 11, t = bt & 2047;
  const int w = threadIdx.x >> 6, lane = threadIdx.x & 63;
  #pragma unroll
  for (int hh = 0; hh < 4; hh++) {
    int h = w * 4 + hh;
    int cq = h * 64 + lane;
    float qa = qcb[cq], ka = kcb[cq];
    #pragma unroll
    for (int tap = 0; tap < 4; tap++) {
      int tr = t - 3 + tap;
      if (tr >= 0) {
        size_t r = (size_t)(b * T_ + tr) * 3072;
        qa += bf2f(qkv[r + cq]) * qcw[cq * 4 + tap];
        ka += bf2f(qkv[r + 1024 + cq]) * kcw[cq * 4 + tap];
      }
    }
    qa = siluf_(qa); ka = siluf_(ka);
    float sq = wave_sum64(qa * qa);
    float sk = wave_sum64(ka * ka);
    float qn = qa / (sqrtf(sq) + 1e-6f) * 0.125f;
    float kn = ka / (sqrtf(sk) + 1e-6f);
    float gr = bf2f(grawB[(size_t)(b * T_ + t) * 1024 + cq]) + dtb[cq];
    float sp = (gr > 20.f) ? gr : log1pf(expf(gr));
    float g = -expf(A_log[h]) * sp;
    size_t o = ((size_t)(b * 16 + h) * T_ + t) * 64 + lane;
    knG[o] = kn;
    qnG[o] = f2bf(qn);
    gG[o] = g;
  }
}

// ---------------------------------------------------------------------------
// prep v2: per (bh, chunk) fully-parallel precompute (grid 64 x 32).
// LDS cut 132.6 -> ~74.5 KB for 2 blocks/CU:
//  - R ratio table recomputed on the fly from dlog (saves 36 KB)
//  - Eab recomputed at its 3 uses (saves 4.6 KB)
//  - Mkk/Mqk stored bf16, OVERLAID on dead cM space (saves 17.4 KB);
//    G overlaid on dead Kt space.
// ---------------------------------------------------------------------------
__global__ __launch_bounds__(256, 2) void prep(
    const float* __restrict__ knG, const ushort* __restrict__ qnG,
    const float* __restrict__ gG, const ushort* __restrict__ qkv,
    const float* __restrict__ f1g1b,
    const float* __restrict__ vcw, const float* __restrict__ vcb,
    ushort* __restrict__ mMGSG, ushort* __restrict__ mWkB,
    ushort* __restrict__ mWqBv, float* __restrict__ geG) {
  const int bh = blockIdx.x, ch = blockIdx.y;
  const int b = bh >> 4, h = bh & 15;
  const int i = bh * 32 + ch;
  const int t0 = ch * 64;
  const int tid = threadIdx.x;
  const int wA = tid >> 6, tA = tid & 63;
  const int tTh = tid >> 2, c4 = tid & 3, kb = c4 * 16;

  __shared__ __align__(16) float Kt[64][68];    // kn -> K~ ; after PH6: G
  __shared__ __align__(16) float Kh[64][68];    // K^ = kn e^{d-c}
  __shared__ __align__(16) float Qt[64][68];    // qn -> Q~ ; PH7: KhE
  __shared__ __align__(16) float cM[64][68];    // g -> cumsum c; PH6+: Mqk/Mkk bf16
  __shared__ __align__(16) float dlog[17][68];  // rows 0-3 first hold cumsum segT
  __shared__ float betaL[64];
  ushort (*MqkT)[68] = (ushort(*)[68])&cM[0][0];    // rows 0..31 of cM space
  ushort (*MkkT)[68] = (ushort(*)[68])&cM[32][0];   // rows 32..63
  float (*Gl)[68] = (float(*)[68])&Kt[0][0];

  // ---- PH1: loads ----
  {
    const size_t base = (size_t)i * 4096 + (size_t)tid * 16;
    #pragma unroll
    for (int u = 0; u < 4; u++) {
      *(float4*)&Kt[tTh][kb + u * 4] = *(const float4*)&knG[base + u * 4];
      *(float4*)&cM[tTh][kb + u * 4] = *(const float4*)&gG[base + u * 4];
    }
    uint4 ua = *(const uint4*)&qnG[base];
    uint4 ub = *(const uint4*)&qnG[base + 8];
    *(float4*)&Qt[tTh][kb + 0] = make_float4(
        bf2f((ushort)ua.x), bf2f((ushort)(ua.x >> 16)),
        bf2f((ushort)ua.y), bf2f((ushort)(ua.y >> 16)));
    *(float4*)&Qt[tTh][kb + 4] = make_float4(
        bf2f((ushort)ua.z), bf2f((ushort)(ua.z >> 16)),
        bf2f((ushort)ua.w), bf2f((ushort)(ua.w >> 16)));
    *(float4*)&Qt[tTh][kb + 8] = make_float4(
        bf2f((ushort)ub.x), bf2f((ushort)(ub.x >> 16)),
        bf2f((ushort)ub.y), bf2f((ushort)(ub.y >> 16)));
    *(float4*)&Qt[tTh][kb + 12] = make_float4(
        bf2f((ushort)ub.z), bf2f((ushort)(ub.z >> 16)),
        bf2f((ushort)ub.w), bf2f((ushort)(ub.w >> 16)));
    if (tid < 64)
      betaL[tid] = sigmoidf_(f1g1b[(size_t)(b * T_ + t0 + tid) * 256 + 128 + h]);
  }
  __syncthreads();
  // ---- PH2: cumsum within quarters ----
  {
    const int q = wA, k = tA;
    float run = 0.f;
    #pragma unroll
    for (int u = 0; u < 16; u++) { run += cM[q * 16 + u][k]; cM[q * 16 + u][k] = run; }
    dlog[q][k] = run;
  }
  __syncthreads();
  // ---- PH3: apply segment offsets ----
  {
    const int q = wA, k = tA;
    if (q > 0) {
      float off = dlog[0][k];
      if (q > 1) off += dlog[1][k];
      if (q > 2) off += dlog[2][k];
      #pragma unroll
      for (int u = 0; u < 16; u++) cM[q * 16 + u][k] += off;
    }
  }
  __syncthreads();
  // ---- PH4: block-base log decays ----
  for (int idx = tid; idx < 17 * 64; idx += 256) {
    int P = idx >> 6, k = idx & 63;
    dlog[P][k] = (P == 0) ? 0.f : cM[4 * P - 1][k];
  }
  __syncthreads();
  // ---- PH5: K~/K^/Q~ in place (cM dead after this) ----
  {
    const int P5 = tTh >> 2;
    #pragma unroll
    for (int u = 0; u < 16; u++) {
      int k = kb + u;
      float kn = Kt[tTh][k], qn = Qt[tTh][k];
      float c = cM[tTh][k], d = dlog[P5][k];
      float e1 = expf(c - d);
      float e2 = expf(d - c);
      Kt[tTh][k] = kn * e1;
      Kh[tTh][k] = kn * e2;
      Qt[tTh][k] = qn * e1;
    }
  }
  __syncthreads();
  // ---- PH6: Wq/WkB/bv/ge outputs + M-build (bf16 into cM overlay) ----
  {
    const int P = tTh >> 2;
    float bt = betaL[tTh];
    float tq[16], tk[16];
    #pragma unroll
    for (int u = 0; u < 16; u++) {
      int k = kb + u;
      float e = expf(dlog[P][k]);
      tq[u] = Qt[tTh][k] * e;
      tk[u] = bt * Kt[tTh][k] * e;
    }
    ushort* pq = mWqBv + (size_t)i * 8192 + tTh * 64 + kb;
    ushort* pk = mWkB + (size_t)i * 4096 + tTh * 64 + kb;
    *(uint4*)&pq[0] = pk8_(&tq[0]);
    *(uint4*)&pq[8] = pk8_(&tq[8]);
    *(uint4*)&pk[0] = pk8_(&tk[0]);
    *(uint4*)&pk[8] = pk8_(&tk[8]);

    float av[16];
    #pragma unroll
    for (int u = 0; u < 16; u++) av[u] = vcb[h * 64 + kb + u];
    #pragma unroll
    for (int tap = 0; tap < 4; tap++) {
      int tr = t0 + tTh - 3 + tap;
      if (tr >= 0) {
        const ushort* vp = qkv + (size_t)(b * T_ + tr) * 3072 + 2048 + h * 64 + kb;
        uint4 va = *(const uint4*)vp;
        uint4 vb2 = *(const uint4*)(vp + 8);
        float xv[16];
        xv[0] = bf2f((ushort)va.x); xv[1] = bf2f((ushort)(va.x >> 16));
        xv[2] = bf2f((ushort)va.y); xv[3] = bf2f((ushort)(va.y >> 16));
        xv[4] = bf2f((ushort)va.z); xv[5] = bf2f((ushort)(va.z >> 16));
        xv[6] = bf2f((ushort)va.w); xv[7] = bf2f((ushort)(va.w >> 16));
        xv[8] = bf2f((ushort)vb2.x); xv[9] = bf2f((ushort)(vb2.x >> 16));
        xv[10] = bf2f((ushort)vb2.y); xv[11] = bf2f((ushort)(vb2.y >> 16));
        xv[12] = bf2f((ushort)vb2.z); xv[13] = bf2f((ushort)(vb2.z >> 16));
        xv[14] = bf2f((ushort)vb2.w); xv[15] = bf2f((ushort)(vb2.w >> 16));
        #pragma unroll
        for (int u = 0; u < 16; u++)
          av[u] += xv[u] * vcw[(h * 64 + kb + u) * 4 + tap];
      }
    }
    #pragma unroll
    for (int u = 0; u < 16; u++) av[u] = bt * siluf_(av[u]);
    ushort* pb = mWqBv + (size_t)i * 8192 + 4096 + tTh * 64 + kb;
    *(uint4*)&pb[0] = pk8_(&av[0]);
    *(uint4*)&pb[8] = pk8_(&av[8]);

    if (tid < 64) geG[(size_t)i * 64 + tid] = expf(dlog[16][tid]);

    // M-build: 272 4x4 tiles, R recomputed on the fly (all exponents <= 0)
    for (int tile = tid; tile < 272; tile += 256) {
      int mq = (tile >= 136) ? 1 : 0;
      int f = tile - mq * 136;
      int rem = f, P2 = 0;
      while (rem >= P2 + 1) { rem -= P2 + 1; ++P2; }
      int J = rem;
      const float (*Xr)[68] = mq ? Qt : Kt;
      float acc[4][4] = {};
      for (int kc = 0; kc < 16; kc++) {
        float4 avv[4];
        #pragma unroll
        for (int r = 0; r < 4; r++) avv[r] = *(const float4*)&Xr[4 * P2 + r][kc * 4];
        float4 dp = *(const float4*)&dlog[P2][kc * 4];
        float4 dj = *(const float4*)&dlog[J][kc * 4];
        float4 rv = make_float4(expf(dp.x - dj.x), expf(dp.y - dj.y),
                                expf(dp.z - dj.z), expf(dp.w - dj.w));
        #pragma unroll
        for (int c = 0; c < 4; c++) {
          float4 kvv = *(const float4*)&Kh[4 * J + c][kc * 4];
          float bx = kvv.x * rv.x, by = kvv.y * rv.y, bz = kvv.z * rv.z, bw = kvv.w * rv.w;
          #pragma unroll
          for (int r = 0; r < 4; r++)
            acc[r][c] += avv[r].x * bx + avv[r].y * by + avv[r].z * bz + avv[r].w * bw;
        }
      }
      if (mq && P2 == J) {
        #pragma unroll
        for (int c = 0; c < 4; c++)
          #pragma unroll
          for (int r = 0; r < 4; r++)
            if (c > r) acc[r][c] = 0.f;
      }
      ushort (*MT)[68] = mq ? MqkT : MkkT;
      #pragma unroll
      for (int c = 0; c < 4; c++) {
        uint2 w;
        w.x = (uint)f2bf(acc[0][c]) | ((uint)f2bf(acc[1][c]) << 16);
        w.y = (uint)f2bf(acc[2][c]) | ((uint)f2bf(acc[3][c]) << 16);
        *(uint2*)&MT[4 * J + c][4 * P2] = w;
      }
    }
  }
  __syncthreads();
  // ---- PH7: KhE into Qt + G-solve (G overlays dead Kt) ----
  for (int idx = tid; idx < 4096; idx += 256) {
    int s = idx >> 6, k = idx & 63;
    Qt[s][k] = Kh[s][k] * expf(dlog[16][k] - dlog[s >> 2][k]);
  }
  {
    const int j = tTh, q = c4;
    float acc[16], gsv[16];
    #pragma unroll
    for (int u = 0; u < 16; u++) { acc[u] = 0.f; gsv[u] = 0.f; }
    for (int s = 0; s < 64; s++) {
      int q0 = s >> 4;
      float g = 0.f;
      if (q == q0) {
        g = ((s == j) ? 1.f : 0.f) - betaL[s] * acc[s & 15];
        gsv[s & 15] = g;
      }
      g = __shfl(g, 4 * (j & 15) + q0, 64);
      #pragma unroll
      for (int u = 0; u < 4; u++) {
        uint2 m2 = *(const uint2*)&MkkT[s][q * 16 + u * 4];
        acc[u * 4 + 0] += bf2f((ushort)m2.x) * g;
        acc[u * 4 + 1] += bf2f((ushort)(m2.x >> 16)) * g;
        acc[u * 4 + 2] += bf2f((ushort)m2.y) * g;
        acc[u * 4 + 3] += bf2f((ushort)(m2.y >> 16)) * g;
      }
    }
    // NOTE: Gl overlays Kt, which M-build read in PH6 — barrier above protects;
    // within PH7, G-solve reads only MkkT/betaL, so Gl writes are safe.
    #pragma unroll
    for (int u = 0; u < 16; u++) Gl[q * 16 + u][j] = gsv[u];
  }
  __syncthreads();
  // ---- PH8: MG = tril(Mqk)@G, SG = KhE^T@G, write bf16 ----
  {
    float o[16];
    #pragma unroll
    for (int u = 0; u < 16; u++) o[u] = 0.f;
    for (int s = 0; s <= tTh; s++) {
      float m = bf2f(MqkT[s][tTh]);
      #pragma unroll
      for (int u = 0; u < 4; u++) {
        float4 g4 = *(const float4*)&Gl[s][kb + u * 4];
        o[u * 4 + 0] += m * g4.x; o[u * 4 + 1] += m * g4.y;
        o[u * 4 + 2] += m * g4.z; o[u * 4 + 3] += m * g4.w;
      }
    }
    ushort* pm = mMGSG + (size_t)i * 8192 + tTh * 64 + kb;
    *(uint4*)&pm[0] = pk8_(&o[0]);
    *(uint4*)&pm[8] = pk8_(&o[8]);

    #pragma unroll
    for (int u = 0; u < 16; u++) o[u] = 0.f;
    for (int s = 0; s < 64; s++) {
      float m = Qt[s][tTh];
      #pragma unroll
      for (int u = 0; u < 4; u++) {
        float4 g4 = *(const float4*)&Gl[s][kb + u * 4];
        o[u * 4 + 0] += m * g4.x; o[u * 4 + 1] += m * g4.y;
        o[u * 4 + 2] += m * g4.z; o[u * 4 + 3] += m * g4.w;
      }
    }
    ushort* ps = mMGSG + (size_t)i * 8192 + 4096 + tTh * 64 + kb;
    *(uint4*)&ps[0] = pk8_(&o[0]);
    *(uint4*)&ps[8] = pk8_(&o[8]);
  }
}

// ---------------------------------------------------------------------------
// scan: sequential-over-chunks state propagation. Grid (64 bh, 4 vq).
// Per chunk: r = bv - WkB@S; O = MG@r + Wq@S; S = ge*S + SG@r.
// ---------------------------------------------------------------------------
__global__ __launch_bounds__(256) void scan(
    const ushort* __restrict__ mMGSG, const ushort* __restrict__ mWkB,
    const ushort* __restrict__ mWqBv, const float* __restrict__ geG,
    ushort* __restrict__ oG) {
  const int bh = blockIdx.x, vq = blockIdx.y;
  const int tid = threadIdx.x;
  const int tTh = tid >> 2, c4 = tid & 3, lvi = c4 * 4;
  const int r0 = tid >> 2, cc = (tid & 3) * 16;

  __shared__ ushort MGs[64][72], SGs[64][72], WkBs[64][72], Wqs[64][72];
  __shared__ __align__(16) float Sl[64][20], rl[64][20];
  __shared__ float geL[64];

  *(float4*)&Sl[tTh][lvi] = make_float4(0.f, 0.f, 0.f, 0.f);

  const size_t i0 = (size_t)bh * 32;
  {
    uint4 a0 = *(const uint4*)&mMGSG[i0 * 8192 + tid * 16];
    uint4 a1 = *(const uint4*)&mMGSG[i0 * 8192 + tid * 16 + 8];
    uint4 b0 = *(const uint4*)&mMGSG[i0 * 8192 + 4096 + tid * 16];
    uint4 b1 = *(const uint4*)&mMGSG[i0 * 8192 + 4096 + tid * 16 + 8];
    uint4 c0 = *(const uint4*)&mWkB[i0 * 4096 + tid * 16];
    uint4 c1 = *(const uint4*)&mWkB[i0 * 4096 + tid * 16 + 8];
    uint4 d0 = *(const uint4*)&mWqBv[i0 * 8192 + tid * 16];
    uint4 d1 = *(const uint4*)&mWqBv[i0 * 8192 + tid * 16 + 8];
    *(uint4*)&MGs[r0][cc] = a0;  *(uint4*)&MGs[r0][cc + 8] = a1;
    *(uint4*)&SGs[r0][cc] = b0;  *(uint4*)&SGs[r0][cc + 8] = b1;
    *(uint4*)&WkBs[r0][cc] = c0; *(uint4*)&WkBs[r0][cc + 8] = c1;
    *(uint4*)&Wqs[r0][cc] = d0;  *(uint4*)&Wqs[r0][cc + 8] = d1;
    if (tid < 64) geL[tid] = geG[i0 * 64 + tid];
  }
  uint2 bvCur = *(const uint2*)&mWqBv[i0 * 8192 + 4096 + tTh * 64 + vq * 16 + lvi];
  __syncthreads();

  for (int ch = 0; ch < 32; ch++) {
    const size_t i = i0 + ch;
    uint4 p0, p1, p2, p3, p4, p5, p6, p7;
    uint2 pbv;
    float pge = 0.f;
    if (ch < 31) {
      const size_t i2 = i + 1;
      p0 = *(const uint4*)&mMGSG[i2 * 8192 + tid * 16];
      p1 = *(const uint4*)&mMGSG[i2 * 8192 + tid * 16 + 8];
      p2 = *(const uint4*)&mMGSG[i2 * 8192 + 4096 + tid * 16];
      p3 = *(const uint4*)&mMGSG[i2 * 8192 + 4096 + tid * 16 + 8];
      p4 = *(const uint4*)&mWkB[i2 * 4096 + tid * 16];
      p5 = *(const uint4*)&mWkB[i2 * 4096 + tid * 16 + 8];
      p6 = *(const uint4*)&mWqBv[i2 * 8192 + tid * 16];
      p7 = *(const uint4*)&mWqBv[i2 * 8192 + tid * 16 + 8];
      pbv = *(const uint2*)&mWqBv[i2 * 8192 + 4096 + tTh * 64 + vq * 16 + lvi];
      if (tid < 64) pge = geG[i2 * 64 + tid];
    }
    float rv[4];
    ub4_(bvCur, rv);
    #pragma unroll
    for (int kc = 0; kc < 16; kc++) {
      float w4[4];
      ub4_(*(const uint2*)&WkBs[tTh][kc * 4], w4);
      #pragma unroll
      for (int jj = 0; jj < 4; jj++) {
        float4 s4 = *(const float4*)&Sl[kc * 4 + jj][lvi];
        rv[0] -= w4[jj] * s4.x; rv[1] -= w4[jj] * s4.y;
        rv[2] -= w4[jj] * s4.z; rv[3] -= w4[jj] * s4.w;
      }
    }
    *(float4*)&rl[tTh][lvi] = make_float4(rv[0], rv[1], rv[2], rv[3]);
    __syncthreads();
    {
      float ov[4] = {0.f, 0.f, 0.f, 0.f};
      #pragma unroll
      for (int sc = 0; sc < 16; sc++) {
        float m4[4];
        ub4_(*(const uint2*)&MGs[tTh][sc * 4], m4);
        #pragma unroll
        for (int jj = 0; jj < 4; jj++) {
          float4 r4 = *(const float4*)&rl[sc * 4 + jj][lvi];
          ov[0] += m4[jj] * r4.x; ov[1] += m4[jj] * r4.y;
          ov[2] += m4[jj] * r4.z; ov[3] += m4[jj] * r4.w;
        }
      }
      #pragma unroll
      for (int kc = 0; kc < 16; kc++) {
        float q4[4];
        ub4_(*(const uint2*)&Wqs[tTh][kc * 4], q4);
        #pragma unroll
        for (int jj = 0; jj < 4; jj++) {
          float4 s4 = *(const float4*)&Sl[kc * 4 + jj][lvi];
          ov[0] += q4[jj] * s4.x; ov[1] += q4[jj] * s4.y;
          ov[2] += q4[jj] * s4.z; ov[3] += q4[jj] * s4.w;
        }
      }
      *(uint2*)&oG[i * 4096 + tTh * 64 + vq * 16 + lvi] =
          pk4_(ov[0], ov[1], ov[2], ov[3]);
    }
    __syncthreads();
    {
      float4 s4 = *(const float4*)&Sl[tTh][lvi];
      float ge = geL[tTh];
      float sv[4] = {ge * s4.x, ge * s4.y, ge * s4.z, ge * s4.w};
      #pragma unroll
      for (int sc = 0; sc < 16; sc++) {
        float g4[4];
        ub4_(*(const uint2*)&SGs[tTh][sc * 4], g4);
        #pragma unroll
        for (int jj = 0; jj < 4; jj++) {
          float4 r4 = *(const float4*)&rl[sc * 4 + jj][lvi];
          sv[0] += g4[jj] * r4.x; sv[1] += g4[jj] * r4.y;
          sv[2] += g4[jj] * r4.z; sv[3] += g4[jj] * r4.w;
        }
      }
      *(float4*)&Sl[tTh][lvi] = make_float4(sv[0], sv[1], sv[2], sv[3]);
    }
    __syncthreads();
    if (ch < 31) {
      *(uint4*)&MGs[r0][cc] = p0;  *(uint4*)&MGs[r0][cc + 8] = p1;
      *(uint4*)&SGs[r0][cc] = p2;  *(uint4*)&SGs[r0][cc + 8] = p3;
      *(uint4*)&WkBs[r0][cc] = p4; *(uint4*)&WkBs[r0][cc + 8] = p5;
      *(uint4*)&Wqs[r0][cc] = p6;  *(uint4*)&Wqs[r0][cc + 8] = p7;
      if (tid < 64) geL[tid] = pge;
      bvCur = pbv;
      __syncthreads();
    }
  }
}

// ---------------------------------------------------------------------------
// RMS-norm + gate + split-pack into [hi|lo] bf16 GEMM operand.
// ---------------------------------------------------------------------------
__global__ __launch_bounds__(256) void onorm_pack(
    const ushort* __restrict__ o, const float* __restrict__ gate,
    const float* __restrict__ onw, ushort* __restrict__ out3) {
  int gi = blockIdx.x * 4 + (threadIdx.x >> 6);
  int lane = threadIdx.x & 63;
  int b = gi >> 15, h = (gi >> 11) & 15, t = gi & 2047;
  float ov = bf2f(o[(size_t)gi * 64 + lane]);
  float ms = wave_sum64(ov * ov) * (1.f / 64.f);
  float r = rsqrtf(ms + 1e-5f);
  float gv = gate[(size_t)(b * T_ + t) * 1024 + h * 64 + lane];
  float val = ov * r * onw[lane] * sigmoidf_(gv);
  ushort hi = f2bf(val);
  float rem = val - bf2f(hi);
  ushort lo = f2bf(rem);
  size_t m = (size_t)(b * T_ + t);
  int c = h * 64 + lane;
  out3[m * 2048 + c] = hi;
  out3[m * 2048 + 1024 + c] = lo;
}

extern "C" void kernel_launch(void* const* d_in, const int* in_sizes, int n_in,
                              void* d_out, int out_size, void* d_ws, size_t ws_size,
                              hipStream_t stream) {
  const float* hs    = (const float*)d_in[0];
  const float* Wq    = (const float*)d_in[1];
  const float* Wk    = (const float*)d_in[2];
  const float* Wv    = (const float*)d_in[3];
  const float* qcw   = (const float*)d_in[4];
  const float* qcb   = (const float*)d_in[5];
  const float* kcw   = (const float*)d_in[6];
  const float* kcb   = (const float*)d_in[7];
  const float* vcw   = (const float*)d_in[8];
  const float* vcb   = (const float*)d_in[9];
  const float* Wf1   = (const float*)d_in[10];
  const float* Wf2   = (const float*)d_in[11];
  const float* Wb    = (const float*)d_in[12];
  const float* A_log = (const float*)d_in[13];
  const float* dtb   = (const float*)d_in[14];
  const float* Wg1   = (const float*)d_in[15];
  const float* Wg2   = (const float*)d_in[16];
  const float* bg2   = (const float*)d_in[17];
  const float* onw   = (const float*)d_in[18];
  const float* Wo    = (const float*)d_in[19];
  float* out = (float*)d_out;

  char* ws = (char*)d_ws;
  ushort* hs3    = (ushort*)(ws);                 // [8192,2048] bf16, 32MiB
  float*  knG    = (float*)(ws);                  // [B,H,T,64] f32 (hs3 dead)
  ushort* qnG    = (ushort*)(ws + 33554432);      // [B,H,T,64] bf16, 16MiB
  ushort* obuf3  = hs3;                           // [8192,2048] bf16 (after scan)
  ushort* mMGSG  = (ushort*)(ws);                 // prep writes over knG slabs
  ushort* mWkB   = (ushort*)(ws + 33554432);      // over qnG slabs
  ushort* qkvhat = (ushort*)(ws + 50331648);      // [8192,3072] bf16, 48MiB
  float*  gate   = (float*)qkvhat;                // [8192,1024] f32 (after prep)
  ushort* oG     = (ushort*)(ws + 50331648 + 33554432);   // ws+80MiB, 16MiB
  ushort* grawB  = (ushort*)(ws + 100663296);     // [8192,1024] bf16, 16MiB
  float*  geG    = (float*)(ws + 100663296);      // over grawB (after frontend)
  float*  gObuf  = (float*)(ws + 117440512);      // [B,H,T,64] f32 g, 32MiB
  ushort* mWqBv  = (ushort*)(ws + 117440512);     // prep overwrites own slab
  char*   R4     = ws + 150994944;                // 18MiB pool
  ushort* Wqkv3  = (ushort*)R4;                   // [3072,2048] bf16, 12MiB
  ushort* Wfgb3  = (ushort*)R4;                   // [256,2048] bf16 (after qkv GEMM)
  float*  f1g1b  = (float*)(R4 + 1572864);        // [8192,256] f32, 8MiB
  ushort* f1_3   = (ushort*)(R4 + 9961472);       // [8192,128] bf16, 2MiB
  ushort* g1_3   = (ushort*)(R4 + 13107200);      // [8192,128] bf16, 2MiB
  ushort* Wf2_3  = (ushort*)(R4 + 16252928);      // [1024,128] bf16
  ushort* Wg2_3  = (ushort*)(R4 + 16646144);      // [1024,128] bf16
  ushort* Wo3    = (ushort*)R4;                   // [1024,2048] bf16 (after gate GEMM)

  dim3 blk(256);
  const int PK = 1024 * 1024;

  split_pack_A<<<dim3((M_ * 1024) / 256), blk, 0, stream>>>(hs, 1024, 1024, M_, hs3);
  pack_w3t<<<dim3(PK / 256), blk, 0, stream>>>(Wq, 1024, 1024, Wqkv3, 2048);
  pack_w3t<<<dim3(PK / 256), blk, 0, stream>>>(Wk, 1024, 1024, Wqkv3 + (size_t)1024 * 2048, 2048);
  pack_w3t<<<dim3(PK / 256), blk, 0, stream>>>(Wv, 1024, 1024, Wqkv3 + (size_t)2048 * 2048, 2048);
  gemm_split<ushort><<<dim3(M_ / 128, 3072 / 128), blk, 0, stream>>>(
      hs3, Wqkv3, nullptr, qkvhat, M_, 3072, 2048);
  hipMemsetAsync(Wfgb3, 0, (size_t)256 * 2048 * 2, stream);
  pack_w3t<<<dim3((1024 * 64) / 256), blk, 0, stream>>>(Wf1, 1024, 64, Wfgb3, 2048);
  pack_w3t<<<dim3((1024 * 64) / 256), blk, 0, stream>>>(Wg1, 1024, 64, Wfgb3 + (size_t)64 * 2048, 2048);
  pack_w3t<<<dim3((1024 * 16) / 256), blk, 0, stream>>>(Wb, 1024, 16, Wfgb3 + (size_t)128 * 2048, 2048);
  gemm_split<float><<<dim3(M_ / 128, 2), blk, 0, stream>>>(
      hs3, Wfgb3, nullptr, f1g1b, M_, 256, 2048);
  split_pack_A<<<dim3((M_ * 64) / 256), blk, 0, stream>>>(f1g1b, 256, 64, M_, f1_3);
  split_pack_A<<<dim3((M_ * 64) / 256), blk, 0, stream>>>(f1g1b + 64, 256, 64, M_, g1_3);
  pack_w3t<<<dim3((64 * 1024) / 256), blk, 0, stream>>>(Wf2, 64, 1024, Wf2_3, 128);
  gemm_split<ushort><<<dim3(M_ / 128, 1024 / 128), blk, 0, stream>>>(
      f1_3, Wf2_3, nullptr, grawB, M_, 1024, 128);

  frontend<<<dim3(M_), blk, 0, stream>>>(qkvhat, grawB, qcw, qcb, kcw, kcb,
                                         A_log, dtb, knG, qnG, gObuf);
  prep<<<dim3(64, 32), blk, 0, stream>>>(knG, qnG, gObuf, qkvhat, f1g1b,
                                         vcw, vcb, mMGSG, mWkB, mWqBv, geG);
  pack_w3t<<<dim3((64 * 1024) / 256), blk, 0, stream>>>(Wg2, 64, 1024, Wg2_3, 128);
  gemm_split<float><<<dim3(M_ / 128, 1024 / 128), blk, 0, stream>>>(
      g1_3, Wg2_3, bg2, gate, M_, 1024, 128);

  scan<<<dim3(64, 4), blk, 0, stream>>>(mMGSG, mWkB, mWqBv, geG, oG);

  onorm_pack<<<dim3((M_ * H_) / 4), blk, 0, stream>>>(oG, gate, onw, obuf3);
  pack_w3t<<<dim3(PK / 256), blk, 0, stream>>>(Wo, 1024, 1024, Wo3, 2048);
  gemm_split<float><<<dim3(M_ / 128, 1024 / 128), blk, 0, stream>>>(
      obuf3, Wo3, nullptr, out, M_, 1024, 2048);
}

// Round 9
// 760.883 us; speedup vs baseline: 4.6069x; 1.0285x over previous
//
#include <hip/hip_runtime.h>
#include <hip/hip_bf16.h>
#include <math.h>

#define H_ 16
#define HIDDEN_ 1024
#define BATCH_ 4
#define T_ 2048
#define M_ (BATCH_ * T_)   // 8192

typedef __attribute__((ext_vector_type(8))) __bf16 bf16x8;
typedef __attribute__((ext_vector_type(4))) float f32x4;

__device__ __forceinline__ float wave_sum64(float v) {
  #pragma unroll
  for (int m = 32; m >= 1; m >>= 1) v += __shfl_xor(v, m, 64);
  return v;
}
__device__ __forceinline__ float sigmoidf_(float x) { return 1.f / (1.f + expf(-x)); }
__device__ __forceinline__ float siluf_(float x) { return x / (1.f + expf(-x)); }
__device__ __forceinline__ float bf2f(ushort u) {
  unsigned int x = ((unsigned int)u) << 16;
  return __builtin_bit_cast(float, x);
}
__device__ __forceinline__ ushort f2bf(float f) {   // RNE
  unsigned int x = __builtin_bit_cast(unsigned int, f);
  unsigned int r = (x + 0x7fffu + ((x >> 16) & 1u)) >> 16;
  return (ushort)r;
}
__device__ __forceinline__ void ub4_(uint2 u, float f[4]) {
  f[0] = bf2f((ushort)u.x); f[1] = bf2f((ushort)(u.x >> 16));
  f[2] = bf2f((ushort)u.y); f[3] = bf2f((ushort)(u.y >> 16));
}
__device__ __forceinline__ uint2 pk4_(float a, float b, float c, float d) {
  return make_uint2((uint)f2bf(a) | ((uint)f2bf(b) << 16),
                    (uint)f2bf(c) | ((uint)f2bf(d) << 16));
}
__device__ __forceinline__ uint4 pk8_(const float* t) {
  uint4 r;
  r.x = (uint)f2bf(t[0]) | ((uint)f2bf(t[1]) << 16);
  r.y = (uint)f2bf(t[2]) | ((uint)f2bf(t[3]) << 16);
  r.z = (uint)f2bf(t[4]) | ((uint)f2bf(t[5]) << 16);
  r.w = (uint)f2bf(t[6]) | ((uint)f2bf(t[7]) << 16);
  return r;
}
// async global -> LDS, 16B per lane (dest: wave-uniform base + lane*16)
__device__ __forceinline__ void gl16(const ushort* g, ushort* l) {
  __builtin_amdgcn_global_load_lds(
      (const __attribute__((address_space(1))) unsigned int*)g,
      (__attribute__((address_space(3))) unsigned int*)l, 16, 0, 0);
}

// ---------------------------------------------------------------------------
// Split-pack A: f32 [M,K] -> bf16 [M,2K] as [hi | lo]  (2-term split).
// ---------------------------------------------------------------------------
__global__ __launch_bounds__(256) void split_pack_A(
    const float* __restrict__ in, int inStride, int K, int M,
    ushort* __restrict__ out) {
  size_t tid = (size_t)blockIdx.x * 256 + threadIdx.x;
  if (tid >= (size_t)M * K) return;
  int k = (int)(tid % K);
  size_t m = tid / K;
  float x = in[m * inStride + k];
  ushort hi = f2bf(x);
  float rem = x - bf2f(hi);
  ushort lo = f2bf(rem);
  size_t o = m * (size_t)(2 * K);
  out[o + k] = hi;
  out[o + K + k] = lo;
}

// ---------------------------------------------------------------------------
// Pack weight W [K,N] f32 -> transposed bf16 [n][hi|hi] (2-term: B repeated).
// ---------------------------------------------------------------------------
__global__ __launch_bounds__(256) void pack_w3t(
    const float* __restrict__ W, int K, int N,
    ushort* __restrict__ out, int rowStride) {
  size_t tid = (size_t)blockIdx.x * 256 + threadIdx.x;
  if (tid >= (size_t)K * N) return;
  int k = (int)(tid % K);
  size_t n = tid / K;
  float x = W[(size_t)k * N + n];
  ushort hi = f2bf(x);
  size_t o = n * (size_t)rowStride;
  out[o + k] = hi;
  out[o + K + k] = hi;
}

// ---------------------------------------------------------------------------
// bf16 MFMA GEMM, m97 structure: global_load_lds(16B) staging into LINEAR
// LDS [128][32], 128x128 tile, 4 waves (2x2), 16x16x32 MFMA, BK=32.
// ---------------------------------------------------------------------------
template <typename OutT>
__global__ __launch_bounds__(256) void gemm_glds(
    const ushort* __restrict__ A, const ushort* __restrict__ Bt,
    const float* __restrict__ bias, OutT* __restrict__ C,
    int M, int N, int K) {
  __shared__ ushort As[128 * 32];
  __shared__ ushort Bs[128 * 32];
  const int tid = threadIdx.x;
  const int bm = blockIdx.x * 128, bn = blockIdx.y * 128;
  const int wid = tid >> 6, lane = tid & 63;
  const int wm = (wid >> 1) * 64, wn = (wid & 1) * 64;
  const int fr = lane & 15, fq = lane >> 4;
  // staging: wave wid covers tile rows [wid*32, wid*32+32); lane -> (row,col16)
  const int srow = wid * 32 + (lane >> 2);
  const int scol = (lane & 3) * 8;              // ushort col (8 us = 16B)

  f32x4 acc[4][4] = {};

  for (int k0 = 0; k0 < K; k0 += 32) {
    const ushort* gA = A + (size_t)(bm + srow) * K + k0 + scol;
    const ushort* gB = Bt + (size_t)(bn + srow) * K + k0 + scol;
    gl16(gA, &As[(wid * 32) * 32]);
    gl16(gA + (size_t)16 * K, &As[(wid * 32 + 16) * 32]);
    gl16(gB, &Bs[(wid * 32) * 32]);
    gl16(gB + (size_t)16 * K, &Bs[(wid * 32 + 16) * 32]);
    __syncthreads();

    bf16x8 af[4], bfr[4];
    #pragma unroll
    for (int i = 0; i < 4; i++) af[i] = *(const bf16x8*)&As[(wm + i * 16 + fr) * 32 + fq * 8];
    #pragma unroll
    for (int j = 0; j < 4; j++) bfr[j] = *(const bf16x8*)&Bs[(wn + j * 16 + fr) * 32 + fq * 8];
    #pragma unroll
    for (int i = 0; i < 4; i++)
      #pragma unroll
      for (int j = 0; j < 4; j++)
        acc[i][j] = __builtin_amdgcn_mfma_f32_16x16x32_bf16(af[i], bfr[j], acc[i][j], 0, 0, 0);
    __syncthreads();
  }

  #pragma unroll
  for (int i = 0; i < 4; i++) {
    #pragma unroll
    for (int j = 0; j < 4; j++) {
      int col = bn + wn + j * 16 + fr;
      float bv = bias ? bias[col] : 0.f;
      #pragma unroll
      for (int r = 0; r < 4; r++) {
        int row = bm + wm + i * 16 + fq * 4 + r;
        float v = acc[i][j][r] + bv;
        if constexpr (sizeof(OutT) == 2) {
          ((ushort*)C)[(size_t)row * N + col] = f2bf(v);
        } else {
          ((float*)C)[(size_t)row * N + col] = v;
        }
      }
    }
  }
}

// ---------------------------------------------------------------------------
// prep v3: frontend FUSED. Per (bh, chunk) fully-parallel (grid 64 x 32).
// PH0: stage q/k bf16 slices (67 rows incl. conv halo) into LDS overlays,
//      compute conv+SiLU+L2norm -> Qt(qn)/Kt(kn); g = -A*softplus into cM.
// PH2..8 as before: cumsum, block decays, K~/K^/Q~, Wq/WkB/bv/ge outputs,
// M-build (bf16 overlay), G-solve, MG/SG. ~74.5 KB LDS -> 2 blocks/CU.
// ---------------------------------------------------------------------------
__global__ __launch_bounds__(256, 2) void prep(
    const ushort* __restrict__ qkv, const ushort* __restrict__ grawB,
    const float* __restrict__ f1g1b,
    const float* __restrict__ qcw, const float* __restrict__ qcb,
    const float* __restrict__ kcw, const float* __restrict__ kcb,
    const float* __restrict__ vcw, const float* __restrict__ vcb,
    const float* __restrict__ A_log, const float* __restrict__ dtb,
    ushort* __restrict__ mMGSG, ushort* __restrict__ mWkB,
    ushort* __restrict__ mWqBv, float* __restrict__ geG) {
  const int bh = blockIdx.x, ch = blockIdx.y;
  const int b = bh >> 4, h = bh & 15;
  const int i = bh * 32 + ch;
  const int t0 = ch * 64;
  const int tid = threadIdx.x;
  const int wA = tid >> 6, tA = tid & 63;
  const int tTh = tid >> 2, c4 = tid & 3, kb = c4 * 16;
  const int c0 = h * 64 + kb;

  __shared__ __align__(16) float Kt[64][68];    // kn -> K~ ; PH7+: G
  __shared__ __align__(16) float Kh[64][68];    // PH0: q-stage; then K^ = kn e^{d-c}
  __shared__ __align__(16) float Qt[64][68];    // qn -> Q~ ; PH7: KhE
  __shared__ __align__(16) float cM[64][68];    // PH0: k-stage; g -> cumsum; PH6+: M bf16
  __shared__ __align__(16) float dlog[17][68];
  __shared__ float betaL[64];
  ushort (*MqkT)[68] = (ushort(*)[68])&cM[0][0];
  ushort (*MkkT)[68] = (ushort(*)[68])&cM[32][0];
  float (*Gl)[68] = (float(*)[68])&Kt[0][0];

  // ---- PH0a: stage q/k bf16 slices [67][64] (rows t0-3 .. t0+63) ----
  {
    uint* bq = (uint*)&Kh[0][0];
    uint* bk = (uint*)&cM[0][0];
    for (int idx = tid; idx < 67 * 32; idx += 256) {
      int j = idx >> 5, cu = idx & 31;
      int t = t0 - 3 + j;
      uint vq = 0, vk = 0;
      if (t >= 0) {
        const uint* pq = (const uint*)(qkv + (size_t)(b * T_ + t) * 3072 + h * 64);
        const uint* pk = (const uint*)(qkv + (size_t)(b * T_ + t) * 3072 + 1024 + h * 64);
        vq = pq[cu]; vk = pk[cu];
      }
      bq[idx] = vq; bk[idx] = vk;
    }
  }
  __syncthreads();
  // ---- PH0b: conv + SiLU + L2 norm -> Qt (qn), Kt (kn) ----
  {
    const ushort* bq = (const ushort*)&Kh[0][0];
    const ushort* bk = (const ushort*)&cM[0][0];
    float qa[16], ka[16];
    #pragma unroll
    for (int u = 0; u < 16; u++) { qa[u] = qcb[c0 + u]; ka[u] = kcb[c0 + u]; }
    #pragma unroll
    for (int tap = 0; tap < 4; tap++) {
      int row = tTh + tap;      // global t = t0 + tTh - 3 + tap
      #pragma unroll
      for (int u = 0; u < 16; u++) {
        qa[u] += bf2f(bq[row * 64 + kb + u]) * qcw[(c0 + u) * 4 + tap];
        ka[u] += bf2f(bk[row * 64 + kb + u]) * kcw[(c0 + u) * 4 + tap];
      }
    }
    float sq = 0.f, sk = 0.f;
    #pragma unroll
    for (int u = 0; u < 16; u++) {
      qa[u] = siluf_(qa[u]); ka[u] = siluf_(ka[u]);
      sq += qa[u] * qa[u]; sk += ka[u] * ka[u];
    }
    sq += __shfl_xor(sq, 1, 64); sq += __shfl_xor(sq, 2, 64);
    sk += __shfl_xor(sk, 1, 64); sk += __shfl_xor(sk, 2, 64);
    float qs = 0.125f / (sqrtf(sq) + 1e-6f);
    float ks = 1.f / (sqrtf(sk) + 1e-6f);
    __syncthreads();   // staging buffers dead; cM will be overwritten with g
    #pragma unroll
    for (int u = 0; u < 16; u++) {
      Qt[tTh][kb + u] = qa[u] * qs;
      Kt[tTh][kb + u] = ka[u] * ks;
    }
  }
  // ---- PH0c: g = -A*softplus(graw+dtb) -> cM; beta ----
  {
    float Aexp = expf(A_log[h]);
    const ushort* gr = grawB + (size_t)(b * T_ + t0 + tTh) * 1024 + c0;
    uint4 ga = *(const uint4*)gr;
    uint4 gb = *(const uint4*)(gr + 8);
    float xv[16];
    xv[0] = bf2f((ushort)ga.x); xv[1] = bf2f((ushort)(ga.x >> 16));
    xv[2] = bf2f((ushort)ga.y); xv[3] = bf2f((ushort)(ga.y >> 16));
    xv[4] = bf2f((ushort)ga.z); xv[5] = bf2f((ushort)(ga.z >> 16));
    xv[6] = bf2f((ushort)ga.w); xv[7] = bf2f((ushort)(ga.w >> 16));
    xv[8] = bf2f((ushort)gb.x); xv[9] = bf2f((ushort)(gb.x >> 16));
    xv[10] = bf2f((ushort)gb.y); xv[11] = bf2f((ushort)(gb.y >> 16));
    xv[12] = bf2f((ushort)gb.z); xv[13] = bf2f((ushort)(gb.z >> 16));
    xv[14] = bf2f((ushort)gb.w); xv[15] = bf2f((ushort)(gb.w >> 16));
    #pragma unroll
    for (int u = 0; u < 16; u++) {
      float x = xv[u] + dtb[c0 + u];
      float sp = (x > 20.f) ? x : log1pf(expf(x));
      cM[tTh][kb + u] = -Aexp * sp;
    }
    if (tid < 64)
      betaL[tid] = sigmoidf_(f1g1b[(size_t)(b * T_ + t0 + tid) * 256 + 128 + h]);
  }
  __syncthreads();
  // ---- PH2: cumsum within quarters ----
  {
    const int q = wA, k = tA;
    float run = 0.f;
    #pragma unroll
    for (int u = 0; u < 16; u++) { run += cM[q * 16 + u][k]; cM[q * 16 + u][k] = run; }
    dlog[q][k] = run;
  }
  __syncthreads();
  // ---- PH3: apply segment offsets ----
  {
    const int q = wA, k = tA;
    if (q > 0) {
      float off = dlog[0][k];
      if (q > 1) off += dlog[1][k];
      if (q > 2) off += dlog[2][k];
      #pragma unroll
      for (int u = 0; u < 16; u++) cM[q * 16 + u][k] += off;
    }
  }
  __syncthreads();
  // ---- PH4: block-base log decays ----
  for (int idx = tid; idx < 17 * 64; idx += 256) {
    int P = idx >> 6, k = idx & 63;
    dlog[P][k] = (P == 0) ? 0.f : cM[4 * P - 1][k];
  }
  __syncthreads();
  // ---- PH5: K~/K^/Q~ in place (cM dead after this) ----
  {
    const int P5 = tTh >> 2;
    #pragma unroll
    for (int u = 0; u < 16; u++) {
      int k = kb + u;
      float kn = Kt[tTh][k], qn = Qt[tTh][k];
      float c = cM[tTh][k], d = dlog[P5][k];
      float e1 = expf(c - d);
      float e2 = expf(d - c);
      Kt[tTh][k] = kn * e1;
      Kh[tTh][k] = kn * e2;
      Qt[tTh][k] = qn * e1;
    }
  }
  __syncthreads();
  // ---- PH6: Wq/WkB/bv/ge outputs + M-build (bf16 into cM overlay) ----
  {
    const int P = tTh >> 2;
    float bt = betaL[tTh];
    float tq[16], tk[16];
    #pragma unroll
    for (int u = 0; u < 16; u++) {
      int k = kb + u;
      float e = expf(dlog[P][k]);
      tq[u] = Qt[tTh][k] * e;
      tk[u] = bt * Kt[tTh][k] * e;
    }
    ushort* pq = mWqBv + (size_t)i * 8192 + tTh * 64 + kb;
    ushort* pk = mWkB + (size_t)i * 4096 + tTh * 64 + kb;
    *(uint4*)&pq[0] = pk8_(&tq[0]);
    *(uint4*)&pq[8] = pk8_(&tq[8]);
    *(uint4*)&pk[0] = pk8_(&tk[0]);
    *(uint4*)&pk[8] = pk8_(&tk[8]);

    float av[16];
    #pragma unroll
    for (int u = 0; u < 16; u++) av[u] = vcb[h * 64 + kb + u];
    #pragma unroll
    for (int tap = 0; tap < 4; tap++) {
      int tr = t0 + tTh - 3 + tap;
      if (tr >= 0) {
        const ushort* vp = qkv + (size_t)(b * T_ + tr) * 3072 + 2048 + h * 64 + kb;
        uint4 va = *(const uint4*)vp;
        uint4 vb2 = *(const uint4*)(vp + 8);
        float xv[16];
        xv[0] = bf2f((ushort)va.x); xv[1] = bf2f((ushort)(va.x >> 16));
        xv[2] = bf2f((ushort)va.y); xv[3] = bf2f((ushort)(va.y >> 16));
        xv[4] = bf2f((ushort)va.z); xv[5] = bf2f((ushort)(va.z >> 16));
        xv[6] = bf2f((ushort)va.w); xv[7] = bf2f((ushort)(va.w >> 16));
        xv[8] = bf2f((ushort)vb2.x); xv[9] = bf2f((ushort)(vb2.x >> 16));
        xv[10] = bf2f((ushort)vb2.y); xv[11] = bf2f((ushort)(vb2.y >> 16));
        xv[12] = bf2f((ushort)vb2.z); xv[13] = bf2f((ushort)(vb2.z >> 16));
        xv[14] = bf2f((ushort)vb2.w); xv[15] = bf2f((ushort)(vb2.w >> 16));
        #pragma unroll
        for (int u = 0; u < 16; u++)
          av[u] += xv[u] * vcw[(h * 64 + kb + u) * 4 + tap];
      }
    }
    #pragma unroll
    for (int u = 0; u < 16; u++) av[u] = bt * siluf_(av[u]);
    ushort* pb = mWqBv + (size_t)i * 8192 + 4096 + tTh * 64 + kb;
    *(uint4*)&pb[0] = pk8_(&av[0]);
    *(uint4*)&pb[8] = pk8_(&av[8]);

    if (tid < 64) geG[(size_t)i * 64 + tid] = expf(dlog[16][tid]);

    // M-build: 272 4x4 tiles, R recomputed on the fly (all exponents <= 0)
    for (int tile = tid; tile < 272; tile += 256) {
      int mq = (tile >= 136) ? 1 : 0;
      int f = tile - mq * 136;
      int rem = f, P2 = 0;
      while (rem >= P2 + 1) { rem -= P2 + 1; ++P2; }
      int J = rem;
      const float (*Xr)[68] = mq ? Qt : Kt;
      float acc[4][4] = {};
      for (int kc = 0; kc < 16; kc++) {
        float4 avv[4];
        #pragma unroll
        for (int r = 0; r < 4; r++) avv[r] = *(const float4*)&Xr[4 * P2 + r][kc * 4];
        float4 dp = *(const float4*)&dlog[P2][kc * 4];
        float4 dj = *(const float4*)&dlog[J][kc * 4];
        float4 rv = make_float4(expf(dp.x - dj.x), expf(dp.y - dj.y),
                                expf(dp.z - dj.z), expf(dp.w - dj.w));
        #pragma unroll
        for (int c = 0; c < 4; c++) {
          float4 kvv = *(const float4*)&Kh[4 * J + c][kc * 4];
          float bx = kvv.x * rv.x, by = kvv.y * rv.y, bz = kvv.z * rv.z, bw = kvv.w * rv.w;
          #pragma unroll
          for (int r = 0; r < 4; r++)
            acc[r][c] += avv[r].x * bx + avv[r].y * by + avv[r].z * bz + avv[r].w * bw;
        }
      }
      if (mq && P2 == J) {
        #pragma unroll
        for (int c = 0; c < 4; c++)
          #pragma unroll
          for (int r = 0; r < 4; r++)
            if (c > r) acc[r][c] = 0.f;
      }
      ushort (*MT)[68] = mq ? MqkT : MkkT;
      #pragma unroll
      for (int c = 0; c < 4; c++) {
        uint2 w;
        w.x = (uint)f2bf(acc[0][c]) | ((uint)f2bf(acc[1][c]) << 16);
        w.y = (uint)f2bf(acc[2][c]) | ((uint)f2bf(acc[3][c]) << 16);
        *(uint2*)&MT[4 * J + c][4 * P2] = w;
      }
    }
  }
  __syncthreads();
  // ---- PH7: KhE into Qt + G-solve (G overlays dead Kt) ----
  for (int idx = tid; idx < 4096; idx += 256) {
    int s = idx >> 6, k = idx & 63;
    Qt[s][k] = Kh[s][k] * expf(dlog[16][k] - dlog[s >> 2][k]);
  }
  {
    const int j = tTh, q = c4;
    float acc[16], gsv[16];
    #pragma unroll
    for (int u = 0; u < 16; u++) { acc[u] = 0.f; gsv[u] = 0.f; }
    for (int s = 0; s < 64; s++) {
      int q0 = s >> 4;
      float g = 0.f;
      if (q == q0) {
        g = ((s == j) ? 1.f : 0.f) - betaL[s] * acc[s & 15];
        gsv[s & 15] = g;
      }
      g = __shfl(g, 4 * (j & 15) + q0, 64);
      #pragma unroll
      for (int u = 0; u < 4; u++) {
        uint2 m2 = *(const uint2*)&MkkT[s][q * 16 + u * 4];
        acc[u * 4 + 0] += bf2f((ushort)m2.x) * g;
        acc[u * 4 + 1] += bf2f((ushort)(m2.x >> 16)) * g;
        acc[u * 4 + 2] += bf2f((ushort)m2.y) * g;
        acc[u * 4 + 3] += bf2f((ushort)(m2.y >> 16)) * g;
      }
    }
    #pragma unroll
    for (int u = 0; u < 16; u++) Gl[q * 16 + u][j] = gsv[u];
  }
  __syncthreads();
  // ---- PH8: MG = tril(Mqk)@G, SG = KhE^T@G, write bf16 ----
  {
    float o[16];
    #pragma unroll
    for (int u = 0; u < 16; u++) o[u] = 0.f;
    for (int s = 0; s <= tTh; s++) {
      float m = bf2f(MqkT[s][tTh]);
      #pragma unroll
      for (int u = 0; u < 4; u++) {
        float4 g4 = *(const float4*)&Gl[s][kb + u * 4];
        o[u * 4 + 0] += m * g4.x; o[u * 4 + 1] += m * g4.y;
        o[u * 4 + 2] += m * g4.z; o[u * 4 + 3] += m * g4.w;
      }
    }
    ushort* pm = mMGSG + (size_t)i * 8192 + tTh * 64 + kb;
    *(uint4*)&pm[0] = pk8_(&o[0]);
    *(uint4*)&pm[8] = pk8_(&o[8]);

    #pragma unroll
    for (int u = 0; u < 16; u++) o[u] = 0.f;
    for (int s = 0; s < 64; s++) {
      float m = Qt[s][tTh];
      #pragma unroll
      for (int u = 0; u < 4; u++) {
        float4 g4 = *(const float4*)&Gl[s][kb + u * 4];
        o[u * 4 + 0] += m * g4.x; o[u * 4 + 1] += m * g4.y;
        o[u * 4 + 2] += m * g4.z; o[u * 4 + 3] += m * g4.w;
      }
    }
    ushort* ps = mMGSG + (size_t)i * 8192 + 4096 + tTh * 64 + kb;
    *(uint4*)&ps[0] = pk8_(&o[0]);
    *(uint4*)&ps[8] = pk8_(&o[8]);
  }
}

// ---------------------------------------------------------------------------
// scan: sequential-over-chunks state propagation. Grid (64 bh, 4 vq).
// Per chunk: r = bv - WkB@S; O = MG@r + Wq@S; S = ge*S + SG@r.
// ---------------------------------------------------------------------------
__global__ __launch_bounds__(256) void scan(
    const ushort* __restrict__ mMGSG, const ushort* __restrict__ mWkB,
    const ushort* __restrict__ mWqBv, const float* __restrict__ geG,
    ushort* __restrict__ oG) {
  const int bh = blockIdx.x, vq = blockIdx.y;
  const int tid = threadIdx.x;
  const int tTh = tid >> 2, c4 = tid & 3, lvi = c4 * 4;
  const int r0 = tid >> 2, cc = (tid & 3) * 16;

  __shared__ ushort MGs[64][72], SGs[64][72], WkBs[64][72], Wqs[64][72];
  __shared__ __align__(16) float Sl[64][20], rl[64][20];
  __shared__ float geL[64];

  *(float4*)&Sl[tTh][lvi] = make_float4(0.f, 0.f, 0.f, 0.f);

  const size_t i0 = (size_t)bh * 32;
  {
    uint4 a0 = *(const uint4*)&mMGSG[i0 * 8192 + tid * 16];
    uint4 a1 = *(const uint4*)&mMGSG[i0 * 8192 + tid * 16 + 8];
    uint4 b0 = *(const uint4*)&mMGSG[i0 * 8192 + 4096 + tid * 16];
    uint4 b1 = *(const uint4*)&mMGSG[i0 * 8192 + 4096 + tid * 16 + 8];
    uint4 c0 = *(const uint4*)&mWkB[i0 * 4096 + tid * 16];
    uint4 c1 = *(const uint4*)&mWkB[i0 * 4096 + tid * 16 + 8];
    uint4 d0 = *(const uint4*)&mWqBv[i0 * 8192 + tid * 16];
    uint4 d1 = *(const uint4*)&mWqBv[i0 * 8192 + tid * 16 + 8];
    *(uint4*)&MGs[r0][cc] = a0;  *(uint4*)&MGs[r0][cc + 8] = a1;
    *(uint4*)&SGs[r0][cc] = b0;  *(uint4*)&SGs[r0][cc + 8] = b1;
    *(uint4*)&WkBs[r0][cc] = c0; *(uint4*)&WkBs[r0][cc + 8] = c1;
    *(uint4*)&Wqs[r0][cc] = d0;  *(uint4*)&Wqs[r0][cc + 8] = d1;
    if (tid < 64) geL[tid] = geG[i0 * 64 + tid];
  }
  uint2 bvCur = *(const uint2*)&mWqBv[i0 * 8192 + 4096 + tTh * 64 + vq * 16 + lvi];
  __syncthreads();

  for (int ch = 0; ch < 32; ch++) {
    const size_t i = i0 + ch;
    uint4 p0, p1, p2, p3, p4, p5, p6, p7;
    uint2 pbv;
    float pge = 0.f;
    if (ch < 31) {
      const size_t i2 = i + 1;
      p0 = *(const uint4*)&mMGSG[i2 * 8192 + tid * 16];
      p1 = *(const uint4*)&mMGSG[i2 * 8192 + tid * 16 + 8];
      p2 = *(const uint4*)&mMGSG[i2 * 8192 + 4096 + tid * 16];
      p3 = *(const uint4*)&mMGSG[i2 * 8192 + 4096 + tid * 16 + 8];
      p4 = *(const uint4*)&mWkB[i2 * 4096 + tid * 16];
      p5 = *(const uint4*)&mWkB[i2 * 4096 + tid * 16 + 8];
      p6 = *(const uint4*)&mWqBv[i2 * 8192 + tid * 16];
      p7 = *(const uint4*)&mWqBv[i2 * 8192 + tid * 16 + 8];
      pbv = *(const uint2*)&mWqBv[i2 * 8192 + 4096 + tTh * 64 + vq * 16 + lvi];
      if (tid < 64) pge = geG[i2 * 64 + tid];
    }
    float rv[4];
    ub4_(bvCur, rv);
    #pragma unroll
    for (int kc = 0; kc < 16; kc++) {
      float w4[4];
      ub4_(*(const uint2*)&WkBs[tTh][kc * 4], w4);
      #pragma unroll
      for (int jj = 0; jj < 4; jj++) {
        float4 s4 = *(const float4*)&Sl[kc * 4 + jj][lvi];
        rv[0] -= w4[jj] * s4.x; rv[1] -= w4[jj] * s4.y;
        rv[2] -= w4[jj] * s4.z; rv[3] -= w4[jj] * s4.w;
      }
    }
    *(float4*)&rl[tTh][lvi] = make_float4(rv[0], rv[1], rv[2], rv[3]);
    __syncthreads();
    {
      float ov[4] = {0.f, 0.f, 0.f, 0.f};
      #pragma unroll
      for (int sc = 0; sc < 16; sc++) {
        float m4[4];
        ub4_(*(const uint2*)&MGs[tTh][sc * 4], m4);
        #pragma unroll
        for (int jj = 0; jj < 4; jj++) {
          float4 r4 = *(const float4*)&rl[sc * 4 + jj][lvi];
          ov[0] += m4[jj] * r4.x; ov[1] += m4[jj] * r4.y;
          ov[2] += m4[jj] * r4.z; ov[3] += m4[jj] * r4.w;
        }
      }
      #pragma unroll
      for (int kc = 0; kc < 16; kc++) {
        float q4[4];
        ub4_(*(const uint2*)&Wqs[tTh][kc * 4], q4);
        #pragma unroll
        for (int jj = 0; jj < 4; jj++) {
          float4 s4 = *(const float4*)&Sl[kc * 4 + jj][lvi];
          ov[0] += q4[jj] * s4.x; ov[1] += q4[jj] * s4.y;
          ov[2] += q4[jj] * s4.z; ov[3] += q4[jj] * s4.w;
        }
      }
      *(uint2*)&oG[i * 4096 + tTh * 64 + vq * 16 + lvi] =
          pk4_(ov[0], ov[1], ov[2], ov[3]);
    }
    __syncthreads();
    {
      float4 s4 = *(const float4*)&Sl[tTh][lvi];
      float ge = geL[tTh];
      float sv[4] = {ge * s4.x, ge * s4.y, ge * s4.z, ge * s4.w};
      #pragma unroll
      for (int sc = 0; sc < 16; sc++) {
        float g4[4];
        ub4_(*(const uint2*)&SGs[tTh][sc * 4], g4);
        #pragma unroll
        for (int jj = 0; jj < 4; jj++) {
          float4 r4 = *(const float4*)&rl[sc * 4 + jj][lvi];
          sv[0] += g4[jj] * r4.x; sv[1] += g4[jj] * r4.y;
          sv[2] += g4[jj] * r4.z; sv[3] += g4[jj] * r4.w;
        }
      }
      *(float4*)&Sl[tTh][lvi] = make_float4(sv[0], sv[1], sv[2], sv[3]);
    }
    __syncthreads();
    if (ch < 31) {
      *(uint4*)&MGs[r0][cc] = p0;  *(uint4*)&MGs[r0][cc + 8] = p1;
      *(uint4*)&SGs[r0][cc] = p2;  *(uint4*)&SGs[r0][cc + 8] = p3;
      *(uint4*)&WkBs[r0][cc] = p4; *(uint4*)&WkBs[r0][cc + 8] = p5;
      *(uint4*)&Wqs[r0][cc] = p6;  *(uint4*)&Wqs[r0][cc + 8] = p7;
      if (tid < 64) geL[tid] = pge;
      bvCur = pbv;
      __syncthreads();
    }
  }
}

// ---------------------------------------------------------------------------
// RMS-norm + gate + split-pack into [hi|lo] bf16 GEMM operand.
// ---------------------------------------------------------------------------
__global__ __launch_bounds__(256) void onorm_pack(
    const ushort* __restrict__ o, const float* __restrict__ gate,
    const float* __restrict__ onw, ushort* __restrict__ out3) {
  int gi = blockIdx.x * 4 + (threadIdx.x >> 6);
  int lane = threadIdx.x & 63;
  int b = gi >> 15, h = (gi >> 11) & 15, t = gi & 2047;
  float ov = bf2f(o[(size_t)gi * 64 + lane]);
  float ms = wave_sum64(ov * ov) * (1.f / 64.f);
  float r = rsqrtf(ms + 1e-5f);
  float gv = gate[(size_t)(b * T_ + t) * 1024 + h * 64 + lane];
  float val = ov * r * onw[lane] * sigmoidf_(gv);
  ushort hi = f2bf(val);
  float rem = val - bf2f(hi);
  ushort lo = f2bf(rem);
  size_t m = (size_t)(b * T_ + t);
  int c = h * 64 + lane;
  out3[m * 2048 + c] = hi;
  out3[m * 2048 + 1024 + c] = lo;
}

extern "C" void kernel_launch(void* const* d_in, const int* in_sizes, int n_in,
                              void* d_out, int out_size, void* d_ws, size_t ws_size,
                              hipStream_t stream) {
  const float* hs    = (const float*)d_in[0];
  const float* Wq    = (const float*)d_in[1];
  const float* Wk    = (const float*)d_in[2];
  const float* Wv    = (const float*)d_in[3];
  const float* qcw   = (const float*)d_in[4];
  const float* qcb   = (const float*)d_in[5];
  const float* kcw   = (const float*)d_in[6];
  const float* kcb   = (const float*)d_in[7];
  const float* vcw   = (const float*)d_in[8];
  const float* vcb   = (const float*)d_in[9];
  const float* Wf1   = (const float*)d_in[10];
  const float* Wf2   = (const float*)d_in[11];
  const float* Wb    = (const float*)d_in[12];
  const float* A_log = (const float*)d_in[13];
  const float* dtb   = (const float*)d_in[14];
  const float* Wg1   = (const float*)d_in[15];
  const float* Wg2   = (const float*)d_in[16];
  const float* bg2   = (const float*)d_in[17];
  const float* onw   = (const float*)d_in[18];
  const float* Wo    = (const float*)d_in[19];
  float* out = (float*)d_out;

  char* ws = (char*)d_ws;
  // [0,32M):    hs3 -> mMGSG (after fgb GEMM) -> obuf3 (after scan)
  // [32,48M):   mWkB
  // [48,96M):   qkvhat (48M) -> gate f32 [48,80M) + oG bf16 [80,96M) after prep
  // [96,112M):  grawB (alive through prep)
  // [112,144.5M): geG (0.5M) + mWqBv (32M)
  // [144.5,162.5M): R4 pool
  ushort* hs3    = (ushort*)(ws);
  ushort* mMGSG  = (ushort*)(ws);
  ushort* obuf3  = (ushort*)(ws);
  ushort* mWkB   = (ushort*)(ws + 33554432);
  ushort* qkvhat = (ushort*)(ws + 50331648);
  float*  gate   = (float*)qkvhat;
  ushort* oG     = (ushort*)(ws + 83886080);
  ushort* grawB  = (ushort*)(ws + 100663296);
  float*  geG    = (float*)(ws + 117440512);
  ushort* mWqBv  = (ushort*)(ws + 117964800);
  char*   R4     = ws + 151519232;
  ushort* Wqkv3  = (ushort*)R4;
  ushort* Wfgb3  = (ushort*)R4;
  float*  f1g1b  = (float*)(R4 + 1572864);
  ushort* f1_3   = (ushort*)(R4 + 9961472);
  ushort* g1_3   = (ushort*)(R4 + 13107200);
  ushort* Wf2_3  = (ushort*)(R4 + 16252928);
  ushort* Wg2_3  = (ushort*)(R4 + 16646144);
  ushort* Wo3    = (ushort*)R4;

  dim3 blk(256);
  const int PK = 1024 * 1024;

  split_pack_A<<<dim3((M_ * 1024) / 256), blk, 0, stream>>>(hs, 1024, 1024, M_, hs3);
  pack_w3t<<<dim3(PK / 256), blk, 0, stream>>>(Wq, 1024, 1024, Wqkv3, 2048);
  pack_w3t<<<dim3(PK / 256), blk, 0, stream>>>(Wk, 1024, 1024, Wqkv3 + (size_t)1024 * 2048, 2048);
  pack_w3t<<<dim3(PK / 256), blk, 0, stream>>>(Wv, 1024, 1024, Wqkv3 + (size_t)2048 * 2048, 2048);
  gemm_glds<ushort><<<dim3(M_ / 128, 3072 / 128), blk, 0, stream>>>(
      hs3, Wqkv3, nullptr, qkvhat, M_, 3072, 2048);
  hipMemsetAsync(Wfgb3, 0, (size_t)256 * 2048 * 2, stream);
  pack_w3t<<<dim3((1024 * 64) / 256), blk, 0, stream>>>(Wf1, 1024, 64, Wfgb3, 2048);
  pack_w3t<<<dim3((1024 * 64) / 256), blk, 0, stream>>>(Wg1, 1024, 64, Wfgb3 + (size_t)64 * 2048, 2048);
  pack_w3t<<<dim3((1024 * 16) / 256), blk, 0, stream>>>(Wb, 1024, 16, Wfgb3 + (size_t)128 * 2048, 2048);
  gemm_glds<float><<<dim3(M_ / 128, 2), blk, 0, stream>>>(
      hs3, Wfgb3, nullptr, f1g1b, M_, 256, 2048);
  split_pack_A<<<dim3((M_ * 64) / 256), blk, 0, stream>>>(f1g1b, 256, 64, M_, f1_3);
  split_pack_A<<<dim3((M_ * 64) / 256), blk, 0, stream>>>(f1g1b + 64, 256, 64, M_, g1_3);
  pack_w3t<<<dim3((64 * 1024) / 256), blk, 0, stream>>>(Wf2, 64, 1024, Wf2_3, 128);
  gemm_glds<ushort><<<dim3(M_ / 128, 1024 / 128), blk, 0, stream>>>(
      f1_3, Wf2_3, nullptr, grawB, M_, 1024, 128);

  prep<<<dim3(64, 32), blk, 0, stream>>>(qkvhat, grawB, f1g1b,
                                         qcw, qcb, kcw, kcb, vcw, vcb,
                                         A_log, dtb, mMGSG, mWkB, mWqBv, geG);
  pack_w3t<<<dim3((64 * 1024) / 256), blk, 0, stream>>>(Wg2, 64, 1024, Wg2_3, 128);
  gemm_glds<float><<<dim3(M_ / 128, 1024 / 128), blk, 0, stream>>>(
      g1_3, Wg2_3, bg2, gate, M_, 1024, 128);

  scan<<<dim3(64, 4), blk, 0, stream>>>(mMGSG, mWkB, mWqBv, geG, oG);

  onorm_pack<<<dim3((M_ * H_) / 4), blk, 0, stream>>>(oG, gate, onw, obuf3);
  pack_w3t<<<dim3(PK / 256), blk, 0, stream>>>(Wo, 1024, 1024, Wo3, 2048);
  gemm_glds<float><<<dim3(M_ / 128, 1024 / 128), blk, 0, stream>>>(
      obuf3, Wo3, nullptr, out, M_, 1024, 2048);
}

// Round 10
// 752.633 us; speedup vs baseline: 4.6574x; 1.0110x over previous
//
#include <hip/hip_runtime.h>
#include <hip/hip_bf16.h>
#include <math.h>

#define H_ 16
#define HIDDEN_ 1024
#define BATCH_ 4
#define T_ 2048
#define M_ (BATCH_ * T_)   // 8192

typedef __attribute__((ext_vector_type(8))) __bf16 bf16x8;
typedef __attribute__((ext_vector_type(4))) float f32x4;

__device__ __forceinline__ float wave_sum64(float v) {
  #pragma unroll
  for (int m = 32; m >= 1; m >>= 1) v += __shfl_xor(v, m, 64);
  return v;
}
__device__ __forceinline__ float sigmoidf_(float x) { return 1.f / (1.f + expf(-x)); }
__device__ __forceinline__ float siluf_(float x) { return x / (1.f + expf(-x)); }
__device__ __forceinline__ float bf2f(ushort u) {
  unsigned int x = ((unsigned int)u) << 16;
  return __builtin_bit_cast(float, x);
}
__device__ __forceinline__ ushort f2bf(float f) {   // RNE
  unsigned int x = __builtin_bit_cast(unsigned int, f);
  unsigned int r = (x + 0x7fffu + ((x >> 16) & 1u)) >> 16;
  return (ushort)r;
}
__device__ __forceinline__ void ub4_(uint2 u, float f[4]) {
  f[0] = bf2f((ushort)u.x); f[1] = bf2f((ushort)(u.x >> 16));
  f[2] = bf2f((ushort)u.y); f[3] = bf2f((ushort)(u.y >> 16));
}
__device__ __forceinline__ uint2 pk4_(float a, float b, float c, float d) {
  return make_uint2((uint)f2bf(a) | ((uint)f2bf(b) << 16),
                    (uint)f2bf(c) | ((uint)f2bf(d) << 16));
}
__device__ __forceinline__ uint4 pk8_(const float* t) {
  uint4 r;
  r.x = (uint)f2bf(t[0]) | ((uint)f2bf(t[1]) << 16);
  r.y = (uint)f2bf(t[2]) | ((uint)f2bf(t[3]) << 16);
  r.z = (uint)f2bf(t[4]) | ((uint)f2bf(t[5]) << 16);
  r.w = (uint)f2bf(t[6]) | ((uint)f2bf(t[7]) << 16);
  return r;
}
// async global -> LDS, 16B per lane (dest: wave-uniform base + lane*16)
__device__ __forceinline__ void gl16(const ushort* g, ushort* l) {
  __builtin_amdgcn_global_load_lds(
      (const __attribute__((address_space(1))) unsigned int*)g,
      (__attribute__((address_space(3))) unsigned int*)l, 16, 0, 0);
}

// ---------------------------------------------------------------------------
// Split-pack A: f32 [M,K] -> bf16 [M,2K] as [hi | lo]  (2-term split).
// ---------------------------------------------------------------------------
__global__ __launch_bounds__(256) void split_pack_A(
    const float* __restrict__ in, int inStride, int K, int M,
    ushort* __restrict__ out) {
  size_t tid = (size_t)blockIdx.x * 256 + threadIdx.x;
  if (tid >= (size_t)M * K) return;
  int k = (int)(tid % K);
  size_t m = tid / K;
  float x = in[m * inStride + k];
  ushort hi = f2bf(x);
  float rem = x - bf2f(hi);
  ushort lo = f2bf(rem);
  size_t o = m * (size_t)(2 * K);
  out[o + k] = hi;
  out[o + K + k] = lo;
}

// ---------------------------------------------------------------------------
// Pack weight W [K,N] f32 -> transposed bf16 [n][hi|hi] (2-term: B repeated).
// ---------------------------------------------------------------------------
__global__ __launch_bounds__(256) void pack_w3t(
    const float* __restrict__ W, int K, int N,
    ushort* __restrict__ out, int rowStride) {
  size_t tid = (size_t)blockIdx.x * 256 + threadIdx.x;
  if (tid >= (size_t)K * N) return;
  int k = (int)(tid % K);
  size_t n = tid / K;
  float x = W[(size_t)k * N + n];
  ushort hi = f2bf(x);
  size_t o = n * (size_t)rowStride;
  out[o + k] = hi;
  out[o + K + k] = hi;
}

// ---------------------------------------------------------------------------
// bf16 MFMA GEMM, m97 structure: global_load_lds(16B) staging into LINEAR
// LDS [128][32], 128x128 tile, 4 waves (2x2), 16x16x32 MFMA, BK=32.
// ---------------------------------------------------------------------------
template <typename OutT>
__global__ __launch_bounds__(256) void gemm_glds(
    const ushort* __restrict__ A, const ushort* __restrict__ Bt,
    const float* __restrict__ bias, OutT* __restrict__ C,
    int M, int N, int K) {
  __shared__ ushort As[128 * 32];
  __shared__ ushort Bs[128 * 32];
  const int tid = threadIdx.x;
  const int bm = blockIdx.x * 128, bn = blockIdx.y * 128;
  const int wid = tid >> 6, lane = tid & 63;
  const int wm = (wid >> 1) * 64, wn = (wid & 1) * 64;
  const int fr = lane & 15, fq = lane >> 4;
  const int srow = wid * 32 + (lane >> 2);
  const int scol = (lane & 3) * 8;

  f32x4 acc[4][4] = {};

  for (int k0 = 0; k0 < K; k0 += 32) {
    const ushort* gA = A + (size_t)(bm + srow) * K + k0 + scol;
    const ushort* gB = Bt + (size_t)(bn + srow) * K + k0 + scol;
    gl16(gA, &As[(wid * 32) * 32]);
    gl16(gA + (size_t)16 * K, &As[(wid * 32 + 16) * 32]);
    gl16(gB, &Bs[(wid * 32) * 32]);
    gl16(gB + (size_t)16 * K, &Bs[(wid * 32 + 16) * 32]);
    __syncthreads();

    bf16x8 af[4], bfr[4];
    #pragma unroll
    for (int i = 0; i < 4; i++) af[i] = *(const bf16x8*)&As[(wm + i * 16 + fr) * 32 + fq * 8];
    #pragma unroll
    for (int j = 0; j < 4; j++) bfr[j] = *(const bf16x8*)&Bs[(wn + j * 16 + fr) * 32 + fq * 8];
    #pragma unroll
    for (int i = 0; i < 4; i++)
      #pragma unroll
      for (int j = 0; j < 4; j++)
        acc[i][j] = __builtin_amdgcn_mfma_f32_16x16x32_bf16(af[i], bfr[j], acc[i][j], 0, 0, 0);
    __syncthreads();
  }

  #pragma unroll
  for (int i = 0; i < 4; i++) {
    #pragma unroll
    for (int j = 0; j < 4; j++) {
      int col = bn + wn + j * 16 + fr;
      float bv = bias ? bias[col] : 0.f;
      #pragma unroll
      for (int r = 0; r < 4; r++) {
        int row = bm + wm + i * 16 + fq * 4 + r;
        float v = acc[i][j][r] + bv;
        if constexpr (sizeof(OutT) == 2) {
          ((ushort*)C)[(size_t)row * N + col] = f2bf(v);
        } else {
          ((float*)C)[(size_t)row * N + col] = v;
        }
      }
    }
  }
}

// unpack element u (0..15) from a 4-row packed conv window x[8] (2 uint4/row)
#define XROW(x, tap, u) \
  bf2f((ushort)(((u) & 1) ? (((const uint*)&(x)[(tap) * 2 + ((u) >> 3)])[((u) >> 1) & 3] >> 16) \
                          : ((const uint*)&(x)[(tap) * 2 + ((u) >> 3)])[((u) >> 1) & 3]))
#define TAPW(w, tap) ((tap) == 0 ? (w).x : (tap) == 1 ? (w).y : (tap) == 2 ? (w).z : (w).w)

// ---------------------------------------------------------------------------
// prep v4: frontend fused via DIRECT-GLOBAL vector conv (no LDS staging —
// R9's staged version cost 128 scalar ds_read_u16/thread, +107us).
// Per (bh, chunk) fully-parallel (grid 64 x 32), ~74.5 KB LDS, 2 blocks/CU.
// ---------------------------------------------------------------------------
__global__ __launch_bounds__(256, 2) void prep(
    const ushort* __restrict__ qkv, const ushort* __restrict__ grawB,
    const float* __restrict__ f1g1b,
    const float* __restrict__ qcw, const float* __restrict__ qcb,
    const float* __restrict__ kcw, const float* __restrict__ kcb,
    const float* __restrict__ vcw, const float* __restrict__ vcb,
    const float* __restrict__ A_log, const float* __restrict__ dtb,
    ushort* __restrict__ mMGSG, ushort* __restrict__ mWkB,
    ushort* __restrict__ mWqBv, float* __restrict__ geG) {
  const int bh = blockIdx.x, ch = blockIdx.y;
  const int b = bh >> 4, h = bh & 15;
  const int i = bh * 32 + ch;
  const int t0 = ch * 64;
  const int tid = threadIdx.x;
  const int wA = tid >> 6, tA = tid & 63;
  const int tTh = tid >> 2, c4 = tid & 3, kb = c4 * 16;
  const int c0 = h * 64 + kb;

  __shared__ __align__(16) float Kt[64][68];    // kn -> K~ ; PH7+: G
  __shared__ __align__(16) float Kh[64][68];    // K^ = kn e^{d-c}
  __shared__ __align__(16) float Qt[64][68];    // qn -> Q~ ; PH7: KhE
  __shared__ __align__(16) float cM[64][68];    // g -> cumsum; PH6+: M bf16
  __shared__ __align__(16) float dlog[17][68];
  __shared__ float betaL[64];
  ushort (*MqkT)[68] = (ushort(*)[68])&cM[0][0];
  ushort (*MkkT)[68] = (ushort(*)[68])&cM[32][0];
  float (*Gl)[68] = (float(*)[68])&Kt[0][0];

  // ---- PH0: conv+SiLU+norm for q,k straight from global (vector loads) ----
  {
    const uint4 z4 = make_uint4(0, 0, 0, 0);
    // q
    {
      uint4 x[8];
      #pragma unroll
      for (int tap = 0; tap < 4; tap++) {
        int tr = t0 + tTh - 3 + tap;
        if (tr >= 0) {
          const uint4* p = (const uint4*)(qkv + (size_t)(b * T_ + tr) * 3072 + c0);
          x[tap * 2] = p[0]; x[tap * 2 + 1] = p[1];
        } else { x[tap * 2] = z4; x[tap * 2 + 1] = z4; }
      }
      float qa[16], s = 0.f;
      #pragma unroll
      for (int u = 0; u < 16; u++) {
        float4 w = ((const float4*)qcw)[c0 + u];
        float a = qcb[c0 + u];
        #pragma unroll
        for (int tap = 0; tap < 4; tap++) a += XROW(x, tap, u) * TAPW(w, tap);
        a = siluf_(a);
        qa[u] = a; s += a * a;
      }
      s += __shfl_xor(s, 1, 64); s += __shfl_xor(s, 2, 64);
      float qs = 0.125f / (sqrtf(s) + 1e-6f);
      #pragma unroll
      for (int u = 0; u < 16; u++) Qt[tTh][kb + u] = qa[u] * qs;
    }
    // k
    {
      uint4 x[8];
      #pragma unroll
      for (int tap = 0; tap < 4; tap++) {
        int tr = t0 + tTh - 3 + tap;
        if (tr >= 0) {
          const uint4* p = (const uint4*)(qkv + (size_t)(b * T_ + tr) * 3072 + 1024 + c0);
          x[tap * 2] = p[0]; x[tap * 2 + 1] = p[1];
        } else { x[tap * 2] = z4; x[tap * 2 + 1] = z4; }
      }
      float ka[16], s = 0.f;
      #pragma unroll
      for (int u = 0; u < 16; u++) {
        float4 w = ((const float4*)kcw)[c0 + u];
        float a = kcb[c0 + u];
        #pragma unroll
        for (int tap = 0; tap < 4; tap++) a += XROW(x, tap, u) * TAPW(w, tap);
        a = siluf_(a);
        ka[u] = a; s += a * a;
      }
      s += __shfl_xor(s, 1, 64); s += __shfl_xor(s, 2, 64);
      float ks = 1.f / (sqrtf(s) + 1e-6f);
      #pragma unroll
      for (int u = 0; u < 16; u++) Kt[tTh][kb + u] = ka[u] * ks;
    }
    // g = -A*softplus(graw+dtb) -> cM; beta
    {
      float Aexp = expf(A_log[h]);
      const ushort* gr = grawB + (size_t)(b * T_ + t0 + tTh) * 1024 + c0;
      uint4 ga = *(const uint4*)gr;
      uint4 gb = *(const uint4*)(gr + 8);
      float xv[16];
      xv[0] = bf2f((ushort)ga.x); xv[1] = bf2f((ushort)(ga.x >> 16));
      xv[2] = bf2f((ushort)ga.y); xv[3] = bf2f((ushort)(ga.y >> 16));
      xv[4] = bf2f((ushort)ga.z); xv[5] = bf2f((ushort)(ga.z >> 16));
      xv[6] = bf2f((ushort)ga.w); xv[7] = bf2f((ushort)(ga.w >> 16));
      xv[8] = bf2f((ushort)gb.x); xv[9] = bf2f((ushort)(gb.x >> 16));
      xv[10] = bf2f((ushort)gb.y); xv[11] = bf2f((ushort)(gb.y >> 16));
      xv[12] = bf2f((ushort)gb.z); xv[13] = bf2f((ushort)(gb.z >> 16));
      xv[14] = bf2f((ushort)gb.w); xv[15] = bf2f((ushort)(gb.w >> 16));
      #pragma unroll
      for (int u = 0; u < 16; u++) {
        float x = xv[u] + dtb[c0 + u];
        float sp = (x > 20.f) ? x : log1pf(expf(x));
        cM[tTh][kb + u] = -Aexp * sp;
      }
      if (tid < 64)
        betaL[tid] = sigmoidf_(f1g1b[(size_t)(b * T_ + t0 + tid) * 256 + 128 + h]);
    }
  }
  __syncthreads();
  // ---- PH2: cumsum within quarters ----
  {
    const int q = wA, k = tA;
    float run = 0.f;
    #pragma unroll
    for (int u = 0; u < 16; u++) { run += cM[q * 16 + u][k]; cM[q * 16 + u][k] = run; }
    dlog[q][k] = run;
  }
  __syncthreads();
  // ---- PH3: apply segment offsets ----
  {
    const int q = wA, k = tA;
    if (q > 0) {
      float off = dlog[0][k];
      if (q > 1) off += dlog[1][k];
      if (q > 2) off += dlog[2][k];
      #pragma unroll
      for (int u = 0; u < 16; u++) cM[q * 16 + u][k] += off;
    }
  }
  __syncthreads();
  // ---- PH4: block-base log decays ----
  for (int idx = tid; idx < 17 * 64; idx += 256) {
    int P = idx >> 6, k = idx & 63;
    dlog[P][k] = (P == 0) ? 0.f : cM[4 * P - 1][k];
  }
  __syncthreads();
  // ---- PH5: K~/K^/Q~ in place (cM dead after this) ----
  {
    const int P5 = tTh >> 2;
    #pragma unroll
    for (int u = 0; u < 16; u++) {
      int k = kb + u;
      float kn = Kt[tTh][k], qn = Qt[tTh][k];
      float c = cM[tTh][k], d = dlog[P5][k];
      float e1 = expf(c - d);
      float e2 = expf(d - c);
      Kt[tTh][k] = kn * e1;
      Kh[tTh][k] = kn * e2;
      Qt[tTh][k] = qn * e1;
    }
  }
  __syncthreads();
  // ---- PH6: Wq/WkB/bv/ge outputs + M-build (bf16 into cM overlay) ----
  {
    const int P = tTh >> 2;
    float bt = betaL[tTh];
    float tq[16], tk[16];
    #pragma unroll
    for (int u = 0; u < 16; u++) {
      int k = kb + u;
      float e = expf(dlog[P][k]);
      tq[u] = Qt[tTh][k] * e;
      tk[u] = bt * Kt[tTh][k] * e;
    }
    ushort* pq = mWqBv + (size_t)i * 8192 + tTh * 64 + kb;
    ushort* pk = mWkB + (size_t)i * 4096 + tTh * 64 + kb;
    *(uint4*)&pq[0] = pk8_(&tq[0]);
    *(uint4*)&pq[8] = pk8_(&tq[8]);
    *(uint4*)&pk[0] = pk8_(&tk[0]);
    *(uint4*)&pk[8] = pk8_(&tk[8]);

    // bv = beta * silu(conv(v)) — direct-global vector conv
    {
      const uint4 z4 = make_uint4(0, 0, 0, 0);
      uint4 x[8];
      #pragma unroll
      for (int tap = 0; tap < 4; tap++) {
        int tr = t0 + tTh - 3 + tap;
        if (tr >= 0) {
          const uint4* p = (const uint4*)(qkv + (size_t)(b * T_ + tr) * 3072 + 2048 + c0);
          x[tap * 2] = p[0]; x[tap * 2 + 1] = p[1];
        } else { x[tap * 2] = z4; x[tap * 2 + 1] = z4; }
      }
      float av[16];
      #pragma unroll
      for (int u = 0; u < 16; u++) {
        float4 w = ((const float4*)vcw)[c0 + u];
        float a = vcb[c0 + u];
        #pragma unroll
        for (int tap = 0; tap < 4; tap++) a += XROW(x, tap, u) * TAPW(w, tap);
        av[u] = bt * siluf_(a);
      }
      ushort* pb = mWqBv + (size_t)i * 8192 + 4096 + tTh * 64 + kb;
      *(uint4*)&pb[0] = pk8_(&av[0]);
      *(uint4*)&pb[8] = pk8_(&av[8]);
    }

    if (tid < 64) geG[(size_t)i * 64 + tid] = expf(dlog[16][tid]);

    // M-build: 272 4x4 tiles, R recomputed on the fly (all exponents <= 0)
    for (int tile = tid; tile < 272; tile += 256) {
      int mq = (tile >= 136) ? 1 : 0;
      int f = tile - mq * 136;
      int rem = f, P2 = 0;
      while (rem >= P2 + 1) { rem -= P2 + 1; ++P2; }
      int J = rem;
      const float (*Xr)[68] = mq ? Qt : Kt;
      float acc[4][4] = {};
      for (int kc = 0; kc < 16; kc++) {
        float4 avv[4];
        #pragma unroll
        for (int r = 0; r < 4; r++) avv[r] = *(const float4*)&Xr[4 * P2 + r][kc * 4];
        float4 dp = *(const float4*)&dlog[P2][kc * 4];
        float4 dj = *(const float4*)&dlog[J][kc * 4];
        float4 rv = make_float4(expf(dp.x - dj.x), expf(dp.y - dj.y),
                                expf(dp.z - dj.z), expf(dp.w - dj.w));
        #pragma unroll
        for (int c = 0; c < 4; c++) {
          float4 kvv = *(const float4*)&Kh[4 * J + c][kc * 4];
          float bx = kvv.x * rv.x, by = kvv.y * rv.y, bz = kvv.z * rv.z, bw = kvv.w * rv.w;
          #pragma unroll
          for (int r = 0; r < 4; r++)
            acc[r][c] += avv[r].x * bx + avv[r].y * by + avv[r].z * bz + avv[r].w * bw;
        }
      }
      if (mq && P2 == J) {
        #pragma unroll
        for (int c = 0; c < 4; c++)
          #pragma unroll
          for (int r = 0; r < 4; r++)
            if (c > r) acc[r][c] = 0.f;
      }
      ushort (*MT)[68] = mq ? MqkT : MkkT;
      #pragma unroll
      for (int c = 0; c < 4; c++) {
        uint2 w;
        w.x = (uint)f2bf(acc[0][c]) | ((uint)f2bf(acc[1][c]) << 16);
        w.y = (uint)f2bf(acc[2][c]) | ((uint)f2bf(acc[3][c]) << 16);
        *(uint2*)&MT[4 * J + c][4 * P2] = w;
      }
    }
  }
  __syncthreads();
  // ---- PH7: KhE into Qt + G-solve (G overlays dead Kt) ----
  for (int idx = tid; idx < 4096; idx += 256) {
    int s = idx >> 6, k = idx & 63;
    Qt[s][k] = Kh[s][k] * expf(dlog[16][k] - dlog[s >> 2][k]);
  }
  {
    const int j = tTh, q = c4;
    float acc[16], gsv[16];
    #pragma unroll
    for (int u = 0; u < 16; u++) { acc[u] = 0.f; gsv[u] = 0.f; }
    for (int s = 0; s < 64; s++) {
      int q0 = s >> 4;
      float g = 0.f;
      if (q == q0) {
        g = ((s == j) ? 1.f : 0.f) - betaL[s] * acc[s & 15];
        gsv[s & 15] = g;
      }
      g = __shfl(g, 4 * (j & 15) + q0, 64);
      #pragma unroll
      for (int u = 0; u < 4; u++) {
        uint2 m2 = *(const uint2*)&MkkT[s][q * 16 + u * 4];
        acc[u * 4 + 0] += bf2f((ushort)m2.x) * g;
        acc[u * 4 + 1] += bf2f((ushort)(m2.x >> 16)) * g;
        acc[u * 4 + 2] += bf2f((ushort)m2.y) * g;
        acc[u * 4 + 3] += bf2f((ushort)(m2.y >> 16)) * g;
      }
    }
    #pragma unroll
    for (int u = 0; u < 16; u++) Gl[q * 16 + u][j] = gsv[u];
  }
  __syncthreads();
  // ---- PH8: MG = tril(Mqk)@G, SG = KhE^T@G, write bf16 ----
  {
    float o[16];
    #pragma unroll
    for (int u = 0; u < 16; u++) o[u] = 0.f;
    for (int s = 0; s <= tTh; s++) {
      float m = bf2f(MqkT[s][tTh]);
      #pragma unroll
      for (int u = 0; u < 4; u++) {
        float4 g4 = *(const float4*)&Gl[s][kb + u * 4];
        o[u * 4 + 0] += m * g4.x; o[u * 4 + 1] += m * g4.y;
        o[u * 4 + 2] += m * g4.z; o[u * 4 + 3] += m * g4.w;
      }
    }
    ushort* pm = mMGSG + (size_t)i * 8192 + tTh * 64 + kb;
    *(uint4*)&pm[0] = pk8_(&o[0]);
    *(uint4*)&pm[8] = pk8_(&o[8]);

    #pragma unroll
    for (int u = 0; u < 16; u++) o[u] = 0.f;
    for (int s = 0; s < 64; s++) {
      float m = Qt[s][tTh];
      #pragma unroll
      for (int u = 0; u < 4; u++) {
        float4 g4 = *(const float4*)&Gl[s][kb + u * 4];
        o[u * 4 + 0] += m * g4.x; o[u * 4 + 1] += m * g4.y;
        o[u * 4 + 2] += m * g4.z; o[u * 4 + 3] += m * g4.w;
      }
    }
    ushort* ps = mMGSG + (size_t)i * 8192 + 4096 + tTh * 64 + kb;
    *(uint4*)&ps[0] = pk8_(&o[0]);
    *(uint4*)&ps[8] = pk8_(&o[8]);
  }
}

// ---------------------------------------------------------------------------
// scan: sequential-over-chunks state propagation. Grid (64 bh, 4 vq).
// Per chunk: r = bv - WkB@S; O = MG@r + Wq@S; S = ge*S + SG@r.
// ---------------------------------------------------------------------------
__global__ __launch_bounds__(256) void scan(
    const ushort* __restrict__ mMGSG, const ushort* __restrict__ mWkB,
    const ushort* __restrict__ mWqBv, const float* __restrict__ geG,
    ushort* __restrict__ oG) {
  const int bh = blockIdx.x, vq = blockIdx.y;
  const int tid = threadIdx.x;
  const int tTh = tid >> 2, c4 = tid & 3, lvi = c4 * 4;
  const int r0 = tid >> 2, cc = (tid & 3) * 16;

  __shared__ ushort MGs[64][72], SGs[64][72], WkBs[64][72], Wqs[64][72];
  __shared__ __align__(16) float Sl[64][20], rl[64][20];
  __shared__ float geL[64];

  *(float4*)&Sl[tTh][lvi] = make_float4(0.f, 0.f, 0.f, 0.f);

  const size_t i0 = (size_t)bh * 32;
  {
    uint4 a0 = *(const uint4*)&mMGSG[i0 * 8192 + tid * 16];
    uint4 a1 = *(const uint4*)&mMGSG[i0 * 8192 + tid * 16 + 8];
    uint4 b0 = *(const uint4*)&mMGSG[i0 * 8192 + 4096 + tid * 16];
    uint4 b1 = *(const uint4*)&mMGSG[i0 * 8192 + 4096 + tid * 16 + 8];
    uint4 c0 = *(const uint4*)&mWkB[i0 * 4096 + tid * 16];
    uint4 c1 = *(const uint4*)&mWkB[i0 * 4096 + tid * 16 + 8];
    uint4 d0 = *(const uint4*)&mWqBv[i0 * 8192 + tid * 16];
    uint4 d1 = *(const uint4*)&mWqBv[i0 * 8192 + tid * 16 + 8];
    *(uint4*)&MGs[r0][cc] = a0;  *(uint4*)&MGs[r0][cc + 8] = a1;
    *(uint4*)&SGs[r0][cc] = b0;  *(uint4*)&SGs[r0][cc + 8] = b1;
    *(uint4*)&WkBs[r0][cc] = c0; *(uint4*)&WkBs[r0][cc + 8] = c1;
    *(uint4*)&Wqs[r0][cc] = d0;  *(uint4*)&Wqs[r0][cc + 8] = d1;
    if (tid < 64) geL[tid] = geG[i0 * 64 + tid];
  }
  uint2 bvCur = *(const uint2*)&mWqBv[i0 * 8192 + 4096 + tTh * 64 + vq * 16 + lvi];
  __syncthreads();

  for (int ch = 0; ch < 32; ch++) {
    const size_t i = i0 + ch;
    uint4 p0, p1, p2, p3, p4, p5, p6, p7;
    uint2 pbv;
    float pge = 0.f;
    if (ch < 31) {
      const size_t i2 = i + 1;
      p0 = *(const uint4*)&mMGSG[i2 * 8192 + tid * 16];
      p1 = *(const uint4*)&mMGSG[i2 * 8192 + tid * 16 + 8];
      p2 = *(const uint4*)&mMGSG[i2 * 8192 + 4096 + tid * 16];
      p3 = *(const uint4*)&mMGSG[i2 * 8192 + 4096 + tid * 16 + 8];
      p4 = *(const uint4*)&mWkB[i2 * 4096 + tid * 16];
      p5 = *(const uint4*)&mWkB[i2 * 4096 + tid * 16 + 8];
      p6 = *(const uint4*)&mWqBv[i2 * 8192 + tid * 16];
      p7 = *(const uint4*)&mWqBv[i2 * 8192 + tid * 16 + 8];
      pbv = *(const uint2*)&mWqBv[i2 * 8192 + 4096 + tTh * 64 + vq * 16 + lvi];
      if (tid < 64) pge = geG[i2 * 64 + tid];
    }
    float rv[4];
    ub4_(bvCur, rv);
    #pragma unroll
    for (int kc = 0; kc < 16; kc++) {
      float w4[4];
      ub4_(*(const uint2*)&WkBs[tTh][kc * 4], w4);
      #pragma unroll
      for (int jj = 0; jj < 4; jj++) {
        float4 s4 = *(const float4*)&Sl[kc * 4 + jj][lvi];
        rv[0] -= w4[jj] * s4.x; rv[1] -= w4[jj] * s4.y;
        rv[2] -= w4[jj] * s4.z; rv[3] -= w4[jj] * s4.w;
      }
    }
    *(float4*)&rl[tTh][lvi] = make_float4(rv[0], rv[1], rv[2], rv[3]);
    __syncthreads();
    {
      float ov[4] = {0.f, 0.f, 0.f, 0.f};
      #pragma unroll
      for (int sc = 0; sc < 16; sc++) {
        float m4[4];
        ub4_(*(const uint2*)&MGs[tTh][sc * 4], m4);
        #pragma unroll
        for (int jj = 0; jj < 4; jj++) {
          float4 r4 = *(const float4*)&rl[sc * 4 + jj][lvi];
          ov[0] += m4[jj] * r4.x; ov[1] += m4[jj] * r4.y;
          ov[2] += m4[jj] * r4.z; ov[3] += m4[jj] * r4.w;
        }
      }
      #pragma unroll
      for (int kc = 0; kc < 16; kc++) {
        float q4[4];
        ub4_(*(const uint2*)&Wqs[tTh][kc * 4], q4);
        #pragma unroll
        for (int jj = 0; jj < 4; jj++) {
          float4 s4 = *(const float4*)&Sl[kc * 4 + jj][lvi];
          ov[0] += q4[jj] * s4.x; ov[1] += q4[jj] * s4.y;
          ov[2] += q4[jj] * s4.z; ov[3] += q4[jj] * s4.w;
        }
      }
      *(uint2*)&oG[i * 4096 + tTh * 64 + vq * 16 + lvi] =
          pk4_(ov[0], ov[1], ov[2], ov[3]);
    }
    __syncthreads();
    {
      float4 s4 = *(const float4*)&Sl[tTh][lvi];
      float ge = geL[tTh];
      float sv[4] = {ge * s4.x, ge * s4.y, ge * s4.z, ge * s4.w};
      #pragma unroll
      for (int sc = 0; sc < 16; sc++) {
        float g4[4];
        ub4_(*(const uint2*)&SGs[tTh][sc * 4], g4);
        #pragma unroll
        for (int jj = 0; jj < 4; jj++) {
          float4 r4 = *(const float4*)&rl[sc * 4 + jj][lvi];
          sv[0] += g4[jj] * r4.x; sv[1] += g4[jj] * r4.y;
          sv[2] += g4[jj] * r4.z; sv[3] += g4[jj] * r4.w;
        }
      }
      *(float4*)&Sl[tTh][lvi] = make_float4(sv[0], sv[1], sv[2], sv[3]);
    }
    __syncthreads();
    if (ch < 31) {
      *(uint4*)&MGs[r0][cc] = p0;  *(uint4*)&MGs[r0][cc + 8] = p1;
      *(uint4*)&SGs[r0][cc] = p2;  *(uint4*)&SGs[r0][cc + 8] = p3;
      *(uint4*)&WkBs[r0][cc] = p4; *(uint4*)&WkBs[r0][cc + 8] = p5;
      *(uint4*)&Wqs[r0][cc] = p6;  *(uint4*)&Wqs[r0][cc + 8] = p7;
      if (tid < 64) geL[tid] = pge;
      bvCur = pbv;
      __syncthreads();
    }
  }
}

// ---------------------------------------------------------------------------
// RMS-norm + gate + split-pack into [hi|lo] bf16 GEMM operand.
// ---------------------------------------------------------------------------
__global__ __launch_bounds__(256) void onorm_pack(
    const ushort* __restrict__ o, const float* __restrict__ gate,
    const float* __restrict__ onw, ushort* __restrict__ out3) {
  int gi = blockIdx.x * 4 + (threadIdx.x >> 6);
  int lane = threadIdx.x & 63;
  int b = gi >> 15, h = (gi >> 11) & 15, t = gi & 2047;
  float ov = bf2f(o[(size_t)gi * 64 + lane]);
  float ms = wave_sum64(ov * ov) * (1.f / 64.f);
  float r = rsqrtf(ms + 1e-5f);
  float gv = gate[(size_t)(b * T_ + t) * 1024 + h * 64 + lane];
  float val = ov * r * onw[lane] * sigmoidf_(gv);
  ushort hi = f2bf(val);
  float rem = val - bf2f(hi);
  ushort lo = f2bf(rem);
  size_t m = (size_t)(b * T_ + t);
  int c = h * 64 + lane;
  out3[m * 2048 + c] = hi;
  out3[m * 2048 + 1024 + c] = lo;
}

extern "C" void kernel_launch(void* const* d_in, const int* in_sizes, int n_in,
                              void* d_out, int out_size, void* d_ws, size_t ws_size,
                              hipStream_t stream) {
  const float* hs    = (const float*)d_in[0];
  const float* Wq    = (const float*)d_in[1];
  const float* Wk    = (const float*)d_in[2];
  const float* Wv    = (const float*)d_in[3];
  const float* qcw   = (const float*)d_in[4];
  const float* qcb   = (const float*)d_in[5];
  const float* kcw   = (const float*)d_in[6];
  const float* kcb   = (const float*)d_in[7];
  const float* vcw   = (const float*)d_in[8];
  const float* vcb   = (const float*)d_in[9];
  const float* Wf1   = (const float*)d_in[10];
  const float* Wf2   = (const float*)d_in[11];
  const float* Wb    = (const float*)d_in[12];
  const float* A_log = (const float*)d_in[13];
  const float* dtb   = (const float*)d_in[14];
  const float* Wg1   = (const float*)d_in[15];
  const float* Wg2   = (const float*)d_in[16];
  const float* bg2   = (const float*)d_in[17];
  const float* onw   = (const float*)d_in[18];
  const float* Wo    = (const float*)d_in[19];
  float* out = (float*)d_out;

  char* ws = (char*)d_ws;
  ushort* hs3    = (ushort*)(ws);
  ushort* mMGSG  = (ushort*)(ws);
  ushort* obuf3  = (ushort*)(ws);
  ushort* mWkB   = (ushort*)(ws + 33554432);
  ushort* qkvhat = (ushort*)(ws + 50331648);
  float*  gate   = (float*)qkvhat;
  ushort* oG     = (ushort*)(ws + 83886080);
  ushort* grawB  = (ushort*)(ws + 100663296);
  float*  geG    = (float*)(ws + 117440512);
  ushort* mWqBv  = (ushort*)(ws + 117964800);
  char*   R4     = ws + 151519232;
  ushort* Wqkv3  = (ushort*)R4;
  ushort* Wfgb3  = (ushort*)R4;
  float*  f1g1b  = (float*)(R4 + 1572864);
  ushort* f1_3   = (ushort*)(R4 + 9961472);
  ushort* g1_3   = (ushort*)(R4 + 13107200);
  ushort* Wf2_3  = (ushort*)(R4 + 16252928);
  ushort* Wg2_3  = (ushort*)(R4 + 16646144);
  ushort* Wo3    = (ushort*)R4;

  dim3 blk(256);
  const int PK = 1024 * 1024;

  split_pack_A<<<dim3((M_ * 1024) / 256), blk, 0, stream>>>(hs, 1024, 1024, M_, hs3);
  pack_w3t<<<dim3(PK / 256), blk, 0, stream>>>(Wq, 1024, 1024, Wqkv3, 2048);
  pack_w3t<<<dim3(PK / 256), blk, 0, stream>>>(Wk, 1024, 1024, Wqkv3 + (size_t)1024 * 2048, 2048);
  pack_w3t<<<dim3(PK / 256), blk, 0, stream>>>(Wv, 1024, 1024, Wqkv3 + (size_t)2048 * 2048, 2048);
  gemm_glds<ushort><<<dim3(M_ / 128, 3072 / 128), blk, 0, stream>>>(
      hs3, Wqkv3, nullptr, qkvhat, M_, 3072, 2048);
  hipMemsetAsync(Wfgb3, 0, (size_t)256 * 2048 * 2, stream);
  pack_w3t<<<dim3((1024 * 64) / 256), blk, 0, stream>>>(Wf1, 1024, 64, Wfgb3, 2048);
  pack_w3t<<<dim3((1024 * 64) / 256), blk, 0, stream>>>(Wg1, 1024, 64, Wfgb3 + (size_t)64 * 2048, 2048);
  pack_w3t<<<dim3((1024 * 16) / 256), blk, 0, stream>>>(Wb, 1024, 16, Wfgb3 + (size_t)128 * 2048, 2048);
  gemm_glds<float><<<dim3(M_ / 128, 2), blk, 0, stream>>>(
      hs3, Wfgb3, nullptr, f1g1b, M_, 256, 2048);
  split_pack_A<<<dim3((M_ * 64) / 256), blk, 0, stream>>>(f1g1b, 256, 64, M_, f1_3);
  split_pack_A<<<dim3((M_ * 64) / 256), blk, 0, stream>>>(f1g1b + 64, 256, 64, M_, g1_3);
  pack_w3t<<<dim3((64 * 1024) / 256), blk, 0, stream>>>(Wf2, 64, 1024, Wf2_3, 128);
  gemm_glds<ushort><<<dim3(M_ / 128, 1024 / 128), blk, 0, stream>>>(
      f1_3, Wf2_3, nullptr, grawB, M_, 1024, 128);

  prep<<<dim3(64, 32), blk, 0, stream>>>(qkvhat, grawB, f1g1b,
                                         qcw, qcb, kcw, kcb, vcw, vcb,
                                         A_log, dtb, mMGSG, mWkB, mWqBv, geG);
  pack_w3t<<<dim3((64 * 1024) / 256), blk, 0, stream>>>(Wg2, 64, 1024, Wg2_3, 128);
  gemm_glds<float><<<dim3(M_ / 128, 1024 / 128), blk, 0, stream>>>(
      g1_3, Wg2_3, bg2, gate, M_, 1024, 128);

  scan<<<dim3(64, 4), blk, 0, stream>>>(mMGSG, mWkB, mWqBv, geG, oG);

  onorm_pack<<<dim3((M_ * H_) / 4), blk, 0, stream>>>(oG, gate, onw, obuf3);
  pack_w3t<<<dim3(PK / 256), blk, 0, stream>>>(Wo, 1024, 1024, Wo3, 2048);
  gemm_glds<float><<<dim3(M_ / 128, 1024 / 128), blk, 0, stream>>>(
      obuf3, Wo3, nullptr, out, M_, 1024, 2048);
}

// Round 11
// 739.953 us; speedup vs baseline: 4.7372x; 1.0171x over previous
//
#include <hip/hip_runtime.h>
#include <hip/hip_bf16.h>
#include <math.h>

#define H_ 16
#define HIDDEN_ 1024
#define BATCH_ 4
#define T_ 2048
#define M_ (BATCH_ * T_)   // 8192

typedef __attribute__((ext_vector_type(8))) __bf16 bf16x8;
typedef __attribute__((ext_vector_type(4))) float f32x4;

__device__ __forceinline__ float wave_sum64(float v) {
  #pragma unroll
  for (int m = 32; m >= 1; m >>= 1) v += __shfl_xor(v, m, 64);
  return v;
}
__device__ __forceinline__ float sigmoidf_(float x) { return 1.f / (1.f + expf(-x)); }
__device__ __forceinline__ float siluf_(float x) { return x / (1.f + expf(-x)); }
__device__ __forceinline__ float bf2f(ushort u) {
  unsigned int x = ((unsigned int)u) << 16;
  return __builtin_bit_cast(float, x);
}
__device__ __forceinline__ ushort f2bf(float f) {   // RNE
  unsigned int x = __builtin_bit_cast(unsigned int, f);
  unsigned int r = (x + 0x7fffu + ((x >> 16) & 1u)) >> 16;
  return (ushort)r;
}
__device__ __forceinline__ void ub4_(uint2 u, float f[4]) {
  f[0] = bf2f((ushort)u.x); f[1] = bf2f((ushort)(u.x >> 16));
  f[2] = bf2f((ushort)u.y); f[3] = bf2f((ushort)(u.y >> 16));
}
__device__ __forceinline__ void ub8_(uint4 u, float* f) {
  f[0] = bf2f((ushort)u.x); f[1] = bf2f((ushort)(u.x >> 16));
  f[2] = bf2f((ushort)u.y); f[3] = bf2f((ushort)(u.y >> 16));
  f[4] = bf2f((ushort)u.z); f[5] = bf2f((ushort)(u.z >> 16));
  f[6] = bf2f((ushort)u.w); f[7] = bf2f((ushort)(u.w >> 16));
}
__device__ __forceinline__ uint2 pk4_(float a, float b, float c, float d) {
  return make_uint2((uint)f2bf(a) | ((uint)f2bf(b) << 16),
                    (uint)f2bf(c) | ((uint)f2bf(d) << 16));
}
__device__ __forceinline__ uint4 pk8_(const float* t) {
  uint4 r;
  r.x = (uint)f2bf(t[0]) | ((uint)f2bf(t[1]) << 16);
  r.y = (uint)f2bf(t[2]) | ((uint)f2bf(t[3]) << 16);
  r.z = (uint)f2bf(t[4]) | ((uint)f2bf(t[5]) << 16);
  r.w = (uint)f2bf(t[6]) | ((uint)f2bf(t[7]) << 16);
  return r;
}
// async global -> LDS, 16B per lane (dest: wave-uniform base + lane*16)
__device__ __forceinline__ void gl16(const ushort* g, ushort* l) {
  __builtin_amdgcn_global_load_lds(
      (const __attribute__((address_space(1))) unsigned int*)g,
      (__attribute__((address_space(3))) unsigned int*)l, 16, 0, 0);
}

// ---------------------------------------------------------------------------
// Split-pack A: f32 [M,K] -> bf16 [M,2K] as [hi | lo]  (2-term split).
// ---------------------------------------------------------------------------
__global__ __launch_bounds__(256) void split_pack_A(
    const float* __restrict__ in, int inStride, int K, int M,
    ushort* __restrict__ out) {
  size_t tid = (size_t)blockIdx.x * 256 + threadIdx.x;
  if (tid >= (size_t)M * K) return;
  int k = (int)(tid % K);
  size_t m = tid / K;
  float x = in[m * inStride + k];
  ushort hi = f2bf(x);
  float rem = x - bf2f(hi);
  ushort lo = f2bf(rem);
  size_t o = m * (size_t)(2 * K);
  out[o + k] = hi;
  out[o + K + k] = lo;
}

// ---------------------------------------------------------------------------
// Pack weight W [K,N] f32 -> transposed bf16 [n][hi|hi] (2-term: B repeated).
// ---------------------------------------------------------------------------
__global__ __launch_bounds__(256) void pack_w3t(
    const float* __restrict__ W, int K, int N,
    ushort* __restrict__ out, int rowStride) {
  size_t tid = (size_t)blockIdx.x * 256 + threadIdx.x;
  if (tid >= (size_t)K * N) return;
  int k = (int)(tid % K);
  size_t n = tid / K;
  float x = W[(size_t)k * N + n];
  ushort hi = f2bf(x);
  size_t o = n * (size_t)rowStride;
  out[o + k] = hi;
  out[o + K + k] = hi;
}

// ---------------------------------------------------------------------------
// bf16 MFMA GEMM, m97 structure: global_load_lds(16B) staging into LINEAR
// LDS [128][32], 128x128 tile, 4 waves (2x2), 16x16x32 MFMA, BK=32.
// ---------------------------------------------------------------------------
template <typename OutT>
__global__ __launch_bounds__(256) void gemm_glds(
    const ushort* __restrict__ A, const ushort* __restrict__ Bt,
    const float* __restrict__ bias, OutT* __restrict__ C,
    int M, int N, int K) {
  __shared__ ushort As[128 * 32];
  __shared__ ushort Bs[128 * 32];
  const int tid = threadIdx.x;
  const int bm = blockIdx.x * 128, bn = blockIdx.y * 128;
  const int wid = tid >> 6, lane = tid & 63;
  const int wm = (wid >> 1) * 64, wn = (wid & 1) * 64;
  const int fr = lane & 15, fq = lane >> 4;
  const int srow = wid * 32 + (lane >> 2);
  const int scol = (lane & 3) * 8;

  f32x4 acc[4][4] = {};

  for (int k0 = 0; k0 < K; k0 += 32) {
    const ushort* gA = A + (size_t)(bm + srow) * K + k0 + scol;
    const ushort* gB = Bt + (size_t)(bn + srow) * K + k0 + scol;
    gl16(gA, &As[(wid * 32) * 32]);
    gl16(gA + (size_t)16 * K, &As[(wid * 32 + 16) * 32]);
    gl16(gB, &Bs[(wid * 32) * 32]);
    gl16(gB + (size_t)16 * K, &Bs[(wid * 32 + 16) * 32]);
    __syncthreads();

    bf16x8 af[4], bfr[4];
    #pragma unroll
    for (int i = 0; i < 4; i++) af[i] = *(const bf16x8*)&As[(wm + i * 16 + fr) * 32 + fq * 8];
    #pragma unroll
    for (int j = 0; j < 4; j++) bfr[j] = *(const bf16x8*)&Bs[(wn + j * 16 + fr) * 32 + fq * 8];
    #pragma unroll
    for (int i = 0; i < 4; i++)
      #pragma unroll
      for (int j = 0; j < 4; j++)
        acc[i][j] = __builtin_amdgcn_mfma_f32_16x16x32_bf16(af[i], bfr[j], acc[i][j], 0, 0, 0);
    __syncthreads();
  }

  #pragma unroll
  for (int i = 0; i < 4; i++) {
    #pragma unroll
    for (int j = 0; j < 4; j++) {
      int col = bn + wn + j * 16 + fr;
      float bv = bias ? bias[col] : 0.f;
      #pragma unroll
      for (int r = 0; r < 4; r++) {
        int row = bm + wm + i * 16 + fq * 4 + r;
        float v = acc[i][j][r] + bv;
        if constexpr (sizeof(OutT) == 2) {
          ((ushort*)C)[(size_t)row * N + col] = f2bf(v);
        } else {
          ((float*)C)[(size_t)row * N + col] = v;
        }
      }
    }
  }
}

// unpack element u (0..15) from a 4-row packed conv window x[8] (2 uint4/row)
#define XROW(x, tap, u) \
  bf2f((ushort)(((u) & 1) ? (((const uint*)&(x)[(tap) * 2 + ((u) >> 3)])[((u) >> 1) & 3] >> 16) \
                          : ((const uint*)&(x)[(tap) * 2 + ((u) >> 3)])[((u) >> 1) & 3]))
#define TAPW(w, tap) ((tap) == 0 ? (w).x : (tap) == 1 ? (w).y : (tap) == 2 ? (w).z : (w).w)

// ---------------------------------------------------------------------------
// prep v5: bf16 LDS for K~/K^/Q~/G => 49.9 KB LDS => 3 blocks/CU (was 74.7
// KB / 2 blocks, Occupancy 22%, VALUBusy 57% — latency-underhidden).
// ---------------------------------------------------------------------------
__global__ __launch_bounds__(256, 3) void prep(
    const ushort* __restrict__ qkv, const ushort* __restrict__ grawB,
    const float* __restrict__ f1g1b,
    const float* __restrict__ qcw, const float* __restrict__ qcb,
    const float* __restrict__ kcw, const float* __restrict__ kcb,
    const float* __restrict__ vcw, const float* __restrict__ vcb,
    const float* __restrict__ A_log, const float* __restrict__ dtb,
    ushort* __restrict__ mMGSG, ushort* __restrict__ mWkB,
    ushort* __restrict__ mWqBv, float* __restrict__ geG) {
  const int bh = blockIdx.x, ch = blockIdx.y;
  const int b = bh >> 4, h = bh & 15;
  const int i = bh * 32 + ch;
  const int t0 = ch * 64;
  const int tid = threadIdx.x;
  const int wA = tid >> 6, tA = tid & 63;
  const int tTh = tid >> 2, c4 = tid & 3, kb = c4 * 16;
  const int c0 = h * 64 + kb;

  __shared__ __align__(16) ushort KtU[64][72];  // kn -> K~ bf16 ; PH7+: G bf16
  __shared__ __align__(16) ushort KhU[64][72];  // K^ bf16
  __shared__ __align__(16) ushort QtU[64][72];  // qn -> Q~ bf16 ; PH7: KhE bf16
  __shared__ __align__(16) float cM[64][68];    // g -> cumsum; PH6+: M bf16 overlay
  __shared__ __align__(16) float dlog[17][68];
  __shared__ float betaL[64];
  ushort (*MqkT)[68] = (ushort(*)[68])&cM[0][0];
  ushort (*MkkT)[68] = (ushort(*)[68])&cM[32][0];
  ushort (*GlU)[72] = KtU;

  // ---- PH0: conv+SiLU+norm for q,k straight from global (vector loads) ----
  {
    const uint4 z4 = make_uint4(0, 0, 0, 0);
    // q
    {
      uint4 x[8];
      #pragma unroll
      for (int tap = 0; tap < 4; tap++) {
        int tr = t0 + tTh - 3 + tap;
        if (tr >= 0) {
          const uint4* p = (const uint4*)(qkv + (size_t)(b * T_ + tr) * 3072 + c0);
          x[tap * 2] = p[0]; x[tap * 2 + 1] = p[1];
        } else { x[tap * 2] = z4; x[tap * 2 + 1] = z4; }
      }
      float qa[16], s = 0.f;
      #pragma unroll
      for (int u = 0; u < 16; u++) {
        float4 w = ((const float4*)qcw)[c0 + u];
        float a = qcb[c0 + u];
        #pragma unroll
        for (int tap = 0; tap < 4; tap++) a += XROW(x, tap, u) * TAPW(w, tap);
        a = siluf_(a);
        qa[u] = a; s += a * a;
      }
      s += __shfl_xor(s, 1, 64); s += __shfl_xor(s, 2, 64);
      float qs = 0.125f / (sqrtf(s) + 1e-6f);
      #pragma unroll
      for (int u = 0; u < 16; u++) qa[u] *= qs;
      *(uint4*)&QtU[tTh][kb] = pk8_(&qa[0]);
      *(uint4*)&QtU[tTh][kb + 8] = pk8_(&qa[8]);
    }
    // k
    {
      uint4 x[8];
      #pragma unroll
      for (int tap = 0; tap < 4; tap++) {
        int tr = t0 + tTh - 3 + tap;
        if (tr >= 0) {
          const uint4* p = (const uint4*)(qkv + (size_t)(b * T_ + tr) * 3072 + 1024 + c0);
          x[tap * 2] = p[0]; x[tap * 2 + 1] = p[1];
        } else { x[tap * 2] = z4; x[tap * 2 + 1] = z4; }
      }
      float ka[16], s = 0.f;
      #pragma unroll
      for (int u = 0; u < 16; u++) {
        float4 w = ((const float4*)kcw)[c0 + u];
        float a = kcb[c0 + u];
        #pragma unroll
        for (int tap = 0; tap < 4; tap++) a += XROW(x, tap, u) * TAPW(w, tap);
        a = siluf_(a);
        ka[u] = a; s += a * a;
      }
      s += __shfl_xor(s, 1, 64); s += __shfl_xor(s, 2, 64);
      float ks = 1.f / (sqrtf(s) + 1e-6f);
      #pragma unroll
      for (int u = 0; u < 16; u++) ka[u] *= ks;
      *(uint4*)&KtU[tTh][kb] = pk8_(&ka[0]);
      *(uint4*)&KtU[tTh][kb + 8] = pk8_(&ka[8]);
    }
    // g = -A*softplus(graw+dtb) -> cM; beta
    {
      float Aexp = expf(A_log[h]);
      const ushort* gr = grawB + (size_t)(b * T_ + t0 + tTh) * 1024 + c0;
      uint4 ga = *(const uint4*)gr;
      uint4 gb = *(const uint4*)(gr + 8);
      float xv[16];
      ub8_(ga, &xv[0]); ub8_(gb, &xv[8]);
      #pragma unroll
      for (int u = 0; u < 16; u++) {
        float x = xv[u] + dtb[c0 + u];
        float sp = (x > 20.f) ? x : log1pf(expf(x));
        cM[tTh][kb + u] = -Aexp * sp;
      }
      if (tid < 64)
        betaL[tid] = sigmoidf_(f1g1b[(size_t)(b * T_ + t0 + tid) * 256 + 128 + h]);
    }
  }
  __syncthreads();
  // ---- PH2: cumsum within quarters ----
  {
    const int q = wA, k = tA;
    float run = 0.f;
    #pragma unroll
    for (int u = 0; u < 16; u++) { run += cM[q * 16 + u][k]; cM[q * 16 + u][k] = run; }
    dlog[q][k] = run;
  }
  __syncthreads();
  // ---- PH3: apply segment offsets ----
  {
    const int q = wA, k = tA;
    if (q > 0) {
      float off = dlog[0][k];
      if (q > 1) off += dlog[1][k];
      if (q > 2) off += dlog[2][k];
      #pragma unroll
      for (int u = 0; u < 16; u++) cM[q * 16 + u][k] += off;
    }
  }
  __syncthreads();
  // ---- PH4: block-base log decays ----
  for (int idx = tid; idx < 17 * 64; idx += 256) {
    int P = idx >> 6, k = idx & 63;
    dlog[P][k] = (P == 0) ? 0.f : cM[4 * P - 1][k];
  }
  __syncthreads();
  // ---- PH5: K~/K^/Q~ in place (bf16; cM dead after this) ----
  {
    const int P5 = tTh >> 2;
    float knv[16], qnv[16];
    ub8_(*(const uint4*)&KtU[tTh][kb], &knv[0]);
    ub8_(*(const uint4*)&KtU[tTh][kb + 8], &knv[8]);
    ub8_(*(const uint4*)&QtU[tTh][kb], &qnv[0]);
    ub8_(*(const uint4*)&QtU[tTh][kb + 8], &qnv[8]);
    float ktv[16], khv[16], qtv[16];
    #pragma unroll
    for (int u = 0; u < 16; u++) {
      int k = kb + u;
      float c = cM[tTh][k], d = dlog[P5][k];
      float e1 = expf(c - d);
      float e2 = expf(d - c);
      ktv[u] = knv[u] * e1;
      khv[u] = knv[u] * e2;
      qtv[u] = qnv[u] * e1;
    }
    *(uint4*)&KtU[tTh][kb] = pk8_(&ktv[0]);
    *(uint4*)&KtU[tTh][kb + 8] = pk8_(&ktv[8]);
    *(uint4*)&KhU[tTh][kb] = pk8_(&khv[0]);
    *(uint4*)&KhU[tTh][kb + 8] = pk8_(&khv[8]);
    *(uint4*)&QtU[tTh][kb] = pk8_(&qtv[0]);
    *(uint4*)&QtU[tTh][kb + 8] = pk8_(&qtv[8]);
  }
  __syncthreads();
  // ---- PH6: Wq/WkB/bv/ge outputs + M-build (bf16 into cM overlay) ----
  {
    const int P = tTh >> 2;
    float bt = betaL[tTh];
    float qtv[16], ktv[16];
    ub8_(*(const uint4*)&QtU[tTh][kb], &qtv[0]);
    ub8_(*(const uint4*)&QtU[tTh][kb + 8], &qtv[8]);
    ub8_(*(const uint4*)&KtU[tTh][kb], &ktv[0]);
    ub8_(*(const uint4*)&KtU[tTh][kb + 8], &ktv[8]);
    float tq[16], tk[16];
    #pragma unroll
    for (int u = 0; u < 16; u++) {
      int k = kb + u;
      float e = expf(dlog[P][k]);
      tq[u] = qtv[u] * e;
      tk[u] = bt * ktv[u] * e;
    }
    ushort* pq = mWqBv + (size_t)i * 8192 + tTh * 64 + kb;
    ushort* pk = mWkB + (size_t)i * 4096 + tTh * 64 + kb;
    *(uint4*)&pq[0] = pk8_(&tq[0]);
    *(uint4*)&pq[8] = pk8_(&tq[8]);
    *(uint4*)&pk[0] = pk8_(&tk[0]);
    *(uint4*)&pk[8] = pk8_(&tk[8]);

    // bv = beta * silu(conv(v)) — direct-global vector conv
    {
      const uint4 z4 = make_uint4(0, 0, 0, 0);
      uint4 x[8];
      #pragma unroll
      for (int tap = 0; tap < 4; tap++) {
        int tr = t0 + tTh - 3 + tap;
        if (tr >= 0) {
          const uint4* p = (const uint4*)(qkv + (size_t)(b * T_ + tr) * 3072 + 2048 + c0);
          x[tap * 2] = p[0]; x[tap * 2 + 1] = p[1];
        } else { x[tap * 2] = z4; x[tap * 2 + 1] = z4; }
      }
      float av[16];
      #pragma unroll
      for (int u = 0; u < 16; u++) {
        float4 w = ((const float4*)vcw)[c0 + u];
        float a = vcb[c0 + u];
        #pragma unroll
        for (int tap = 0; tap < 4; tap++) a += XROW(x, tap, u) * TAPW(w, tap);
        av[u] = bt * siluf_(a);
      }
      ushort* pb = mWqBv + (size_t)i * 8192 + 4096 + tTh * 64 + kb;
      *(uint4*)&pb[0] = pk8_(&av[0]);
      *(uint4*)&pb[8] = pk8_(&av[8]);
    }

    if (tid < 64) geG[(size_t)i * 64 + tid] = expf(dlog[16][tid]);

    // M-build: 272 4x4 tiles, R recomputed on the fly (all exponents <= 0)
    for (int tile = tid; tile < 272; tile += 256) {
      int mq = (tile >= 136) ? 1 : 0;
      int f = tile - mq * 136;
      int rem = f, P2 = 0;
      while (rem >= P2 + 1) { rem -= P2 + 1; ++P2; }
      int J = rem;
      const ushort (*Xr)[72] = mq ? QtU : KtU;
      float acc[4][4] = {};
      for (int kc = 0; kc < 16; kc++) {
        float av0[4], av1[4], av2[4], av3[4];
        ub4_(*(const uint2*)&Xr[4 * P2 + 0][kc * 4], av0);
        ub4_(*(const uint2*)&Xr[4 * P2 + 1][kc * 4], av1);
        ub4_(*(const uint2*)&Xr[4 * P2 + 2][kc * 4], av2);
        ub4_(*(const uint2*)&Xr[4 * P2 + 3][kc * 4], av3);
        float4 dp = *(const float4*)&dlog[P2][kc * 4];
        float4 dj = *(const float4*)&dlog[J][kc * 4];
        float rv[4] = {expf(dp.x - dj.x), expf(dp.y - dj.y),
                       expf(dp.z - dj.z), expf(dp.w - dj.w)};
        #pragma unroll
        for (int c = 0; c < 4; c++) {
          float kv[4];
          ub4_(*(const uint2*)&KhU[4 * J + c][kc * 4], kv);
          float bx = kv[0] * rv[0], by = kv[1] * rv[1], bz = kv[2] * rv[2], bw = kv[3] * rv[3];
          acc[0][c] += av0[0] * bx + av0[1] * by + av0[2] * bz + av0[3] * bw;
          acc[1][c] += av1[0] * bx + av1[1] * by + av1[2] * bz + av1[3] * bw;
          acc[2][c] += av2[0] * bx + av2[1] * by + av2[2] * bz + av2[3] * bw;
          acc[3][c] += av3[0] * bx + av3[1] * by + av3[2] * bz + av3[3] * bw;
        }
      }
      if (mq && P2 == J) {
        #pragma unroll
        for (int c = 0; c < 4; c++)
          #pragma unroll
          for (int r = 0; r < 4; r++)
            if (c > r) acc[r][c] = 0.f;
      }
      ushort (*MT)[68] = mq ? MqkT : MkkT;
      #pragma unroll
      for (int c = 0; c < 4; c++) {
        uint2 w;
        w.x = (uint)f2bf(acc[0][c]) | ((uint)f2bf(acc[1][c]) << 16);
        w.y = (uint)f2bf(acc[2][c]) | ((uint)f2bf(acc[3][c]) << 16);
        *(uint2*)&MT[4 * J + c][4 * P2] = w;
      }
    }
  }
  __syncthreads();
  // ---- PH7: KhE into QtU + G-solve (G bf16 overlays dead KtU) ----
  for (int idx = tid; idx < 4096; idx += 256) {
    int s = idx >> 6, k = idx & 63;
    QtU[s][k] = f2bf(bf2f(KhU[s][k]) * expf(dlog[16][k] - dlog[s >> 2][k]));
  }
  {
    const int j = tTh, q = c4;
    float acc[16], gsv[16];
    #pragma unroll
    for (int u = 0; u < 16; u++) { acc[u] = 0.f; gsv[u] = 0.f; }
    for (int s = 0; s < 64; s++) {
      int q0 = s >> 4;
      float g = 0.f;
      if (q == q0) {
        g = ((s == j) ? 1.f : 0.f) - betaL[s] * acc[s & 15];
        gsv[s & 15] = g;
      }
      g = __shfl(g, 4 * (j & 15) + q0, 64);
      #pragma unroll
      for (int u = 0; u < 4; u++) {
        uint2 m2 = *(const uint2*)&MkkT[s][q * 16 + u * 4];
        acc[u * 4 + 0] += bf2f((ushort)m2.x) * g;
        acc[u * 4 + 1] += bf2f((ushort)(m2.x >> 16)) * g;
        acc[u * 4 + 2] += bf2f((ushort)m2.y) * g;
        acc[u * 4 + 3] += bf2f((ushort)(m2.y >> 16)) * g;
      }
    }
    // GlU overlays KtU (K~ dead after PH6; barrier above protects)
    #pragma unroll
    for (int u = 0; u < 16; u++) GlU[q * 16 + u][j] = f2bf(gsv[u]);
  }
  __syncthreads();
  // ---- PH8: MG = tril(Mqk)@G, SG = KhE^T@G, write bf16 ----
  {
    float o[16];
    #pragma unroll
    for (int u = 0; u < 16; u++) o[u] = 0.f;
    for (int s = 0; s <= tTh; s++) {
      float m = bf2f(MqkT[s][tTh]);
      #pragma unroll
      for (int u = 0; u < 4; u++) {
        float g4[4];
        ub4_(*(const uint2*)&GlU[s][kb + u * 4], g4);
        o[u * 4 + 0] += m * g4[0]; o[u * 4 + 1] += m * g4[1];
        o[u * 4 + 2] += m * g4[2]; o[u * 4 + 3] += m * g4[3];
      }
    }
    ushort* pm = mMGSG + (size_t)i * 8192 + tTh * 64 + kb;
    *(uint4*)&pm[0] = pk8_(&o[0]);
    *(uint4*)&pm[8] = pk8_(&o[8]);

    #pragma unroll
    for (int u = 0; u < 16; u++) o[u] = 0.f;
    for (int s = 0; s < 64; s++) {
      float m = bf2f(QtU[s][tTh]);
      #pragma unroll
      for (int u = 0; u < 4; u++) {
        float g4[4];
        ub4_(*(const uint2*)&GlU[s][kb + u * 4], g4);
        o[u * 4 + 0] += m * g4[0]; o[u * 4 + 1] += m * g4[1];
        o[u * 4 + 2] += m * g4[2]; o[u * 4 + 3] += m * g4[3];
      }
    }
    ushort* ps = mMGSG + (size_t)i * 8192 + 4096 + tTh * 64 + kb;
    *(uint4*)&ps[0] = pk8_(&o[0]);
    *(uint4*)&ps[8] = pk8_(&o[8]);
  }
}

// ---------------------------------------------------------------------------
// scan: sequential-over-chunks state propagation. Grid (64 bh, 4 vq).
// Per chunk: r = bv - WkB@S; O = MG@r + Wq@S; S = ge*S + SG@r.
// ---------------------------------------------------------------------------
__global__ __launch_bounds__(256) void scan(
    const ushort* __restrict__ mMGSG, const ushort* __restrict__ mWkB,
    const ushort* __restrict__ mWqBv, const float* __restrict__ geG,
    ushort* __restrict__ oG) {
  const int bh = blockIdx.x, vq = blockIdx.y;
  const int tid = threadIdx.x;
  const int tTh = tid >> 2, c4 = tid & 3, lvi = c4 * 4;
  const int r0 = tid >> 2, cc = (tid & 3) * 16;

  __shared__ ushort MGs[64][72], SGs[64][72], WkBs[64][72], Wqs[64][72];
  __shared__ __align__(16) float Sl[64][20], rl[64][20];
  __shared__ float geL[64];

  *(float4*)&Sl[tTh][lvi] = make_float4(0.f, 0.f, 0.f, 0.f);

  const size_t i0 = (size_t)bh * 32;
  {
    uint4 a0 = *(const uint4*)&mMGSG[i0 * 8192 + tid * 16];
    uint4 a1 = *(const uint4*)&mMGSG[i0 * 8192 + tid * 16 + 8];
    uint4 b0 = *(const uint4*)&mMGSG[i0 * 8192 + 4096 + tid * 16];
    uint4 b1 = *(const uint4*)&mMGSG[i0 * 8192 + 4096 + tid * 16 + 8];
    uint4 c0 = *(const uint4*)&mWkB[i0 * 4096 + tid * 16];
    uint4 c1 = *(const uint4*)&mWkB[i0 * 4096 + tid * 16 + 8];
    uint4 d0 = *(const uint4*)&mWqBv[i0 * 8192 + tid * 16];
    uint4 d1 = *(const uint4*)&mWqBv[i0 * 8192 + tid * 16 + 8];
    *(uint4*)&MGs[r0][cc] = a0;  *(uint4*)&MGs[r0][cc + 8] = a1;
    *(uint4*)&SGs[r0][cc] = b0;  *(uint4*)&SGs[r0][cc + 8] = b1;
    *(uint4*)&WkBs[r0][cc] = c0; *(uint4*)&WkBs[r0][cc + 8] = c1;
    *(uint4*)&Wqs[r0][cc] = d0;  *(uint4*)&Wqs[r0][cc + 8] = d1;
    if (tid < 64) geL[tid] = geG[i0 * 64 + tid];
  }
  uint2 bvCur = *(const uint2*)&mWqBv[i0 * 8192 + 4096 + tTh * 64 + vq * 16 + lvi];
  __syncthreads();

  for (int ch = 0; ch < 32; ch++) {
    const size_t i = i0 + ch;
    uint4 p0, p1, p2, p3, p4, p5, p6, p7;
    uint2 pbv;
    float pge = 0.f;
    if (ch < 31) {
      const size_t i2 = i + 1;
      p0 = *(const uint4*)&mMGSG[i2 * 8192 + tid * 16];
      p1 = *(const uint4*)&mMGSG[i2 * 8192 + tid * 16 + 8];
      p2 = *(const uint4*)&mMGSG[i2 * 8192 + 4096 + tid * 16];
      p3 = *(const uint4*)&mMGSG[i2 * 8192 + 4096 + tid * 16 + 8];
      p4 = *(const uint4*)&mWkB[i2 * 4096 + tid * 16];
      p5 = *(const uint4*)&mWkB[i2 * 4096 + tid * 16 + 8];
      p6 = *(const uint4*)&mWqBv[i2 * 8192 + tid * 16];
      p7 = *(const uint4*)&mWqBv[i2 * 8192 + tid * 16 + 8];
      pbv = *(const uint2*)&mWqBv[i2 * 8192 + 4096 + tTh * 64 + vq * 16 + lvi];
      if (tid < 64) pge = geG[i2 * 64 + tid];
    }
    float rv[4];
    ub4_(bvCur, rv);
    #pragma unroll
    for (int kc = 0; kc < 16; kc++) {
      float w4[4];
      ub4_(*(const uint2*)&WkBs[tTh][kc * 4], w4);
      #pragma unroll
      for (int jj = 0; jj < 4; jj++) {
        float4 s4 = *(const float4*)&Sl[kc * 4 + jj][lvi];
        rv[0] -= w4[jj] * s4.x; rv[1] -= w4[jj] * s4.y;
        rv[2] -= w4[jj] * s4.z; rv[3] -= w4[jj] * s4.w;
      }
    }
    *(float4*)&rl[tTh][lvi] = make_float4(rv[0], rv[1], rv[2], rv[3]);
    __syncthreads();
    {
      float ov[4] = {0.f, 0.f, 0.f, 0.f};
      #pragma unroll
      for (int sc = 0; sc < 16; sc++) {
        float m4[4];
        ub4_(*(const uint2*)&MGs[tTh][sc * 4], m4);
        #pragma unroll
        for (int jj = 0; jj < 4; jj++) {
          float4 r4 = *(const float4*)&rl[sc * 4 + jj][lvi];
          ov[0] += m4[jj] * r4.x; ov[1] += m4[jj] * r4.y;
          ov[2] += m4[jj] * r4.z; ov[3] += m4[jj] * r4.w;
        }
      }
      #pragma unroll
      for (int kc = 0; kc < 16; kc++) {
        float q4[4];
        ub4_(*(const uint2*)&Wqs[tTh][kc * 4], q4);
        #pragma unroll
        for (int jj = 0; jj < 4; jj++) {
          float4 s4 = *(const float4*)&Sl[kc * 4 + jj][lvi];
          ov[0] += q4[jj] * s4.x; ov[1] += q4[jj] * s4.y;
          ov[2] += q4[jj] * s4.z; ov[3] += q4[jj] * s4.w;
        }
      }
      *(uint2*)&oG[i * 4096 + tTh * 64 + vq * 16 + lvi] =
          pk4_(ov[0], ov[1], ov[2], ov[3]);
    }
    __syncthreads();
    {
      float4 s4 = *(const float4*)&Sl[tTh][lvi];
      float ge = geL[tTh];
      float sv[4] = {ge * s4.x, ge * s4.y, ge * s4.z, ge * s4.w};
      #pragma unroll
      for (int sc = 0; sc < 16; sc++) {
        float g4[4];
        ub4_(*(const uint2*)&SGs[tTh][sc * 4], g4);
        #pragma unroll
        for (int jj = 0; jj < 4; jj++) {
          float4 r4 = *(const float4*)&rl[sc * 4 + jj][lvi];
          sv[0] += g4[jj] * r4.x; sv[1] += g4[jj] * r4.y;
          sv[2] += g4[jj] * r4.z; sv[3] += g4[jj] * r4.w;
        }
      }
      *(float4*)&Sl[tTh][lvi] = make_float4(sv[0], sv[1], sv[2], sv[3]);
    }
    __syncthreads();
    if (ch < 31) {
      *(uint4*)&MGs[r0][cc] = p0;  *(uint4*)&MGs[r0][cc + 8] = p1;
      *(uint4*)&SGs[r0][cc] = p2;  *(uint4*)&SGs[r0][cc + 8] = p3;
      *(uint4*)&WkBs[r0][cc] = p4; *(uint4*)&WkBs[r0][cc + 8] = p5;
      *(uint4*)&Wqs[r0][cc] = p6;  *(uint4*)&Wqs[r0][cc + 8] = p7;
      if (tid < 64) geL[tid] = pge;
      bvCur = pbv;
      __syncthreads();
    }
  }
}

// ---------------------------------------------------------------------------
// RMS-norm + gate + split-pack into [hi|lo] bf16 GEMM operand.
// ---------------------------------------------------------------------------
__global__ __launch_bounds__(256) void onorm_pack(
    const ushort* __restrict__ o, const float* __restrict__ gate,
    const float* __restrict__ onw, ushort* __restrict__ out3) {
  int gi = blockIdx.x * 4 + (threadIdx.x >> 6);
  int lane = threadIdx.x & 63;
  int b = gi >> 15, h = (gi >> 11) & 15, t = gi & 2047;
  float ov = bf2f(o[(size_t)gi * 64 + lane]);
  float ms = wave_sum64(ov * ov) * (1.f / 64.f);
  float r = rsqrtf(ms + 1e-5f);
  float gv = gate[(size_t)(b * T_ + t) * 1024 + h * 64 + lane];
  float val = ov * r * onw[lane] * sigmoidf_(gv);
  ushort hi = f2bf(val);
  float rem = val - bf2f(hi);
  ushort lo = f2bf(rem);
  size_t m = (size_t)(b * T_ + t);
  int c = h * 64 + lane;
  out3[m * 2048 + c] = hi;
  out3[m * 2048 + 1024 + c] = lo;
}

extern "C" void kernel_launch(void* const* d_in, const int* in_sizes, int n_in,
                              void* d_out, int out_size, void* d_ws, size_t ws_size,
                              hipStream_t stream) {
  const float* hs    = (const float*)d_in[0];
  const float* Wq    = (const float*)d_in[1];
  const float* Wk    = (const float*)d_in[2];
  const float* Wv    = (const float*)d_in[3];
  const float* qcw   = (const float*)d_in[4];
  const float* qcb   = (const float*)d_in[5];
  const float* kcw   = (const float*)d_in[6];
  const float* kcb   = (const float*)d_in[7];
  const float* vcw   = (const float*)d_in[8];
  const float* vcb   = (const float*)d_in[9];
  const float* Wf1   = (const float*)d_in[10];
  const float* Wf2   = (const float*)d_in[11];
  const float* Wb    = (const float*)d_in[12];
  const float* A_log = (const float*)d_in[13];
  const float* dtb   = (const float*)d_in[14];
  const float* Wg1   = (const float*)d_in[15];
  const float* Wg2   = (const float*)d_in[16];
  const float* bg2   = (const float*)d_in[17];
  const float* onw   = (const float*)d_in[18];
  const float* Wo    = (const float*)d_in[19];
  float* out = (float*)d_out;

  char* ws = (char*)d_ws;
  ushort* hs3    = (ushort*)(ws);
  ushort* mMGSG  = (ushort*)(ws);
  ushort* obuf3  = (ushort*)(ws);
  ushort* mWkB   = (ushort*)(ws + 33554432);
  ushort* qkvhat = (ushort*)(ws + 50331648);
  float*  gate   = (float*)qkvhat;
  ushort* oG     = (ushort*)(ws + 83886080);
  ushort* grawB  = (ushort*)(ws + 100663296);
  float*  geG    = (float*)(ws + 117440512);
  ushort* mWqBv  = (ushort*)(ws + 117964800);
  char*   R4     = ws + 151519232;
  ushort* Wqkv3  = (ushort*)R4;
  ushort* Wfgb3  = (ushort*)R4;
  float*  f1g1b  = (float*)(R4 + 1572864);
  ushort* f1_3   = (ushort*)(R4 + 9961472);
  ushort* g1_3   = (ushort*)(R4 + 13107200);
  ushort* Wf2_3  = (ushort*)(R4 + 16252928);
  ushort* Wg2_3  = (ushort*)(R4 + 16646144);
  ushort* Wo3    = (ushort*)R4;

  dim3 blk(256);
  const int PK = 1024 * 1024;

  split_pack_A<<<dim3((M_ * 1024) / 256), blk, 0, stream>>>(hs, 1024, 1024, M_, hs3);
  pack_w3t<<<dim3(PK / 256), blk, 0, stream>>>(Wq, 1024, 1024, Wqkv3, 2048);
  pack_w3t<<<dim3(PK / 256), blk, 0, stream>>>(Wk, 1024, 1024, Wqkv3 + (size_t)1024 * 2048, 2048);
  pack_w3t<<<dim3(PK / 256), blk, 0, stream>>>(Wv, 1024, 1024, Wqkv3 + (size_t)2048 * 2048, 2048);
  gemm_glds<ushort><<<dim3(M_ / 128, 3072 / 128), blk, 0, stream>>>(
      hs3, Wqkv3, nullptr, qkvhat, M_, 3072, 2048);
  hipMemsetAsync(Wfgb3, 0, (size_t)256 * 2048 * 2, stream);
  pack_w3t<<<dim3((1024 * 64) / 256), blk, 0, stream>>>(Wf1, 1024, 64, Wfgb3, 2048);
  pack_w3t<<<dim3((1024 * 64) / 256), blk, 0, stream>>>(Wg1, 1024, 64, Wfgb3 + (size_t)64 * 2048, 2048);
  pack_w3t<<<dim3((1024 * 16) / 256), blk, 0, stream>>>(Wb, 1024, 16, Wfgb3 + (size_t)128 * 2048, 2048);
  gemm_glds<float><<<dim3(M_ / 128, 2), blk, 0, stream>>>(
      hs3, Wfgb3, nullptr, f1g1b, M_, 256, 2048);
  split_pack_A<<<dim3((M_ * 64) / 256), blk, 0, stream>>>(f1g1b, 256, 64, M_, f1_3);
  split_pack_A<<<dim3((M_ * 64) / 256), blk, 0, stream>>>(f1g1b + 64, 256, 64, M_, g1_3);
  pack_w3t<<<dim3((64 * 1024) / 256), blk, 0, stream>>>(Wf2, 64, 1024, Wf2_3, 128);
  gemm_glds<ushort><<<dim3(M_ / 128, 1024 / 128), blk, 0, stream>>>(
      f1_3, Wf2_3, nullptr, grawB, M_, 1024, 128);

  prep<<<dim3(64, 32), blk, 0, stream>>>(qkvhat, grawB, f1g1b,
                                         qcw, qcb, kcw, kcb, vcw, vcb,
                                         A_log, dtb, mMGSG, mWkB, mWqBv, geG);
  pack_w3t<<<dim3((64 * 1024) / 256), blk, 0, stream>>>(Wg2, 64, 1024, Wg2_3, 128);
  gemm_glds<float><<<dim3(M_ / 128, 1024 / 128), blk, 0, stream>>>(
      g1_3, Wg2_3, bg2, gate, M_, 1024, 128);

  scan<<<dim3(64, 4), blk, 0, stream>>>(mMGSG, mWkB, mWqBv, geG, oG);

  onorm_pack<<<dim3((M_ * H_) / 4), blk, 0, stream>>>(oG, gate, onw, obuf3);
  pack_w3t<<<dim3(PK / 256), blk, 0, stream>>>(Wo, 1024, 1024, Wo3, 2048);
  gemm_glds<float><<<dim3(M_ / 128, 1024 / 128), blk, 0, stream>>>(
      obuf3, Wo3, nullptr, out, M_, 1024, 2048);
}

// Round 12
// 711.904 us; speedup vs baseline: 4.9238x; 1.0394x over previous
//
#include <hip/hip_runtime.h>
#include <hip/hip_bf16.h>
#include <math.h>

#define H_ 16
#define HIDDEN_ 1024
#define BATCH_ 4
#define T_ 2048
#define M_ (BATCH_ * T_)   // 8192

typedef __attribute__((ext_vector_type(8))) __bf16 bf16x8;
typedef __attribute__((ext_vector_type(4))) float f32x4;

__device__ __forceinline__ float wave_sum64(float v) {
  #pragma unroll
  for (int m = 32; m >= 1; m >>= 1) v += __shfl_xor(v, m, 64);
  return v;
}
__device__ __forceinline__ float sigmoidf_(float x) { return 1.f / (1.f + expf(-x)); }
__device__ __forceinline__ float siluf_(float x) { return x / (1.f + expf(-x)); }
__device__ __forceinline__ float bf2f(ushort u) {
  unsigned int x = ((unsigned int)u) << 16;
  return __builtin_bit_cast(float, x);
}
__device__ __forceinline__ ushort f2bf(float f) {   // RNE
  unsigned int x = __builtin_bit_cast(unsigned int, f);
  unsigned int r = (x + 0x7fffu + ((x >> 16) & 1u)) >> 16;
  return (ushort)r;
}
__device__ __forceinline__ void ub4_(uint2 u, float f[4]) {
  f[0] = bf2f((ushort)u.x); f[1] = bf2f((ushort)(u.x >> 16));
  f[2] = bf2f((ushort)u.y); f[3] = bf2f((ushort)(u.y >> 16));
}
__device__ __forceinline__ void ub8_(uint4 u, float* f) {
  f[0] = bf2f((ushort)u.x); f[1] = bf2f((ushort)(u.x >> 16));
  f[2] = bf2f((ushort)u.y); f[3] = bf2f((ushort)(u.y >> 16));
  f[4] = bf2f((ushort)u.z); f[5] = bf2f((ushort)(u.z >> 16));
  f[6] = bf2f((ushort)u.w); f[7] = bf2f((ushort)(u.w >> 16));
}
__device__ __forceinline__ uint2 pk4_(float a, float b, float c, float d) {
  return make_uint2((uint)f2bf(a) | ((uint)f2bf(b) << 16),
                    (uint)f2bf(c) | ((uint)f2bf(d) << 16));
}
__device__ __forceinline__ uint4 pk8_(const float* t) {
  uint4 r;
  r.x = (uint)f2bf(t[0]) | ((uint)f2bf(t[1]) << 16);
  r.y = (uint)f2bf(t[2]) | ((uint)f2bf(t[3]) << 16);
  r.z = (uint)f2bf(t[4]) | ((uint)f2bf(t[5]) << 16);
  r.w = (uint)f2bf(t[6]) | ((uint)f2bf(t[7]) << 16);
  return r;
}
// async global -> LDS, 16B per lane (dest: wave-uniform base + lane*16)
__device__ __forceinline__ void gl16(const ushort* g, ushort* l) {
  __builtin_amdgcn_global_load_lds(
      (const __attribute__((address_space(1))) unsigned int*)g,
      (__attribute__((address_space(3))) unsigned int*)l, 16, 0, 0);
}

// ---------------------------------------------------------------------------
// Split-pack A: f32 [M,K] -> bf16 [M,2K] as [hi | lo]  (2-term split).
// ---------------------------------------------------------------------------
__global__ __launch_bounds__(256) void split_pack_A(
    const float* __restrict__ in, int inStride, int K, int M,
    ushort* __restrict__ out) {
  size_t tid = (size_t)blockIdx.x * 256 + threadIdx.x;
  if (tid >= (size_t)M * K) return;
  int k = (int)(tid % K);
  size_t m = tid / K;
  float x = in[m * inStride + k];
  ushort hi = f2bf(x);
  float rem = x - bf2f(hi);
  ushort lo = f2bf(rem);
  size_t o = m * (size_t)(2 * K);
  out[o + k] = hi;
  out[o + K + k] = lo;
}

// ---------------------------------------------------------------------------
// Pack weight W [K,N] f32 -> transposed bf16 [n][hi|hi] (2-term: B repeated).
// ---------------------------------------------------------------------------
__global__ __launch_bounds__(256) void pack_w3t(
    const float* __restrict__ W, int K, int N,
    ushort* __restrict__ out, int rowStride) {
  size_t tid = (size_t)blockIdx.x * 256 + threadIdx.x;
  if (tid >= (size_t)K * N) return;
  int k = (int)(tid % K);
  size_t n = tid / K;
  float x = W[(size_t)k * N + n];
  ushort hi = f2bf(x);
  size_t o = n * (size_t)rowStride;
  out[o + k] = hi;
  out[o + K + k] = hi;
}

// ---------------------------------------------------------------------------
// bf16 MFMA GEMM, m97 structure: global_load_lds(16B) staging into LINEAR
// LDS [128][32], 128x128 tile, 4 waves (2x2), 16x16x32 MFMA, BK=32.
// ---------------------------------------------------------------------------
template <typename OutT>
__global__ __launch_bounds__(256) void gemm_glds(
    const ushort* __restrict__ A, const ushort* __restrict__ Bt,
    const float* __restrict__ bias, OutT* __restrict__ C,
    int M, int N, int K) {
  __shared__ ushort As[128 * 32];
  __shared__ ushort Bs[128 * 32];
  const int tid = threadIdx.x;
  const int bm = blockIdx.x * 128, bn = blockIdx.y * 128;
  const int wid = tid >> 6, lane = tid & 63;
  const int wm = (wid >> 1) * 64, wn = (wid & 1) * 64;
  const int fr = lane & 15, fq = lane >> 4;
  const int srow = wid * 32 + (lane >> 2);
  const int scol = (lane & 3) * 8;

  f32x4 acc[4][4] = {};

  for (int k0 = 0; k0 < K; k0 += 32) {
    const ushort* gA = A + (size_t)(bm + srow) * K + k0 + scol;
    const ushort* gB = Bt + (size_t)(bn + srow) * K + k0 + scol;
    gl16(gA, &As[(wid * 32) * 32]);
    gl16(gA + (size_t)16 * K, &As[(wid * 32 + 16) * 32]);
    gl16(gB, &Bs[(wid * 32) * 32]);
    gl16(gB + (size_t)16 * K, &Bs[(wid * 32 + 16) * 32]);
    __syncthreads();

    bf16x8 af[4], bfr[4];
    #pragma unroll
    for (int i = 0; i < 4; i++) af[i] = *(const bf16x8*)&As[(wm + i * 16 + fr) * 32 + fq * 8];
    #pragma unroll
    for (int j = 0; j < 4; j++) bfr[j] = *(const bf16x8*)&Bs[(wn + j * 16 + fr) * 32 + fq * 8];
    #pragma unroll
    for (int i = 0; i < 4; i++)
      #pragma unroll
      for (int j = 0; j < 4; j++)
        acc[i][j] = __builtin_amdgcn_mfma_f32_16x16x32_bf16(af[i], bfr[j], acc[i][j], 0, 0, 0);
    __syncthreads();
  }

  #pragma unroll
  for (int i = 0; i < 4; i++) {
    #pragma unroll
    for (int j = 0; j < 4; j++) {
      int col = bn + wn + j * 16 + fr;
      float bv = bias ? bias[col] : 0.f;
      #pragma unroll
      for (int r = 0; r < 4; r++) {
        int row = bm + wm + i * 16 + fq * 4 + r;
        float v = acc[i][j][r] + bv;
        if constexpr (sizeof(OutT) == 2) {
          ((ushort*)C)[(size_t)row * N + col] = f2bf(v);
        } else {
          ((float*)C)[(size_t)row * N + col] = v;
        }
      }
    }
  }
}

// unpack element u (0..15) from a 4-row packed conv window x[8] (2 uint4/row)
#define XROW(x, tap, u) \
  bf2f((ushort)(((u) & 1) ? (((const uint*)&(x)[(tap) * 2 + ((u) >> 3)])[((u) >> 1) & 3] >> 16) \
                          : ((const uint*)&(x)[(tap) * 2 + ((u) >> 3)])[((u) >> 1) & 3]))
#define TAPW(w, tap) ((tap) == 0 ? (w).x : (tap) == 1 ? (w).y : (tap) == 2 ? (w).z : (w).w)

// ---------------------------------------------------------------------------
// prep v6: PH8 (MG = tril(Mqk)@G, SG = KhE^T@G — two dense 64x64x64 products)
// moved to MFMA. Storage changes: Mqk row-major [t][s] with strict-upper tiles
// zeroed; G stored transposed Gt[j][s] (Bt layout); KhE stored transposed
// KhET[k][s]. Rows padded to 72 ushorts for 16B-aligned ds_read_b128.
// ~51.2 KB LDS -> still 3 blocks/CU.
// ---------------------------------------------------------------------------
__global__ __launch_bounds__(256, 3) void prep(
    const ushort* __restrict__ qkv, const ushort* __restrict__ grawB,
    const float* __restrict__ f1g1b,
    const float* __restrict__ qcw, const float* __restrict__ qcb,
    const float* __restrict__ kcw, const float* __restrict__ kcb,
    const float* __restrict__ vcw, const float* __restrict__ vcb,
    const float* __restrict__ A_log, const float* __restrict__ dtb,
    ushort* __restrict__ mMGSG, ushort* __restrict__ mWkB,
    ushort* __restrict__ mWqBv, float* __restrict__ geG) {
  const int bh = blockIdx.x, ch = blockIdx.y;
  const int b = bh >> 4, h = bh & 15;
  const int i = bh * 32 + ch;
  const int t0 = ch * 64;
  const int tid = threadIdx.x;
  const int wA = tid >> 6, tA = tid & 63;
  const int tTh = tid >> 2, c4 = tid & 3, kb = c4 * 16;
  const int c0 = h * 64 + kb;

  __shared__ __align__(16) ushort KtU[64][72];  // kn -> K~ bf16 ; PH7+: Gt (G^T)
  __shared__ __align__(16) ushort KhU[64][72];  // K^ bf16
  __shared__ __align__(16) ushort QtU[64][72];  // qn -> Q~ bf16 ; PH7: KhET
  __shared__ __align__(16) float cM[64][72];    // g -> cumsum; PH6+: Mqk/MkkT bf16
  __shared__ __align__(16) float dlog[17][68];
  __shared__ float betaL[64];
  ushort* cMu = (ushort*)&cM[0][0];
  ushort (*MqkRM)[72] = (ushort(*)[72])cMu;            // Mqk[t][s] row-major
  ushort (*MkkT)[72] = (ushort(*)[72])(cMu + 64 * 72); // Mkk^T[s][t]
  ushort (*Gt)[72] = KtU;                              // G^T[j][s]
  ushort (*KhET)[72] = QtU;                            // KhE^T[k][s]

  // ---- PH0: conv+SiLU+norm for q,k straight from global (vector loads) ----
  {
    const uint4 z4 = make_uint4(0, 0, 0, 0);
    // q
    {
      uint4 x[8];
      #pragma unroll
      for (int tap = 0; tap < 4; tap++) {
        int tr = t0 + tTh - 3 + tap;
        if (tr >= 0) {
          const uint4* p = (const uint4*)(qkv + (size_t)(b * T_ + tr) * 3072 + c0);
          x[tap * 2] = p[0]; x[tap * 2 + 1] = p[1];
        } else { x[tap * 2] = z4; x[tap * 2 + 1] = z4; }
      }
      float qa[16], s = 0.f;
      #pragma unroll
      for (int u = 0; u < 16; u++) {
        float4 w = ((const float4*)qcw)[c0 + u];
        float a = qcb[c0 + u];
        #pragma unroll
        for (int tap = 0; tap < 4; tap++) a += XROW(x, tap, u) * TAPW(w, tap);
        a = siluf_(a);
        qa[u] = a; s += a * a;
      }
      s += __shfl_xor(s, 1, 64); s += __shfl_xor(s, 2, 64);
      float qs = 0.125f / (sqrtf(s) + 1e-6f);
      #pragma unroll
      for (int u = 0; u < 16; u++) qa[u] *= qs;
      *(uint4*)&QtU[tTh][kb] = pk8_(&qa[0]);
      *(uint4*)&QtU[tTh][kb + 8] = pk8_(&qa[8]);
    }
    // k
    {
      uint4 x[8];
      #pragma unroll
      for (int tap = 0; tap < 4; tap++) {
        int tr = t0 + tTh - 3 + tap;
        if (tr >= 0) {
          const uint4* p = (const uint4*)(qkv + (size_t)(b * T_ + tr) * 3072 + 1024 + c0);
          x[tap * 2] = p[0]; x[tap * 2 + 1] = p[1];
        } else { x[tap * 2] = z4; x[tap * 2 + 1] = z4; }
      }
      float ka[16], s = 0.f;
      #pragma unroll
      for (int u = 0; u < 16; u++) {
        float4 w = ((const float4*)kcw)[c0 + u];
        float a = kcb[c0 + u];
        #pragma unroll
        for (int tap = 0; tap < 4; tap++) a += XROW(x, tap, u) * TAPW(w, tap);
        a = siluf_(a);
        ka[u] = a; s += a * a;
      }
      s += __shfl_xor(s, 1, 64); s += __shfl_xor(s, 2, 64);
      float ks = 1.f / (sqrtf(s) + 1e-6f);
      #pragma unroll
      for (int u = 0; u < 16; u++) ka[u] *= ks;
      *(uint4*)&KtU[tTh][kb] = pk8_(&ka[0]);
      *(uint4*)&KtU[tTh][kb + 8] = pk8_(&ka[8]);
    }
    // g = -A*softplus(graw+dtb) -> cM; beta
    {
      float Aexp = expf(A_log[h]);
      const ushort* gr = grawB + (size_t)(b * T_ + t0 + tTh) * 1024 + c0;
      uint4 ga = *(const uint4*)gr;
      uint4 gb = *(const uint4*)(gr + 8);
      float xv[16];
      ub8_(ga, &xv[0]); ub8_(gb, &xv[8]);
      #pragma unroll
      for (int u = 0; u < 16; u++) {
        float x = xv[u] + dtb[c0 + u];
        float sp = (x > 20.f) ? x : log1pf(expf(x));
        cM[tTh][kb + u] = -Aexp * sp;
      }
      if (tid < 64)
        betaL[tid] = sigmoidf_(f1g1b[(size_t)(b * T_ + t0 + tid) * 256 + 128 + h]);
    }
  }
  __syncthreads();
  // ---- PH2: cumsum within quarters ----
  {
    const int q = wA, k = tA;
    float run = 0.f;
    #pragma unroll
    for (int u = 0; u < 16; u++) { run += cM[q * 16 + u][k]; cM[q * 16 + u][k] = run; }
    dlog[q][k] = run;
  }
  __syncthreads();
  // ---- PH3: apply segment offsets ----
  {
    const int q = wA, k = tA;
    if (q > 0) {
      float off = dlog[0][k];
      if (q > 1) off += dlog[1][k];
      if (q > 2) off += dlog[2][k];
      #pragma unroll
      for (int u = 0; u < 16; u++) cM[q * 16 + u][k] += off;
    }
  }
  __syncthreads();
  // ---- PH4: block-base log decays ----
  for (int idx = tid; idx < 17 * 64; idx += 256) {
    int P = idx >> 6, k = idx & 63;
    dlog[P][k] = (P == 0) ? 0.f : cM[4 * P - 1][k];
  }
  __syncthreads();
  // ---- PH5: K~/K^/Q~ in place (bf16; cM dead after this) ----
  {
    const int P5 = tTh >> 2;
    float knv[16], qnv[16];
    ub8_(*(const uint4*)&KtU[tTh][kb], &knv[0]);
    ub8_(*(const uint4*)&KtU[tTh][kb + 8], &knv[8]);
    ub8_(*(const uint4*)&QtU[tTh][kb], &qnv[0]);
    ub8_(*(const uint4*)&QtU[tTh][kb + 8], &qnv[8]);
    float ktv[16], khv[16], qtv[16];
    #pragma unroll
    for (int u = 0; u < 16; u++) {
      int k = kb + u;
      float c = cM[tTh][k], d = dlog[P5][k];
      float e1 = expf(c - d);
      float e2 = expf(d - c);
      ktv[u] = knv[u] * e1;
      khv[u] = knv[u] * e2;
      qtv[u] = qnv[u] * e1;
    }
    *(uint4*)&KtU[tTh][kb] = pk8_(&ktv[0]);
    *(uint4*)&KtU[tTh][kb + 8] = pk8_(&ktv[8]);
    *(uint4*)&KhU[tTh][kb] = pk8_(&khv[0]);
    *(uint4*)&KhU[tTh][kb + 8] = pk8_(&khv[8]);
    *(uint4*)&QtU[tTh][kb] = pk8_(&qtv[0]);
    *(uint4*)&QtU[tTh][kb + 8] = pk8_(&qtv[8]);
  }
  __syncthreads();
  // ---- PH6: Wq/WkB/bv/ge outputs + Mqk-upper zeroing + M-build ----
  {
    const int P = tTh >> 2;
    float bt = betaL[tTh];
    float qtv[16], ktv[16];
    ub8_(*(const uint4*)&QtU[tTh][kb], &qtv[0]);
    ub8_(*(const uint4*)&QtU[tTh][kb + 8], &qtv[8]);
    ub8_(*(const uint4*)&KtU[tTh][kb], &ktv[0]);
    ub8_(*(const uint4*)&KtU[tTh][kb + 8], &ktv[8]);
    float tq[16], tk[16];
    #pragma unroll
    for (int u = 0; u < 16; u++) {
      int k = kb + u;
      float e = expf(dlog[P][k]);
      tq[u] = qtv[u] * e;
      tk[u] = bt * ktv[u] * e;
    }
    ushort* pq = mWqBv + (size_t)i * 8192 + tTh * 64 + kb;
    ushort* pk = mWkB + (size_t)i * 4096 + tTh * 64 + kb;
    *(uint4*)&pq[0] = pk8_(&tq[0]);
    *(uint4*)&pq[8] = pk8_(&tq[8]);
    *(uint4*)&pk[0] = pk8_(&tk[0]);
    *(uint4*)&pk[8] = pk8_(&tk[8]);

    // bv = beta * silu(conv(v)) — direct-global vector conv
    {
      const uint4 z4 = make_uint4(0, 0, 0, 0);
      uint4 x[8];
      #pragma unroll
      for (int tap = 0; tap < 4; tap++) {
        int tr = t0 + tTh - 3 + tap;
        if (tr >= 0) {
          const uint4* p = (const uint4*)(qkv + (size_t)(b * T_ + tr) * 3072 + 2048 + c0);
          x[tap * 2] = p[0]; x[tap * 2 + 1] = p[1];
        } else { x[tap * 2] = z4; x[tap * 2 + 1] = z4; }
      }
      float av[16];
      #pragma unroll
      for (int u = 0; u < 16; u++) {
        float4 w = ((const float4*)vcw)[c0 + u];
        float a = vcb[c0 + u];
        #pragma unroll
        for (int tap = 0; tap < 4; tap++) a += XROW(x, tap, u) * TAPW(w, tap);
        av[u] = bt * siluf_(a);
      }
      ushort* pb = mWqBv + (size_t)i * 8192 + 4096 + tTh * 64 + kb;
      *(uint4*)&pb[0] = pk8_(&av[0]);
      *(uint4*)&pb[8] = pk8_(&av[8]);
    }

    if (tid < 64) geG[(size_t)i * 64 + tid] = expf(dlog[16][tid]);

    // zero Mqk strict-upper TILES + pad cols (disjoint from M-build writes)
    for (int idx = tid; idx < 64 * 72; idx += 256) {
      int t = idx / 72, s = idx - t * 72;
      if (s >= 64 || (s >> 2) > (t >> 2)) MqkRM[t][s] = 0;
    }

    // M-build: 272 4x4 tiles, R recomputed on the fly (all exponents <= 0)
    for (int tile = tid; tile < 272; tile += 256) {
      int mq = (tile >= 136) ? 1 : 0;
      int f = tile - mq * 136;
      int rem = f, P2 = 0;
      while (rem >= P2 + 1) { rem -= P2 + 1; ++P2; }
      int J = rem;
      const ushort (*Xr)[72] = mq ? QtU : KtU;
      float acc[4][4] = {};
      for (int kc = 0; kc < 16; kc++) {
        float av0[4], av1[4], av2[4], av3[4];
        ub4_(*(const uint2*)&Xr[4 * P2 + 0][kc * 4], av0);
        ub4_(*(const uint2*)&Xr[4 * P2 + 1][kc * 4], av1);
        ub4_(*(const uint2*)&Xr[4 * P2 + 2][kc * 4], av2);
        ub4_(*(const uint2*)&Xr[4 * P2 + 3][kc * 4], av3);
        float4 dp = *(const float4*)&dlog[P2][kc * 4];
        float4 dj = *(const float4*)&dlog[J][kc * 4];
        float rv[4] = {expf(dp.x - dj.x), expf(dp.y - dj.y),
                       expf(dp.z - dj.z), expf(dp.w - dj.w)};
        #pragma unroll
        for (int c = 0; c < 4; c++) {
          float kv[4];
          ub4_(*(const uint2*)&KhU[4 * J + c][kc * 4], kv);
          float bx = kv[0] * rv[0], by = kv[1] * rv[1], bz = kv[2] * rv[2], bw = kv[3] * rv[3];
          acc[0][c] += av0[0] * bx + av0[1] * by + av0[2] * bz + av0[3] * bw;
          acc[1][c] += av1[0] * bx + av1[1] * by + av1[2] * bz + av1[3] * bw;
          acc[2][c] += av2[0] * bx + av2[1] * by + av2[2] * bz + av2[3] * bw;
          acc[3][c] += av3[0] * bx + av3[1] * by + av3[2] * bz + av3[3] * bw;
        }
      }
      if (mq && P2 == J) {   // inclusive-tril mask inside diag tile
        #pragma unroll
        for (int c = 0; c < 4; c++)
          #pragma unroll
          for (int r = 0; r < 4; r++)
            if (c > r) acc[r][c] = 0.f;
      }
      if (mq) {
        // Mqk row-major: [t = 4P2+r][s = 4J+c]
        #pragma unroll
        for (int r = 0; r < 4; r++)
          *(uint2*)&MqkRM[4 * P2 + r][4 * J] =
              pk4_(acc[r][0], acc[r][1], acc[r][2], acc[r][3]);
      } else {
        // Mkk transposed (solve reads rows of MkkT)
        #pragma unroll
        for (int c = 0; c < 4; c++) {
          uint2 w;
          w.x = (uint)f2bf(acc[0][c]) | ((uint)f2bf(acc[1][c]) << 16);
          w.y = (uint)f2bf(acc[2][c]) | ((uint)f2bf(acc[3][c]) << 16);
          *(uint2*)&MkkT[4 * J + c][4 * P2] = w;
        }
      }
    }
  }
  __syncthreads();
  // ---- PH7: KhET (transposed) into QtU + G-solve writing Gt (transposed) ----
  for (int idx = tid; idx < 4096; idx += 256) {
    int k = idx >> 6, s = idx & 63;
    KhET[k][s] = f2bf(bf2f(KhU[s][k]) * expf(dlog[16][k] - dlog[s >> 2][k]));
  }
  {
    const int j = tTh, q = c4;
    float acc[16], gsv[16];
    #pragma unroll
    for (int u = 0; u < 16; u++) { acc[u] = 0.f; gsv[u] = 0.f; }
    for (int s = 0; s < 64; s++) {
      int q0 = s >> 4;
      float g = 0.f;
      if (q == q0) {
        g = ((s == j) ? 1.f : 0.f) - betaL[s] * acc[s & 15];
        gsv[s & 15] = g;
      }
      g = __shfl(g, 4 * (j & 15) + q0, 64);
      #pragma unroll
      for (int u = 0; u < 4; u++) {
        uint2 m2 = *(const uint2*)&MkkT[s][q * 16 + u * 4];
        acc[u * 4 + 0] += bf2f((ushort)m2.x) * g;
        acc[u * 4 + 1] += bf2f((ushort)(m2.x >> 16)) * g;
        acc[u * 4 + 2] += bf2f((ushort)m2.y) * g;
        acc[u * 4 + 3] += bf2f((ushort)(m2.y >> 16)) * g;
      }
    }
    // Gt[j][s] = G[s][j]  (Gt overlays dead KtU; contiguous 16-elem pack)
    *(uint4*)&Gt[j][q * 16] = pk8_(&gsv[0]);
    *(uint4*)&Gt[j][q * 16 + 8] = pk8_(&gsv[8]);
  }
  __syncthreads();
  // ---- PH8 (MFMA): MG = tril(Mqk)@G, SG = KhET@G ----
  {
    const int wid = tid >> 6, lane = tid & 63;
    const int fr = lane & 15, fq = lane >> 4;
    const int wrow = wid * 16;
    bf16x8 aM[2], aS[2];
    #pragma unroll
    for (int kt = 0; kt < 2; kt++) {
      aM[kt] = *(const bf16x8*)&MqkRM[wrow + fr][kt * 32 + fq * 8];
      aS[kt] = *(const bf16x8*)&KhET[wrow + fr][kt * 32 + fq * 8];
    }
    #pragma unroll
    for (int jt = 0; jt < 4; jt++) {
      bf16x8 bG[2];
      #pragma unroll
      for (int kt = 0; kt < 2; kt++)
        bG[kt] = *(const bf16x8*)&Gt[jt * 16 + fr][kt * 32 + fq * 8];
      f32x4 accM = {}, accS = {};
      #pragma unroll
      for (int kt = 0; kt < 2; kt++) {
        accM = __builtin_amdgcn_mfma_f32_16x16x32_bf16(aM[kt], bG[kt], accM, 0, 0, 0);
        accS = __builtin_amdgcn_mfma_f32_16x16x32_bf16(aS[kt], bG[kt], accS, 0, 0, 0);
      }
      #pragma unroll
      for (int r = 0; r < 4; r++) {
        int row = wrow + fq * 4 + r, col = jt * 16 + fr;
        mMGSG[(size_t)i * 8192 + row * 64 + col] = f2bf(accM[r]);
        mMGSG[(size_t)i * 8192 + 4096 + row * 64 + col] = f2bf(accS[r]);
      }
    }
  }
}

// ---------------------------------------------------------------------------
// scan: sequential-over-chunks state propagation. Grid (64 bh, 4 vq).
// Per chunk: r = bv - WkB@S; O = MG@r + Wq@S; S = ge*S + SG@r.
// ---------------------------------------------------------------------------
__global__ __launch_bounds__(256) void scan(
    const ushort* __restrict__ mMGSG, const ushort* __restrict__ mWkB,
    const ushort* __restrict__ mWqBv, const float* __restrict__ geG,
    ushort* __restrict__ oG) {
  const int bh = blockIdx.x, vq = blockIdx.y;
  const int tid = threadIdx.x;
  const int tTh = tid >> 2, c4 = tid & 3, lvi = c4 * 4;
  const int r0 = tid >> 2, cc = (tid & 3) * 16;

  __shared__ ushort MGs[64][72], SGs[64][72], WkBs[64][72], Wqs[64][72];
  __shared__ __align__(16) float Sl[64][20], rl[64][20];
  __shared__ float geL[64];

  *(float4*)&Sl[tTh][lvi] = make_float4(0.f, 0.f, 0.f, 0.f);

  const size_t i0 = (size_t)bh * 32;
  {
    uint4 a0 = *(const uint4*)&mMGSG[i0 * 8192 + tid * 16];
    uint4 a1 = *(const uint4*)&mMGSG[i0 * 8192 + tid * 16 + 8];
    uint4 b0 = *(const uint4*)&mMGSG[i0 * 8192 + 4096 + tid * 16];
    uint4 b1 = *(const uint4*)&mMGSG[i0 * 8192 + 4096 + tid * 16 + 8];
    uint4 c0 = *(const uint4*)&mWkB[i0 * 4096 + tid * 16];
    uint4 c1 = *(const uint4*)&mWkB[i0 * 4096 + tid * 16 + 8];
    uint4 d0 = *(const uint4*)&mWqBv[i0 * 8192 + tid * 16];
    uint4 d1 = *(const uint4*)&mWqBv[i0 * 8192 + tid * 16 + 8];
    *(uint4*)&MGs[r0][cc] = a0;  *(uint4*)&MGs[r0][cc + 8] = a1;
    *(uint4*)&SGs[r0][cc] = b0;  *(uint4*)&SGs[r0][cc + 8] = b1;
    *(uint4*)&WkBs[r0][cc] = c0; *(uint4*)&WkBs[r0][cc + 8] = c1;
    *(uint4*)&Wqs[r0][cc] = d0;  *(uint4*)&Wqs[r0][cc + 8] = d1;
    if (tid < 64) geL[tid] = geG[i0 * 64 + tid];
  }
  uint2 bvCur = *(const uint2*)&mWqBv[i0 * 8192 + 4096 + tTh * 64 + vq * 16 + lvi];
  __syncthreads();

  for (int ch = 0; ch < 32; ch++) {
    const size_t i = i0 + ch;
    uint4 p0, p1, p2, p3, p4, p5, p6, p7;
    uint2 pbv;
    float pge = 0.f;
    if (ch < 31) {
      const size_t i2 = i + 1;
      p0 = *(const uint4*)&mMGSG[i2 * 8192 + tid * 16];
      p1 = *(const uint4*)&mMGSG[i2 * 8192 + tid * 16 + 8];
      p2 = *(const uint4*)&mMGSG[i2 * 8192 + 4096 + tid * 16];
      p3 = *(const uint4*)&mMGSG[i2 * 8192 + 4096 + tid * 16 + 8];
      p4 = *(const uint4*)&mWkB[i2 * 4096 + tid * 16];
      p5 = *(const uint4*)&mWkB[i2 * 4096 + tid * 16 + 8];
      p6 = *(const uint4*)&mWqBv[i2 * 8192 + tid * 16];
      p7 = *(const uint4*)&mWqBv[i2 * 8192 + tid * 16 + 8];
      pbv = *(const uint2*)&mWqBv[i2 * 8192 + 4096 + tTh * 64 + vq * 16 + lvi];
      if (tid < 64) pge = geG[i2 * 64 + tid];
    }
    float rv[4];
    ub4_(bvCur, rv);
    #pragma unroll
    for (int kc = 0; kc < 16; kc++) {
      float w4[4];
      ub4_(*(const uint2*)&WkBs[tTh][kc * 4], w4);
      #pragma unroll
      for (int jj = 0; jj < 4; jj++) {
        float4 s4 = *(const float4*)&Sl[kc * 4 + jj][lvi];
        rv[0] -= w4[jj] * s4.x; rv[1] -= w4[jj] * s4.y;
        rv[2] -= w4[jj] * s4.z; rv[3] -= w4[jj] * s4.w;
      }
    }
    *(float4*)&rl[tTh][lvi] = make_float4(rv[0], rv[1], rv[2], rv[3]);
    __syncthreads();
    {
      float ov[4] = {0.f, 0.f, 0.f, 0.f};
      #pragma unroll
      for (int sc = 0; sc < 16; sc++) {
        float m4[4];
        ub4_(*(const uint2*)&MGs[tTh][sc * 4], m4);
        #pragma unroll
        for (int jj = 0; jj < 4; jj++) {
          float4 r4 = *(const float4*)&rl[sc * 4 + jj][lvi];
          ov[0] += m4[jj] * r4.x; ov[1] += m4[jj] * r4.y;
          ov[2] += m4[jj] * r4.z; ov[3] += m4[jj] * r4.w;
        }
      }
      #pragma unroll
      for (int kc = 0; kc < 16; kc++) {
        float q4[4];
        ub4_(*(const uint2*)&Wqs[tTh][kc * 4], q4);
        #pragma unroll
        for (int jj = 0; jj < 4; jj++) {
          float4 s4 = *(const float4*)&Sl[kc * 4 + jj][lvi];
          ov[0] += q4[jj] * s4.x; ov[1] += q4[jj] * s4.y;
          ov[2] += q4[jj] * s4.z; ov[3] += q4[jj] * s4.w;
        }
      }
      *(uint2*)&oG[i * 4096 + tTh * 64 + vq * 16 + lvi] =
          pk4_(ov[0], ov[1], ov[2], ov[3]);
    }
    __syncthreads();
    {
      float4 s4 = *(const float4*)&Sl[tTh][lvi];
      float ge = geL[tTh];
      float sv[4] = {ge * s4.x, ge * s4.y, ge * s4.z, ge * s4.w};
      #pragma unroll
      for (int sc = 0; sc < 16; sc++) {
        float g4[4];
        ub4_(*(const uint2*)&SGs[tTh][sc * 4], g4);
        #pragma unroll
        for (int jj = 0; jj < 4; jj++) {
          float4 r4 = *(const float4*)&rl[sc * 4 + jj][lvi];
          sv[0] += g4[jj] * r4.x; sv[1] += g4[jj] * r4.y;
          sv[2] += g4[jj] * r4.z; sv[3] += g4[jj] * r4.w;
        }
      }
      *(float4*)&Sl[tTh][lvi] = make_float4(sv[0], sv[1], sv[2], sv[3]);
    }
    __syncthreads();
    if (ch < 31) {
      *(uint4*)&MGs[r0][cc] = p0;  *(uint4*)&MGs[r0][cc + 8] = p1;
      *(uint4*)&SGs[r0][cc] = p2;  *(uint4*)&SGs[r0][cc + 8] = p3;
      *(uint4*)&WkBs[r0][cc] = p4; *(uint4*)&WkBs[r0][cc + 8] = p5;
      *(uint4*)&Wqs[r0][cc] = p6;  *(uint4*)&Wqs[r0][cc + 8] = p7;
      if (tid < 64) geL[tid] = pge;
      bvCur = pbv;
      __syncthreads();
    }
  }
}

// ---------------------------------------------------------------------------
// RMS-norm + gate + split-pack into [hi|lo] bf16 GEMM operand.
// ---------------------------------------------------------------------------
__global__ __launch_bounds__(256) void onorm_pack(
    const ushort* __restrict__ o, const float* __restrict__ gate,
    const float* __restrict__ onw, ushort* __restrict__ out3) {
  int gi = blockIdx.x * 4 + (threadIdx.x >> 6);
  int lane = threadIdx.x & 63;
  int b = gi >> 15, h = (gi >> 11) & 15, t = gi & 2047;
  float ov = bf2f(o[(size_t)gi * 64 + lane]);
  float ms = wave_sum64(ov * ov) * (1.f / 64.f);
  float r = rsqrtf(ms + 1e-5f);
  float gv = gate[(size_t)(b * T_ + t) * 1024 + h * 64 + lane];
  float val = ov * r * onw[lane] * sigmoidf_(gv);
  ushort hi = f2bf(val);
  float rem = val - bf2f(hi);
  ushort lo = f2bf(rem);
  size_t m = (size_t)(b * T_ + t);
  int c = h * 64 + lane;
  out3[m * 2048 + c] = hi;
  out3[m * 2048 + 1024 + c] = lo;
}

extern "C" void kernel_launch(void* const* d_in, const int* in_sizes, int n_in,
                              void* d_out, int out_size, void* d_ws, size_t ws_size,
                              hipStream_t stream) {
  const float* hs    = (const float*)d_in[0];
  const float* Wq    = (const float*)d_in[1];
  const float* Wk    = (const float*)d_in[2];
  const float* Wv    = (const float*)d_in[3];
  const float* qcw   = (const float*)d_in[4];
  const float* qcb   = (const float*)d_in[5];
  const float* kcw   = (const float*)d_in[6];
  const float* kcb   = (const float*)d_in[7];
  const float* vcw   = (const float*)d_in[8];
  const float* vcb   = (const float*)d_in[9];
  const float* Wf1   = (const float*)d_in[10];
  const float* Wf2   = (const float*)d_in[11];
  const float* Wb    = (const float*)d_in[12];
  const float* A_log = (const float*)d_in[13];
  const float* dtb   = (const float*)d_in[14];
  const float* Wg1   = (const float*)d_in[15];
  const float* Wg2   = (const float*)d_in[16];
  const float* bg2   = (const float*)d_in[17];
  const float* onw   = (const float*)d_in[18];
  const float* Wo    = (const float*)d_in[19];
  float* out = (float*)d_out;

  char* ws = (char*)d_ws;
  ushort* hs3    = (ushort*)(ws);
  ushort* mMGSG  = (ushort*)(ws);
  ushort* obuf3  = (ushort*)(ws);
  ushort* mWkB   = (ushort*)(ws + 33554432);
  ushort* qkvhat = (ushort*)(ws + 50331648);
  float*  gate   = (float*)qkvhat;
  ushort* oG     = (ushort*)(ws + 83886080);
  ushort* grawB  = (ushort*)(ws + 100663296);
  float*  geG    = (float*)(ws + 117440512);
  ushort* mWqBv  = (ushort*)(ws + 117964800);
  char*   R4     = ws + 151519232;
  ushort* Wqkv3  = (ushort*)R4;
  ushort* Wfgb3  = (ushort*)R4;
  float*  f1g1b  = (float*)(R4 + 1572864);
  ushort* f1_3   = (ushort*)(R4 + 9961472);
  ushort* g1_3   = (ushort*)(R4 + 13107200);
  ushort* Wf2_3  = (ushort*)(R4 + 16252928);
  ushort* Wg2_3  = (ushort*)(R4 + 16646144);
  ushort* Wo3    = (ushort*)R4;

  dim3 blk(256);
  const int PK = 1024 * 1024;

  split_pack_A<<<dim3((M_ * 1024) / 256), blk, 0, stream>>>(hs, 1024, 1024, M_, hs3);
  pack_w3t<<<dim3(PK / 256), blk, 0, stream>>>(Wq, 1024, 1024, Wqkv3, 2048);
  pack_w3t<<<dim3(PK / 256), blk, 0, stream>>>(Wk, 1024, 1024, Wqkv3 + (size_t)1024 * 2048, 2048);
  pack_w3t<<<dim3(PK / 256), blk, 0, stream>>>(Wv, 1024, 1024, Wqkv3 + (size_t)2048 * 2048, 2048);
  gemm_glds<ushort><<<dim3(M_ / 128, 3072 / 128), blk, 0, stream>>>(
      hs3, Wqkv3, nullptr, qkvhat, M_, 3072, 2048);
  hipMemsetAsync(Wfgb3, 0, (size_t)256 * 2048 * 2, stream);
  pack_w3t<<<dim3((1024 * 64) / 256), blk, 0, stream>>>(Wf1, 1024, 64, Wfgb3, 2048);
  pack_w3t<<<dim3((1024 * 64) / 256), blk, 0, stream>>>(Wg1, 1024, 64, Wfgb3 + (size_t)64 * 2048, 2048);
  pack_w3t<<<dim3((1024 * 16) / 256), blk, 0, stream>>>(Wb, 1024, 16, Wfgb3 + (size_t)128 * 2048, 2048);
  gemm_glds<float><<<dim3(M_ / 128, 2), blk, 0, stream>>>(
      hs3, Wfgb3, nullptr, f1g1b, M_, 256, 2048);
  split_pack_A<<<dim3((M_ * 64) / 256), blk, 0, stream>>>(f1g1b, 256, 64, M_, f1_3);
  split_pack_A<<<dim3((M_ * 64) / 256), blk, 0, stream>>>(f1g1b + 64, 256, 64, M_, g1_3);
  pack_w3t<<<dim3((64 * 1024) / 256), blk, 0, stream>>>(Wf2, 64, 1024, Wf2_3, 128);
  gemm_glds<ushort><<<dim3(M_ / 128, 1024 / 128), blk, 0, stream>>>(
      f1_3, Wf2_3, nullptr, grawB, M_, 1024, 128);

  prep<<<dim3(64, 32), blk, 0, stream>>>(qkvhat, grawB, f1g1b,
                                         qcw, qcb, kcw, kcb, vcw, vcb,
                                         A_log, dtb, mMGSG, mWkB, mWqBv, geG);
  pack_w3t<<<dim3((64 * 1024) / 256), blk, 0, stream>>>(Wg2, 64, 1024, Wg2_3, 128);
  gemm_glds<float><<<dim3(M_ / 128, 1024 / 128), blk, 0, stream>>>(
      g1_3, Wg2_3, bg2, gate, M_, 1024, 128);

  scan<<<dim3(64, 4), blk, 0, stream>>>(mMGSG, mWkB, mWqBv, geG, oG);

  onorm_pack<<<dim3((M_ * H_) / 4), blk, 0, stream>>>(oG, gate, onw, obuf3);
  pack_w3t<<<dim3(PK / 256), blk, 0, stream>>>(Wo, 1024, 1024, Wo3, 2048);
  gemm_glds<float><<<dim3(M_ / 128, 1024 / 128), blk, 0, stream>>>(
      obuf3, Wo3, nullptr, out, M_, 1024, 2048);
}

// Round 13
// 649.817 us; speedup vs baseline: 5.3943x; 1.0955x over previous
//
#include <hip/hip_runtime.h>
#include <hip/hip_bf16.h>
#include <math.h>

#define H_ 16
#define HIDDEN_ 1024
#define BATCH_ 4
#define T_ 2048
#define M_ (BATCH_ * T_)   // 8192

typedef __attribute__((ext_vector_type(8))) __bf16 bf16x8;
typedef __attribute__((ext_vector_type(4))) float f32x4;

__device__ __forceinline__ float fexp_(float x) { return __expf(x); }       // v_exp_f32
__device__ __forceinline__ float frcp_(float x) { return __builtin_amdgcn_rcpf(x); }
__device__ __forceinline__ float wave_sum64(float v) {
  #pragma unroll
  for (int m = 32; m >= 1; m >>= 1) v += __shfl_xor(v, m, 64);
  return v;
}
__device__ __forceinline__ float sigmoidf_(float x) { return frcp_(1.f + fexp_(-x)); }
__device__ __forceinline__ float siluf_(float x) { return x * frcp_(1.f + fexp_(-x)); }
__device__ __forceinline__ float bf2f(ushort u) {
  unsigned int x = ((unsigned int)u) << 16;
  return __builtin_bit_cast(float, x);
}
__device__ __forceinline__ ushort f2bf(float f) {   // RNE
  unsigned int x = __builtin_bit_cast(unsigned int, f);
  unsigned int r = (x + 0x7fffu + ((x >> 16) & 1u)) >> 16;
  return (ushort)r;
}
__device__ __forceinline__ void ub2_(uint u, float f[2]) {
  f[0] = bf2f((ushort)u); f[1] = bf2f((ushort)(u >> 16));
}
__device__ __forceinline__ void ub4_(uint2 u, float f[4]) {
  f[0] = bf2f((ushort)u.x); f[1] = bf2f((ushort)(u.x >> 16));
  f[2] = bf2f((ushort)u.y); f[3] = bf2f((ushort)(u.y >> 16));
}
__device__ __forceinline__ void ub8_(uint4 u, float* f) {
  f[0] = bf2f((ushort)u.x); f[1] = bf2f((ushort)(u.x >> 16));
  f[2] = bf2f((ushort)u.y); f[3] = bf2f((ushort)(u.y >> 16));
  f[4] = bf2f((ushort)u.z); f[5] = bf2f((ushort)(u.z >> 16));
  f[6] = bf2f((ushort)u.w); f[7] = bf2f((ushort)(u.w >> 16));
}
__device__ __forceinline__ uint pk2_(float a, float b) {
  return (uint)f2bf(a) | ((uint)f2bf(b) << 16);
}
__device__ __forceinline__ uint2 pk4_(float a, float b, float c, float d) {
  return make_uint2((uint)f2bf(a) | ((uint)f2bf(b) << 16),
                    (uint)f2bf(c) | ((uint)f2bf(d) << 16));
}
__device__ __forceinline__ uint4 pk8_(const float* t) {
  uint4 r;
  r.x = (uint)f2bf(t[0]) | ((uint)f2bf(t[1]) << 16);
  r.y = (uint)f2bf(t[2]) | ((uint)f2bf(t[3]) << 16);
  r.z = (uint)f2bf(t[4]) | ((uint)f2bf(t[5]) << 16);
  r.w = (uint)f2bf(t[6]) | ((uint)f2bf(t[7]) << 16);
  return r;
}
// async global -> LDS, 16B per lane (dest: wave-uniform base + lane*16)
__device__ __forceinline__ void gl16(const ushort* g, ushort* l) {
  __builtin_amdgcn_global_load_lds(
      (const __attribute__((address_space(1))) unsigned int*)g,
      (__attribute__((address_space(3))) unsigned int*)l, 16, 0, 0);
}

// ---------------------------------------------------------------------------
// Split-pack A: f32 [M,K] -> bf16 [M,2K] as [hi | lo]  (2-term split).
// ---------------------------------------------------------------------------
__global__ __launch_bounds__(256) void split_pack_A(
    const float* __restrict__ in, int inStride, int K, int M,
    ushort* __restrict__ out) {
  size_t tid = (size_t)blockIdx.x * 256 + threadIdx.x;
  if (tid >= (size_t)M * K) return;
  int k = (int)(tid % K);
  size_t m = tid / K;
  float x = in[m * inStride + k];
  ushort hi = f2bf(x);
  float rem = x - bf2f(hi);
  ushort lo = f2bf(rem);
  size_t o = m * (size_t)(2 * K);
  out[o + k] = hi;
  out[o + K + k] = lo;
}

// ---------------------------------------------------------------------------
// Pack weight W [K,N] f32 -> transposed bf16 [n][hi|hi] (2-term: B repeated).
// ---------------------------------------------------------------------------
__global__ __launch_bounds__(256) void pack_w3t(
    const float* __restrict__ W, int K, int N,
    ushort* __restrict__ out, int rowStride) {
  size_t tid = (size_t)blockIdx.x * 256 + threadIdx.x;
  if (tid >= (size_t)K * N) return;
  int k = (int)(tid % K);
  size_t n = tid / K;
  float x = W[(size_t)k * N + n];
  ushort hi = f2bf(x);
  size_t o = n * (size_t)rowStride;
  out[o + k] = hi;
  out[o + K + k] = hi;
}

// ---------------------------------------------------------------------------
// bf16 MFMA GEMM, m97 structure: global_load_lds(16B) staging into LINEAR
// LDS [128][32], 128x128 tile, 4 waves (2x2), 16x16x32 MFMA, BK=32.
// ---------------------------------------------------------------------------
template <typename OutT>
__global__ __launch_bounds__(256) void gemm_glds(
    const ushort* __restrict__ A, const ushort* __restrict__ Bt,
    const float* __restrict__ bias, OutT* __restrict__ C,
    int M, int N, int K) {
  __shared__ ushort As[128 * 32];
  __shared__ ushort Bs[128 * 32];
  const int tid = threadIdx.x;
  const int bm = blockIdx.x * 128, bn = blockIdx.y * 128;
  const int wid = tid >> 6, lane = tid & 63;
  const int wm = (wid >> 1) * 64, wn = (wid & 1) * 64;
  const int fr = lane & 15, fq = lane >> 4;
  const int srow = wid * 32 + (lane >> 2);
  const int scol = (lane & 3) * 8;

  f32x4 acc[4][4] = {};

  for (int k0 = 0; k0 < K; k0 += 32) {
    const ushort* gA = A + (size_t)(bm + srow) * K + k0 + scol;
    const ushort* gB = Bt + (size_t)(bn + srow) * K + k0 + scol;
    gl16(gA, &As[(wid * 32) * 32]);
    gl16(gA + (size_t)16 * K, &As[(wid * 32 + 16) * 32]);
    gl16(gB, &Bs[(wid * 32) * 32]);
    gl16(gB + (size_t)16 * K, &Bs[(wid * 32 + 16) * 32]);
    __syncthreads();

    bf16x8 af[4], bfr[4];
    #pragma unroll
    for (int i = 0; i < 4; i++) af[i] = *(const bf16x8*)&As[(wm + i * 16 + fr) * 32 + fq * 8];
    #pragma unroll
    for (int j = 0; j < 4; j++) bfr[j] = *(const bf16x8*)&Bs[(wn + j * 16 + fr) * 32 + fq * 8];
    #pragma unroll
    for (int i = 0; i < 4; i++)
      #pragma unroll
      for (int j = 0; j < 4; j++)
        acc[i][j] = __builtin_amdgcn_mfma_f32_16x16x32_bf16(af[i], bfr[j], acc[i][j], 0, 0, 0);
    __syncthreads();
  }

  #pragma unroll
  for (int i = 0; i < 4; i++) {
    #pragma unroll
    for (int j = 0; j < 4; j++) {
      int col = bn + wn + j * 16 + fr;
      float bv = bias ? bias[col] : 0.f;
      #pragma unroll
      for (int r = 0; r < 4; r++) {
        int row = bm + wm + i * 16 + fq * 4 + r;
        float v = acc[i][j][r] + bv;
        if constexpr (sizeof(OutT) == 2) {
          ((ushort*)C)[(size_t)row * N + col] = f2bf(v);
        } else {
          ((float*)C)[(size_t)row * N + col] = v;
        }
      }
    }
  }
}

// unpack element u (0..15) from a 4-row packed conv window x[8] (2 uint4/row)
#define XROW(x, tap, u) \
  bf2f((ushort)(((u) & 1) ? (((const uint*)&(x)[(tap) * 2 + ((u) >> 3)])[((u) >> 1) & 3] >> 16) \
                          : ((const uint*)&(x)[(tap) * 2 + ((u) >> 3)])[((u) >> 1) & 3]))
#define TAPW(w, tap) ((tap) == 0 ? (w).x : (tap) == 1 ? (w).y : (tap) == 2 ? (w).z : (w).w)

// ---------------------------------------------------------------------------
// prep v7: fast-math transcendentals (__expf = v_exp_f32, v_rcp) — saves
// ~25-30% of the VALU instruction stream vs libm expf/div. Structure as v6.
// ---------------------------------------------------------------------------
__global__ __launch_bounds__(256, 3) void prep(
    const ushort* __restrict__ qkv, const ushort* __restrict__ grawB,
    const float* __restrict__ f1g1b,
    const float* __restrict__ qcw, const float* __restrict__ qcb,
    const float* __restrict__ kcw, const float* __restrict__ kcb,
    const float* __restrict__ vcw, const float* __restrict__ vcb,
    const float* __restrict__ A_log, const float* __restrict__ dtb,
    ushort* __restrict__ mMGSG, ushort* __restrict__ mWkB,
    ushort* __restrict__ mWqBv, float* __restrict__ geG) {
  const int bh = blockIdx.x, ch = blockIdx.y;
  const int b = bh >> 4, h = bh & 15;
  const int i = bh * 32 + ch;
  const int t0 = ch * 64;
  const int tid = threadIdx.x;
  const int wA = tid >> 6, tA = tid & 63;
  const int tTh = tid >> 2, c4 = tid & 3, kb = c4 * 16;
  const int c0 = h * 64 + kb;

  __shared__ __align__(16) ushort KtU[64][72];  // kn -> K~ bf16 ; PH7+: Gt (G^T)
  __shared__ __align__(16) ushort KhU[64][72];  // K^ bf16
  __shared__ __align__(16) ushort QtU[64][72];  // qn -> Q~ bf16 ; PH7: KhET
  __shared__ __align__(16) float cM[64][72];    // g -> cumsum; PH6+: Mqk/MkkT bf16
  __shared__ __align__(16) float dlog[17][68];
  __shared__ float betaL[64];
  ushort* cMu = (ushort*)&cM[0][0];
  ushort (*MqkRM)[72] = (ushort(*)[72])cMu;            // Mqk[t][s] row-major
  ushort (*MkkT)[72] = (ushort(*)[72])(cMu + 64 * 72); // Mkk^T[s][t]
  ushort (*Gt)[72] = KtU;                              // G^T[j][s]
  ushort (*KhET)[72] = QtU;                            // KhE^T[k][s]

  // ---- PH0: conv+SiLU+norm for q,k straight from global (vector loads) ----
  {
    const uint4 z4 = make_uint4(0, 0, 0, 0);
    // q
    {
      uint4 x[8];
      #pragma unroll
      for (int tap = 0; tap < 4; tap++) {
        int tr = t0 + tTh - 3 + tap;
        if (tr >= 0) {
          const uint4* p = (const uint4*)(qkv + (size_t)(b * T_ + tr) * 3072 + c0);
          x[tap * 2] = p[0]; x[tap * 2 + 1] = p[1];
        } else { x[tap * 2] = z4; x[tap * 2 + 1] = z4; }
      }
      float qa[16], s = 0.f;
      #pragma unroll
      for (int u = 0; u < 16; u++) {
        float4 w = ((const float4*)qcw)[c0 + u];
        float a = qcb[c0 + u];
        #pragma unroll
        for (int tap = 0; tap < 4; tap++) a += XROW(x, tap, u) * TAPW(w, tap);
        a = siluf_(a);
        qa[u] = a; s += a * a;
      }
      s += __shfl_xor(s, 1, 64); s += __shfl_xor(s, 2, 64);
      float qs = 0.125f / (sqrtf(s) + 1e-6f);
      #pragma unroll
      for (int u = 0; u < 16; u++) qa[u] *= qs;
      *(uint4*)&QtU[tTh][kb] = pk8_(&qa[0]);
      *(uint4*)&QtU[tTh][kb + 8] = pk8_(&qa[8]);
    }
    // k
    {
      uint4 x[8];
      #pragma unroll
      for (int tap = 0; tap < 4; tap++) {
        int tr = t0 + tTh - 3 + tap;
        if (tr >= 0) {
          const uint4* p = (const uint4*)(qkv + (size_t)(b * T_ + tr) * 3072 + 1024 + c0);
          x[tap * 2] = p[0]; x[tap * 2 + 1] = p[1];
        } else { x[tap * 2] = z4; x[tap * 2 + 1] = z4; }
      }
      float ka[16], s = 0.f;
      #pragma unroll
      for (int u = 0; u < 16; u++) {
        float4 w = ((const float4*)kcw)[c0 + u];
        float a = kcb[c0 + u];
        #pragma unroll
        for (int tap = 0; tap < 4; tap++) a += XROW(x, tap, u) * TAPW(w, tap);
        a = siluf_(a);
        ka[u] = a; s += a * a;
      }
      s += __shfl_xor(s, 1, 64); s += __shfl_xor(s, 2, 64);
      float ks = frcp_(sqrtf(s) + 1e-6f);
      #pragma unroll
      for (int u = 0; u < 16; u++) ka[u] *= ks;
      *(uint4*)&KtU[tTh][kb] = pk8_(&ka[0]);
      *(uint4*)&KtU[tTh][kb + 8] = pk8_(&ka[8]);
    }
    // g = -A*softplus(graw+dtb) -> cM; beta
    {
      float Aexp = fexp_(A_log[h]);
      const ushort* gr = grawB + (size_t)(b * T_ + t0 + tTh) * 1024 + c0;
      uint4 ga = *(const uint4*)gr;
      uint4 gb = *(const uint4*)(gr + 8);
      float xv[16];
      ub8_(ga, &xv[0]); ub8_(gb, &xv[8]);
      #pragma unroll
      for (int u = 0; u < 16; u++) {
        float x = xv[u] + dtb[c0 + u];
        float sp = (x > 20.f) ? x : __logf(1.f + fexp_(x));
        cM[tTh][kb + u] = -Aexp * sp;
      }
      if (tid < 64)
        betaL[tid] = sigmoidf_(f1g1b[(size_t)(b * T_ + t0 + tid) * 256 + 128 + h]);
    }
  }
  __syncthreads();
  // ---- PH2: cumsum within quarters ----
  {
    const int q = wA, k = tA;
    float run = 0.f;
    #pragma unroll
    for (int u = 0; u < 16; u++) { run += cM[q * 16 + u][k]; cM[q * 16 + u][k] = run; }
    dlog[q][k] = run;
  }
  __syncthreads();
  // ---- PH3: apply segment offsets ----
  {
    const int q = wA, k = tA;
    if (q > 0) {
      float off = dlog[0][k];
      if (q > 1) off += dlog[1][k];
      if (q > 2) off += dlog[2][k];
      #pragma unroll
      for (int u = 0; u < 16; u++) cM[q * 16 + u][k] += off;
    }
  }
  __syncthreads();
  // ---- PH4: block-base log decays ----
  for (int idx = tid; idx < 17 * 64; idx += 256) {
    int P = idx >> 6, k = idx & 63;
    dlog[P][k] = (P == 0) ? 0.f : cM[4 * P - 1][k];
  }
  __syncthreads();
  // ---- PH5: K~/K^/Q~ in place (bf16; cM dead after this) ----
  {
    const int P5 = tTh >> 2;
    float knv[16], qnv[16];
    ub8_(*(const uint4*)&KtU[tTh][kb], &knv[0]);
    ub8_(*(const uint4*)&KtU[tTh][kb + 8], &knv[8]);
    ub8_(*(const uint4*)&QtU[tTh][kb], &qnv[0]);
    ub8_(*(const uint4*)&QtU[tTh][kb + 8], &qnv[8]);
    float ktv[16], khv[16], qtv[16];
    #pragma unroll
    for (int u = 0; u < 16; u++) {
      int k = kb + u;
      float c = cM[tTh][k], d = dlog[P5][k];
      float e1 = fexp_(c - d);
      float e2 = fexp_(d - c);
      ktv[u] = knv[u] * e1;
      khv[u] = knv[u] * e2;
      qtv[u] = qnv[u] * e1;
    }
    *(uint4*)&KtU[tTh][kb] = pk8_(&ktv[0]);
    *(uint4*)&KtU[tTh][kb + 8] = pk8_(&ktv[8]);
    *(uint4*)&KhU[tTh][kb] = pk8_(&khv[0]);
    *(uint4*)&KhU[tTh][kb + 8] = pk8_(&khv[8]);
    *(uint4*)&QtU[tTh][kb] = pk8_(&qtv[0]);
    *(uint4*)&QtU[tTh][kb + 8] = pk8_(&qtv[8]);
  }
  __syncthreads();
  // ---- PH6: Wq/WkB/bv/ge outputs + Mqk-upper zeroing + M-build ----
  {
    const int P = tTh >> 2;
    float bt = betaL[tTh];
    float qtv[16], ktv[16];
    ub8_(*(const uint4*)&QtU[tTh][kb], &qtv[0]);
    ub8_(*(const uint4*)&QtU[tTh][kb + 8], &qtv[8]);
    ub8_(*(const uint4*)&KtU[tTh][kb], &ktv[0]);
    ub8_(*(const uint4*)&KtU[tTh][kb + 8], &ktv[8]);
    float tq[16], tk[16];
    #pragma unroll
    for (int u = 0; u < 16; u++) {
      int k = kb + u;
      float e = fexp_(dlog[P][k]);
      tq[u] = qtv[u] * e;
      tk[u] = bt * ktv[u] * e;
    }
    ushort* pq = mWqBv + (size_t)i * 8192 + tTh * 64 + kb;
    ushort* pk = mWkB + (size_t)i * 4096 + tTh * 64 + kb;
    *(uint4*)&pq[0] = pk8_(&tq[0]);
    *(uint4*)&pq[8] = pk8_(&tq[8]);
    *(uint4*)&pk[0] = pk8_(&tk[0]);
    *(uint4*)&pk[8] = pk8_(&tk[8]);

    // bv = beta * silu(conv(v)) — direct-global vector conv
    {
      const uint4 z4 = make_uint4(0, 0, 0, 0);
      uint4 x[8];
      #pragma unroll
      for (int tap = 0; tap < 4; tap++) {
        int tr = t0 + tTh - 3 + tap;
        if (tr >= 0) {
          const uint4* p = (const uint4*)(qkv + (size_t)(b * T_ + tr) * 3072 + 2048 + c0);
          x[tap * 2] = p[0]; x[tap * 2 + 1] = p[1];
        } else { x[tap * 2] = z4; x[tap * 2 + 1] = z4; }
      }
      float av[16];
      #pragma unroll
      for (int u = 0; u < 16; u++) {
        float4 w = ((const float4*)vcw)[c0 + u];
        float a = vcb[c0 + u];
        #pragma unroll
        for (int tap = 0; tap < 4; tap++) a += XROW(x, tap, u) * TAPW(w, tap);
        av[u] = bt * siluf_(a);
      }
      ushort* pb = mWqBv + (size_t)i * 8192 + 4096 + tTh * 64 + kb;
      *(uint4*)&pb[0] = pk8_(&av[0]);
      *(uint4*)&pb[8] = pk8_(&av[8]);
    }

    if (tid < 64) geG[(size_t)i * 64 + tid] = fexp_(dlog[16][tid]);

    // zero Mqk strict-upper TILES + pad cols (disjoint from M-build writes)
    for (int idx = tid; idx < 64 * 72; idx += 256) {
      int t = idx / 72, s = idx - t * 72;
      if (s >= 64 || (s >> 2) > (t >> 2)) MqkRM[t][s] = 0;
    }

    // M-build: 272 4x4 tiles, R recomputed on the fly (all exponents <= 0)
    for (int tile = tid; tile < 272; tile += 256) {
      int mq = (tile >= 136) ? 1 : 0;
      int f = tile - mq * 136;
      int rem = f, P2 = 0;
      while (rem >= P2 + 1) { rem -= P2 + 1; ++P2; }
      int J = rem;
      const ushort (*Xr)[72] = mq ? QtU : KtU;
      float acc[4][4] = {};
      for (int kc = 0; kc < 16; kc++) {
        float av0[4], av1[4], av2[4], av3[4];
        ub4_(*(const uint2*)&Xr[4 * P2 + 0][kc * 4], av0);
        ub4_(*(const uint2*)&Xr[4 * P2 + 1][kc * 4], av1);
        ub4_(*(const uint2*)&Xr[4 * P2 + 2][kc * 4], av2);
        ub4_(*(const uint2*)&Xr[4 * P2 + 3][kc * 4], av3);
        float4 dp = *(const float4*)&dlog[P2][kc * 4];
        float4 dj = *(const float4*)&dlog[J][kc * 4];
        float rv[4] = {fexp_(dp.x - dj.x), fexp_(dp.y - dj.y),
                       fexp_(dp.z - dj.z), fexp_(dp.w - dj.w)};
        #pragma unroll
        for (int c = 0; c < 4; c++) {
          float kv[4];
          ub4_(*(const uint2*)&KhU[4 * J + c][kc * 4], kv);
          float bx = kv[0] * rv[0], by = kv[1] * rv[1], bz = kv[2] * rv[2], bw = kv[3] * rv[3];
          acc[0][c] += av0[0] * bx + av0[1] * by + av0[2] * bz + av0[3] * bw;
          acc[1][c] += av1[0] * bx + av1[1] * by + av1[2] * bz + av1[3] * bw;
          acc[2][c] += av2[0] * bx + av2[1] * by + av2[2] * bz + av2[3] * bw;
          acc[3][c] += av3[0] * bx + av3[1] * by + av3[2] * bz + av3[3] * bw;
        }
      }
      if (mq && P2 == J) {   // inclusive-tril mask inside diag tile
        #pragma unroll
        for (int c = 0; c < 4; c++)
          #pragma unroll
          for (int r = 0; r < 4; r++)
            if (c > r) acc[r][c] = 0.f;
      }
      if (mq) {
        #pragma unroll
        for (int r = 0; r < 4; r++)
          *(uint2*)&MqkRM[4 * P2 + r][4 * J] =
              pk4_(acc[r][0], acc[r][1], acc[r][2], acc[r][3]);
      } else {
        #pragma unroll
        for (int c = 0; c < 4; c++) {
          uint2 w;
          w.x = (uint)f2bf(acc[0][c]) | ((uint)f2bf(acc[1][c]) << 16);
          w.y = (uint)f2bf(acc[2][c]) | ((uint)f2bf(acc[3][c]) << 16);
          *(uint2*)&MkkT[4 * J + c][4 * P2] = w;
        }
      }
    }
  }
  __syncthreads();
  // ---- PH7: KhET (transposed) into QtU + G-solve writing Gt (transposed) ----
  for (int idx = tid; idx < 4096; idx += 256) {
    int k = idx >> 6, s = idx & 63;
    KhET[k][s] = f2bf(bf2f(KhU[s][k]) * fexp_(dlog[16][k] - dlog[s >> 2][k]));
  }
  {
    const int j = tTh, q = c4;
    float acc[16], gsv[16];
    #pragma unroll
    for (int u = 0; u < 16; u++) { acc[u] = 0.f; gsv[u] = 0.f; }
    for (int s = 0; s < 64; s++) {
      int q0 = s >> 4;
      float g = 0.f;
      if (q == q0) {
        g = ((s == j) ? 1.f : 0.f) - betaL[s] * acc[s & 15];
        gsv[s & 15] = g;
      }
      g = __shfl(g, 4 * (j & 15) + q0, 64);
      #pragma unroll
      for (int u = 0; u < 4; u++) {
        uint2 m2 = *(const uint2*)&MkkT[s][q * 16 + u * 4];
        acc[u * 4 + 0] += bf2f((ushort)m2.x) * g;
        acc[u * 4 + 1] += bf2f((ushort)(m2.x >> 16)) * g;
        acc[u * 4 + 2] += bf2f((ushort)m2.y) * g;
        acc[u * 4 + 3] += bf2f((ushort)(m2.y >> 16)) * g;
      }
    }
    *(uint4*)&Gt[j][q * 16] = pk8_(&gsv[0]);
    *(uint4*)&Gt[j][q * 16 + 8] = pk8_(&gsv[8]);
  }
  __syncthreads();
  // ---- PH8 (MFMA): MG = tril(Mqk)@G, SG = KhET@G ----
  {
    const int wid = tid >> 6, lane = tid & 63;
    const int fr = lane & 15, fq = lane >> 4;
    const int wrow = wid * 16;
    bf16x8 aM[2], aS[2];
    #pragma unroll
    for (int kt = 0; kt < 2; kt++) {
      aM[kt] = *(const bf16x8*)&MqkRM[wrow + fr][kt * 32 + fq * 8];
      aS[kt] = *(const bf16x8*)&KhET[wrow + fr][kt * 32 + fq * 8];
    }
    #pragma unroll
    for (int jt = 0; jt < 4; jt++) {
      bf16x8 bG[2];
      #pragma unroll
      for (int kt = 0; kt < 2; kt++)
        bG[kt] = *(const bf16x8*)&Gt[jt * 16 + fr][kt * 32 + fq * 8];
      f32x4 accM = {}, accS = {};
      #pragma unroll
      for (int kt = 0; kt < 2; kt++) {
        accM = __builtin_amdgcn_mfma_f32_16x16x32_bf16(aM[kt], bG[kt], accM, 0, 0, 0);
        accS = __builtin_amdgcn_mfma_f32_16x16x32_bf16(aS[kt], bG[kt], accS, 0, 0, 0);
      }
      #pragma unroll
      for (int r = 0; r < 4; r++) {
        int row = wrow + fq * 4 + r, col = jt * 16 + fr;
        mMGSG[(size_t)i * 8192 + row * 64 + col] = f2bf(accM[r]);
        mMGSG[(size_t)i * 8192 + 4096 + row * 64 + col] = f2bf(accS[r]);
      }
    }
  }
}

// ---------------------------------------------------------------------------
// scan v2: 512 threads (8 waves, 2/SIMD — was 4 waves = 1/SIMD, latency-
// exposed). Each thread owns 2 v-columns. Grid (64 bh, 4 vq).
// Per chunk: r = bv - WkB@S; O = MG@r + Wq@S; S = ge*S + SG@r.
// ---------------------------------------------------------------------------
__global__ __launch_bounds__(512) void scan(
    const ushort* __restrict__ mMGSG, const ushort* __restrict__ mWkB,
    const ushort* __restrict__ mWqBv, const float* __restrict__ geG,
    ushort* __restrict__ oG) {
  const int bh = blockIdx.x, vq = blockIdx.y;
  const int tid = threadIdx.x;
  const int tTh = tid >> 3, c8 = tid & 7, lvi = c8 * 2;
  const int r0 = tid >> 3, cc = (tid & 7) * 8;

  __shared__ ushort MGs[64][72], SGs[64][72], WkBs[64][72], Wqs[64][72];
  __shared__ __align__(16) float Sl[64][20], rl[64][20];
  __shared__ float geL[64];

  Sl[tTh][lvi] = 0.f; Sl[tTh][lvi + 1] = 0.f;

  const size_t i0 = (size_t)bh * 32;
  {
    uint4 a0 = *(const uint4*)&mMGSG[i0 * 8192 + tid * 8];
    uint4 b0 = *(const uint4*)&mMGSG[i0 * 8192 + 4096 + tid * 8];
    uint4 c0 = *(const uint4*)&mWkB[i0 * 4096 + (tid & 511) * 8];
    uint4 d0 = *(const uint4*)&mWqBv[i0 * 8192 + tid * 8];
    *(uint4*)&MGs[r0][cc] = a0;
    *(uint4*)&SGs[r0][cc] = b0;
    *(uint4*)&WkBs[r0][cc] = c0;
    *(uint4*)&Wqs[r0][cc] = d0;
    if (tid < 64) geL[tid] = geG[i0 * 64 + tid];
  }
  uint bvCur = *(const uint*)&mWqBv[i0 * 8192 + 4096 + tTh * 64 + vq * 16 + lvi];
  __syncthreads();

  for (int ch = 0; ch < 32; ch++) {
    const size_t i = i0 + ch;
    uint4 p0, p1, p2, p3;
    uint pbv;
    float pge = 0.f;
    if (ch < 31) {
      const size_t i2 = i + 1;
      p0 = *(const uint4*)&mMGSG[i2 * 8192 + tid * 8];
      p1 = *(const uint4*)&mMGSG[i2 * 8192 + 4096 + tid * 8];
      p2 = *(const uint4*)&mWkB[i2 * 4096 + tid * 8];
      p3 = *(const uint4*)&mWqBv[i2 * 8192 + tid * 8];
      pbv = *(const uint*)&mWqBv[i2 * 8192 + 4096 + tTh * 64 + vq * 16 + lvi];
      if (tid < 64) pge = geG[i2 * 64 + tid];
    }
    // P1: r = bv - WkB@S
    float rv0, rv1;
    {
      float b2[2]; ub2_(bvCur, b2); rv0 = b2[0]; rv1 = b2[1];
    }
    #pragma unroll
    for (int kc = 0; kc < 16; kc++) {
      float w4[4];
      ub4_(*(const uint2*)&WkBs[tTh][kc * 4], w4);
      #pragma unroll
      for (int jj = 0; jj < 4; jj++) {
        float2 s2 = *(const float2*)&Sl[kc * 4 + jj][lvi];
        rv0 -= w4[jj] * s2.x; rv1 -= w4[jj] * s2.y;
      }
    }
    rl[tTh][lvi] = rv0; rl[tTh][lvi + 1] = rv1;
    __syncthreads();
    // P2: O = MG@r + Wq@S
    {
      float ov0 = 0.f, ov1 = 0.f;
      #pragma unroll
      for (int sc = 0; sc < 16; sc++) {
        float m4[4];
        ub4_(*(const uint2*)&MGs[tTh][sc * 4], m4);
        #pragma unroll
        for (int jj = 0; jj < 4; jj++) {
          float2 r2 = *(const float2*)&rl[sc * 4 + jj][lvi];
          ov0 += m4[jj] * r2.x; ov1 += m4[jj] * r2.y;
        }
      }
      #pragma unroll
      for (int kc = 0; kc < 16; kc++) {
        float q4[4];
        ub4_(*(const uint2*)&Wqs[tTh][kc * 4], q4);
        #pragma unroll
        for (int jj = 0; jj < 4; jj++) {
          float2 s2 = *(const float2*)&Sl[kc * 4 + jj][lvi];
          ov0 += q4[jj] * s2.x; ov1 += q4[jj] * s2.y;
        }
      }
      *(uint*)&oG[i * 4096 + tTh * 64 + vq * 16 + lvi] = pk2_(ov0, ov1);
    }
    __syncthreads();
    // P3: S = ge*S + SG@r
    {
      float ge = geL[tTh];
      float sv0 = ge * Sl[tTh][lvi], sv1 = ge * Sl[tTh][lvi + 1];
      #pragma unroll
      for (int sc = 0; sc < 16; sc++) {
        float g4[4];
        ub4_(*(const uint2*)&SGs[tTh][sc * 4], g4);
        #pragma unroll
        for (int jj = 0; jj < 4; jj++) {
          float2 r2 = *(const float2*)&rl[sc * 4 + jj][lvi];
          sv0 += g4[jj] * r2.x; sv1 += g4[jj] * r2.y;
        }
      }
      Sl[tTh][lvi] = sv0; Sl[tTh][lvi + 1] = sv1;
    }
    __syncthreads();
    if (ch < 31) {
      *(uint4*)&MGs[r0][cc] = p0;
      *(uint4*)&SGs[r0][cc] = p1;
      *(uint4*)&WkBs[r0][cc] = p2;
      *(uint4*)&Wqs[r0][cc] = p3;
      if (tid < 64) geL[tid] = pge;
      bvCur = pbv;
      __syncthreads();
    }
  }
}

// ---------------------------------------------------------------------------
// RMS-norm + gate + split-pack into [hi|lo] bf16 GEMM operand.
// ---------------------------------------------------------------------------
__global__ __launch_bounds__(256) void onorm_pack(
    const ushort* __restrict__ o, const float* __restrict__ gate,
    const float* __restrict__ onw, ushort* __restrict__ out3) {
  int gi = blockIdx.x * 4 + (threadIdx.x >> 6);
  int lane = threadIdx.x & 63;
  int b = gi >> 15, h = (gi >> 11) & 15, t = gi & 2047;
  float ov = bf2f(o[(size_t)gi * 64 + lane]);
  float ms = wave_sum64(ov * ov) * (1.f / 64.f);
  float r = rsqrtf(ms + 1e-5f);
  float gv = gate[(size_t)(b * T_ + t) * 1024 + h * 64 + lane];
  float val = ov * r * onw[lane] * sigmoidf_(gv);
  ushort hi = f2bf(val);
  float rem = val - bf2f(hi);
  ushort lo = f2bf(rem);
  size_t m = (size_t)(b * T_ + t);
  int c = h * 64 + lane;
  out3[m * 2048 + c] = hi;
  out3[m * 2048 + 1024 + c] = lo;
}

extern "C" void kernel_launch(void* const* d_in, const int* in_sizes, int n_in,
                              void* d_out, int out_size, void* d_ws, size_t ws_size,
                              hipStream_t stream) {
  const float* hs    = (const float*)d_in[0];
  const float* Wq    = (const float*)d_in[1];
  const float* Wk    = (const float*)d_in[2];
  const float* Wv    = (const float*)d_in[3];
  const float* qcw   = (const float*)d_in[4];
  const float* qcb   = (const float*)d_in[5];
  const float* kcw   = (const float*)d_in[6];
  const float* kcb   = (const float*)d_in[7];
  const float* vcw   = (const float*)d_in[8];
  const float* vcb   = (const float*)d_in[9];
  const float* Wf1   = (const float*)d_in[10];
  const float* Wf2   = (const float*)d_in[11];
  const float* Wb    = (const float*)d_in[12];
  const float* A_log = (const float*)d_in[13];
  const float* dtb   = (const float*)d_in[14];
  const float* Wg1   = (const float*)d_in[15];
  const float* Wg2   = (const float*)d_in[16];
  const float* bg2   = (const float*)d_in[17];
  const float* onw   = (const float*)d_in[18];
  const float* Wo    = (const float*)d_in[19];
  float* out = (float*)d_out;

  char* ws = (char*)d_ws;
  ushort* hs3    = (ushort*)(ws);
  ushort* mMGSG  = (ushort*)(ws);
  ushort* obuf3  = (ushort*)(ws);
  ushort* mWkB   = (ushort*)(ws + 33554432);
  ushort* qkvhat = (ushort*)(ws + 50331648);
  float*  gate   = (float*)qkvhat;
  ushort* oG     = (ushort*)(ws + 83886080);
  ushort* grawB  = (ushort*)(ws + 100663296);
  float*  geG    = (float*)(ws + 117440512);
  ushort* mWqBv  = (ushort*)(ws + 117964800);
  char*   R4     = ws + 151519232;
  ushort* Wqkv3  = (ushort*)R4;
  ushort* Wfgb3  = (ushort*)R4;
  float*  f1g1b  = (float*)(R4 + 1572864);
  ushort* f1_3   = (ushort*)(R4 + 9961472);
  ushort* g1_3   = (ushort*)(R4 + 13107200);
  ushort* Wf2_3  = (ushort*)(R4 + 16252928);
  ushort* Wg2_3  = (ushort*)(R4 + 16646144);
  ushort* Wo3    = (ushort*)R4;

  dim3 blk(256);
  const int PK = 1024 * 1024;

  split_pack_A<<<dim3((M_ * 1024) / 256), blk, 0, stream>>>(hs, 1024, 1024, M_, hs3);
  pack_w3t<<<dim3(PK / 256), blk, 0, stream>>>(Wq, 1024, 1024, Wqkv3, 2048);
  pack_w3t<<<dim3(PK / 256), blk, 0, stream>>>(Wk, 1024, 1024, Wqkv3 + (size_t)1024 * 2048, 2048);
  pack_w3t<<<dim3(PK / 256), blk, 0, stream>>>(Wv, 1024, 1024, Wqkv3 + (size_t)2048 * 2048, 2048);
  gemm_glds<ushort><<<dim3(M_ / 128, 3072 / 128), blk, 0, stream>>>(
      hs3, Wqkv3, nullptr, qkvhat, M_, 3072, 2048);
  hipMemsetAsync(Wfgb3, 0, (size_t)256 * 2048 * 2, stream);
  pack_w3t<<<dim3((1024 * 64) / 256), blk, 0, stream>>>(Wf1, 1024, 64, Wfgb3, 2048);
  pack_w3t<<<dim3((1024 * 64) / 256), blk, 0, stream>>>(Wg1, 1024, 64, Wfgb3 + (size_t)64 * 2048, 2048);
  pack_w3t<<<dim3((1024 * 16) / 256), blk, 0, stream>>>(Wb, 1024, 16, Wfgb3 + (size_t)128 * 2048, 2048);
  gemm_glds<float><<<dim3(M_ / 128, 2), blk, 0, stream>>>(
      hs3, Wfgb3, nullptr, f1g1b, M_, 256, 2048);
  split_pack_A<<<dim3((M_ * 64) / 256), blk, 0, stream>>>(f1g1b, 256, 64, M_, f1_3);
  split_pack_A<<<dim3((M_ * 64) / 256), blk, 0, stream>>>(f1g1b + 64, 256, 64, M_, g1_3);
  pack_w3t<<<dim3((64 * 1024) / 256), blk, 0, stream>>>(Wf2, 64, 1024, Wf2_3, 128);
  gemm_glds<ushort><<<dim3(M_ / 128, 1024 / 128), blk, 0, stream>>>(
      f1_3, Wf2_3, nullptr, grawB, M_, 1024, 128);

  prep<<<dim3(64, 32), blk, 0, stream>>>(qkvhat, grawB, f1g1b,
                                         qcw, qcb, kcw, kcb, vcw, vcb,
                                         A_log, dtb, mMGSG, mWkB, mWqBv, geG);
  pack_w3t<<<dim3((64 * 1024) / 256), blk, 0, stream>>>(Wg2, 64, 1024, Wg2_3, 128);
  gemm_glds<float><<<dim3(M_ / 128, 1024 / 128), blk, 0, stream>>>(
      g1_3, Wg2_3, bg2, gate, M_, 1024, 128);

  scan<<<dim3(64, 4), dim3(512), 0, stream>>>(mMGSG, mWkB, mWqBv, geG, oG);

  onorm_pack<<<dim3((M_ * H_) / 4), blk, 0, stream>>>(oG, gate, onw, obuf3);
  pack_w3t<<<dim3(PK / 256), blk, 0, stream>>>(Wo, 1024, 1024, Wo3, 2048);
  gemm_glds<float><<<dim3(M_ / 128, 1024 / 128), blk, 0, stream>>>(
      obuf3, Wo3, nullptr, out, M_, 1024, 2048);
}

// Round 14
// 537.463 us; speedup vs baseline: 6.5219x; 1.2090x over previous
//
#include <hip/hip_runtime.h>
#include <hip/hip_bf16.h>
#include <math.h>

#define H_ 16
#define HIDDEN_ 1024
#define BATCH_ 4
#define T_ 2048
#define M_ (BATCH_ * T_)   // 8192

typedef __attribute__((ext_vector_type(8))) __bf16 bf16x8;
typedef __attribute__((ext_vector_type(4))) float f32x4;

__device__ __forceinline__ float fexp_(float x) { return __expf(x); }
__device__ __forceinline__ float frcp_(float x) { return __builtin_amdgcn_rcpf(x); }
__device__ __forceinline__ float wave_sum64(float v) {
  #pragma unroll
  for (int m = 32; m >= 1; m >>= 1) v += __shfl_xor(v, m, 64);
  return v;
}
__device__ __forceinline__ float sigmoidf_(float x) { return frcp_(1.f + fexp_(-x)); }
__device__ __forceinline__ float siluf_(float x) { return x * frcp_(1.f + fexp_(-x)); }
__device__ __forceinline__ float bf2f(ushort u) {
  unsigned int x = ((unsigned int)u) << 16;
  return __builtin_bit_cast(float, x);
}
__device__ __forceinline__ ushort f2bf(float f) {   // RNE
  unsigned int x = __builtin_bit_cast(unsigned int, f);
  unsigned int r = (x + 0x7fffu + ((x >> 16) & 1u)) >> 16;
  return (ushort)r;
}
__device__ __forceinline__ void ub2_(uint u, float f[2]) {
  f[0] = bf2f((ushort)u); f[1] = bf2f((ushort)(u >> 16));
}
__device__ __forceinline__ void ub4_(uint2 u, float f[4]) {
  f[0] = bf2f((ushort)u.x); f[1] = bf2f((ushort)(u.x >> 16));
  f[2] = bf2f((ushort)u.y); f[3] = bf2f((ushort)(u.y >> 16));
}
__device__ __forceinline__ void ub8_(uint4 u, float* f) {
  f[0] = bf2f((ushort)u.x); f[1] = bf2f((ushort)(u.x >> 16));
  f[2] = bf2f((ushort)u.y); f[3] = bf2f((ushort)(u.y >> 16));
  f[4] = bf2f((ushort)u.z); f[5] = bf2f((ushort)(u.z >> 16));
  f[6] = bf2f((ushort)u.w); f[7] = bf2f((ushort)(u.w >> 16));
}
__device__ __forceinline__ uint pk2_(float a, float b) {
  return (uint)f2bf(a) | ((uint)f2bf(b) << 16);
}
__device__ __forceinline__ uint2 pk4_(float a, float b, float c, float d) {
  return make_uint2((uint)f2bf(a) | ((uint)f2bf(b) << 16),
                    (uint)f2bf(c) | ((uint)f2bf(d) << 16));
}
__device__ __forceinline__ uint4 pk8_(const float* t) {
  uint4 r;
  r.x = (uint)f2bf(t[0]) | ((uint)f2bf(t[1]) << 16);
  r.y = (uint)f2bf(t[2]) | ((uint)f2bf(t[3]) << 16);
  r.z = (uint)f2bf(t[4]) | ((uint)f2bf(t[5]) << 16);
  r.w = (uint)f2bf(t[6]) | ((uint)f2bf(t[7]) << 16);
  return r;
}
// async global -> LDS, 16B per lane
__device__ __forceinline__ void gl16(const ushort* g, ushort* l) {
  __builtin_amdgcn_global_load_lds(
      (const __attribute__((address_space(1))) unsigned int*)g,
      (__attribute__((address_space(3))) unsigned int*)l, 16, 0, 0);
}

// ---------------------------------------------------------------------------
// Pack f32 [M,K] (row stride inStride) -> bf16 [M,K].
// ---------------------------------------------------------------------------
__global__ __launch_bounds__(256) void pack_bf16(
    const float* __restrict__ in, int inStride, int K, int M,
    ushort* __restrict__ out) {
  size_t tid = (size_t)blockIdx.x * 256 + threadIdx.x;
  if (tid >= (size_t)M * K) return;
  int k = (int)(tid % K);
  size_t m = tid / K;
  out[m * (size_t)K + k] = f2bf(in[m * inStride + k]);
}

// ---------------------------------------------------------------------------
// Pack weight W [K,N] f32 -> transposed bf16 [n][k], rowStride = K.
// ---------------------------------------------------------------------------
__global__ __launch_bounds__(256) void pack_wt(
    const float* __restrict__ W, int K, int N,
    ushort* __restrict__ out, int rowStride) {
  size_t tid = (size_t)blockIdx.x * 256 + threadIdx.x;
  if (tid >= (size_t)K * N) return;
  int k = (int)(tid % K);
  size_t n = tid / K;
  out[n * (size_t)rowStride + k] = f2bf(W[(size_t)k * N + n]);
}

// ---------------------------------------------------------------------------
// bf16 MFMA GEMM, m97 structure: global_load_lds(16B) into LINEAR LDS
// [128][32], 128x128 tile, 4 waves (2x2), 16x16x32 MFMA, BK=32.
// ---------------------------------------------------------------------------
template <typename OutT>
__global__ __launch_bounds__(256) void gemm_glds(
    const ushort* __restrict__ A, const ushort* __restrict__ Bt,
    const float* __restrict__ bias, OutT* __restrict__ C,
    int M, int N, int K) {
  __shared__ ushort As[128 * 32];
  __shared__ ushort Bs[128 * 32];
  const int tid = threadIdx.x;
  const int bm = blockIdx.x * 128, bn = blockIdx.y * 128;
  const int wid = tid >> 6, lane = tid & 63;
  const int wm = (wid >> 1) * 64, wn = (wid & 1) * 64;
  const int fr = lane & 15, fq = lane >> 4;
  const int srow = wid * 32 + (lane >> 2);
  const int scol = (lane & 3) * 8;

  f32x4 acc[4][4] = {};

  for (int k0 = 0; k0 < K; k0 += 32) {
    const ushort* gA = A + (size_t)(bm + srow) * K + k0 + scol;
    const ushort* gB = Bt + (size_t)(bn + srow) * K + k0 + scol;
    gl16(gA, &As[(wid * 32) * 32]);
    gl16(gA + (size_t)16 * K, &As[(wid * 32 + 16) * 32]);
    gl16(gB, &Bs[(wid * 32) * 32]);
    gl16(gB + (size_t)16 * K, &Bs[(wid * 32 + 16) * 32]);
    __syncthreads();

    bf16x8 af[4], bfr[4];
    #pragma unroll
    for (int i = 0; i < 4; i++) af[i] = *(const bf16x8*)&As[(wm + i * 16 + fr) * 32 + fq * 8];
    #pragma unroll
    for (int j = 0; j < 4; j++) bfr[j] = *(const bf16x8*)&Bs[(wn + j * 16 + fr) * 32 + fq * 8];
    #pragma unroll
    for (int i = 0; i < 4; i++)
      #pragma unroll
      for (int j = 0; j < 4; j++)
        acc[i][j] = __builtin_amdgcn_mfma_f32_16x16x32_bf16(af[i], bfr[j], acc[i][j], 0, 0, 0);
    __syncthreads();
  }

  #pragma unroll
  for (int i = 0; i < 4; i++) {
    #pragma unroll
    for (int j = 0; j < 4; j++) {
      int col = bn + wn + j * 16 + fr;
      float bv = bias ? bias[col] : 0.f;
      #pragma unroll
      for (int r = 0; r < 4; r++) {
        int row = bm + wm + i * 16 + fq * 4 + r;
        float v = acc[i][j][r] + bv;
        if constexpr (sizeof(OutT) == 2) {
          ((ushort*)C)[(size_t)row * N + col] = f2bf(v);
        } else {
          ((float*)C)[(size_t)row * N + col] = v;
        }
      }
    }
  }
}

// unpack element u (0..15) from a 4-row packed conv window x[8] (2 uint4/row)
#define XROW(x, tap, u) \
  bf2f((ushort)(((u) & 1) ? (((const uint*)&(x)[(tap) * 2 + ((u) >> 3)])[((u) >> 1) & 3] >> 16) \
                          : ((const uint*)&(x)[(tap) * 2 + ((u) >> 3)])[((u) >> 1) & 3]))
#define TAPW(w, tap) ((tap) == 0 ? (w).x : (tap) == 1 ? (w).y : (tap) == 2 ? (w).z : (w).w)

// ---------------------------------------------------------------------------
// prep v7 (unchanged from R13): fused frontend + UT-transform precompute.
// ---------------------------------------------------------------------------
__global__ __launch_bounds__(256, 3) void prep(
    const ushort* __restrict__ qkv, const ushort* __restrict__ grawB,
    const float* __restrict__ f1g1b,
    const float* __restrict__ qcw, const float* __restrict__ qcb,
    const float* __restrict__ kcw, const float* __restrict__ kcb,
    const float* __restrict__ vcw, const float* __restrict__ vcb,
    const float* __restrict__ A_log, const float* __restrict__ dtb,
    ushort* __restrict__ mMGSG, ushort* __restrict__ mWkB,
    ushort* __restrict__ mWqBv, float* __restrict__ geG) {
  const int bh = blockIdx.x, ch = blockIdx.y;
  const int b = bh >> 4, h = bh & 15;
  const int i = bh * 32 + ch;
  const int t0 = ch * 64;
  const int tid = threadIdx.x;
  const int wA = tid >> 6, tA = tid & 63;
  const int tTh = tid >> 2, c4 = tid & 3, kb = c4 * 16;
  const int c0 = h * 64 + kb;

  __shared__ __align__(16) ushort KtU[64][72];
  __shared__ __align__(16) ushort KhU[64][72];
  __shared__ __align__(16) ushort QtU[64][72];
  __shared__ __align__(16) float cM[64][72];
  __shared__ __align__(16) float dlog[17][68];
  __shared__ float betaL[64];
  ushort* cMu = (ushort*)&cM[0][0];
  ushort (*MqkRM)[72] = (ushort(*)[72])cMu;
  ushort (*MkkT)[72] = (ushort(*)[72])(cMu + 64 * 72);
  ushort (*Gt)[72] = KtU;
  ushort (*KhET)[72] = QtU;

  // ---- PH0: conv+SiLU+norm for q,k ----
  {
    const uint4 z4 = make_uint4(0, 0, 0, 0);
    {
      uint4 x[8];
      #pragma unroll
      for (int tap = 0; tap < 4; tap++) {
        int tr = t0 + tTh - 3 + tap;
        if (tr >= 0) {
          const uint4* p = (const uint4*)(qkv + (size_t)(b * T_ + tr) * 3072 + c0);
          x[tap * 2] = p[0]; x[tap * 2 + 1] = p[1];
        } else { x[tap * 2] = z4; x[tap * 2 + 1] = z4; }
      }
      float qa[16], s = 0.f;
      #pragma unroll
      for (int u = 0; u < 16; u++) {
        float4 w = ((const float4*)qcw)[c0 + u];
        float a = qcb[c0 + u];
        #pragma unroll
        for (int tap = 0; tap < 4; tap++) a += XROW(x, tap, u) * TAPW(w, tap);
        a = siluf_(a);
        qa[u] = a; s += a * a;
      }
      s += __shfl_xor(s, 1, 64); s += __shfl_xor(s, 2, 64);
      float qs = 0.125f / (sqrtf(s) + 1e-6f);
      #pragma unroll
      for (int u = 0; u < 16; u++) qa[u] *= qs;
      *(uint4*)&QtU[tTh][kb] = pk8_(&qa[0]);
      *(uint4*)&QtU[tTh][kb + 8] = pk8_(&qa[8]);
    }
    {
      uint4 x[8];
      #pragma unroll
      for (int tap = 0; tap < 4; tap++) {
        int tr = t0 + tTh - 3 + tap;
        if (tr >= 0) {
          const uint4* p = (const uint4*)(qkv + (size_t)(b * T_ + tr) * 3072 + 1024 + c0);
          x[tap * 2] = p[0]; x[tap * 2 + 1] = p[1];
        } else { x[tap * 2] = z4; x[tap * 2 + 1] = z4; }
      }
      float ka[16], s = 0.f;
      #pragma unroll
      for (int u = 0; u < 16; u++) {
        float4 w = ((const float4*)kcw)[c0 + u];
        float a = kcb[c0 + u];
        #pragma unroll
        for (int tap = 0; tap < 4; tap++) a += XROW(x, tap, u) * TAPW(w, tap);
        a = siluf_(a);
        ka[u] = a; s += a * a;
      }
      s += __shfl_xor(s, 1, 64); s += __shfl_xor(s, 2, 64);
      float ks = frcp_(sqrtf(s) + 1e-6f);
      #pragma unroll
      for (int u = 0; u < 16; u++) ka[u] *= ks;
      *(uint4*)&KtU[tTh][kb] = pk8_(&ka[0]);
      *(uint4*)&KtU[tTh][kb + 8] = pk8_(&ka[8]);
    }
    {
      float Aexp = fexp_(A_log[h]);
      const ushort* gr = grawB + (size_t)(b * T_ + t0 + tTh) * 1024 + c0;
      uint4 ga = *(const uint4*)gr;
      uint4 gb = *(const uint4*)(gr + 8);
      float xv[16];
      ub8_(ga, &xv[0]); ub8_(gb, &xv[8]);
      #pragma unroll
      for (int u = 0; u < 16; u++) {
        float x = xv[u] + dtb[c0 + u];
        float sp = (x > 20.f) ? x : __logf(1.f + fexp_(x));
        cM[tTh][kb + u] = -Aexp * sp;
      }
      if (tid < 64)
        betaL[tid] = sigmoidf_(f1g1b[(size_t)(b * T_ + t0 + tid) * 256 + 128 + h]);
    }
  }
  __syncthreads();
  // ---- PH2: cumsum within quarters ----
  {
    const int q = wA, k = tA;
    float run = 0.f;
    #pragma unroll
    for (int u = 0; u < 16; u++) { run += cM[q * 16 + u][k]; cM[q * 16 + u][k] = run; }
    dlog[q][k] = run;
  }
  __syncthreads();
  // ---- PH3: segment offsets ----
  {
    const int q = wA, k = tA;
    if (q > 0) {
      float off = dlog[0][k];
      if (q > 1) off += dlog[1][k];
      if (q > 2) off += dlog[2][k];
      #pragma unroll
      for (int u = 0; u < 16; u++) cM[q * 16 + u][k] += off;
    }
  }
  __syncthreads();
  // ---- PH4: block-base log decays ----
  for (int idx = tid; idx < 17 * 64; idx += 256) {
    int P = idx >> 6, k = idx & 63;
    dlog[P][k] = (P == 0) ? 0.f : cM[4 * P - 1][k];
  }
  __syncthreads();
  // ---- PH5: K~/K^/Q~ ----
  {
    const int P5 = tTh >> 2;
    float knv[16], qnv[16];
    ub8_(*(const uint4*)&KtU[tTh][kb], &knv[0]);
    ub8_(*(const uint4*)&KtU[tTh][kb + 8], &knv[8]);
    ub8_(*(const uint4*)&QtU[tTh][kb], &qnv[0]);
    ub8_(*(const uint4*)&QtU[tTh][kb + 8], &qnv[8]);
    float ktv[16], khv[16], qtv[16];
    #pragma unroll
    for (int u = 0; u < 16; u++) {
      int k = kb + u;
      float c = cM[tTh][k], d = dlog[P5][k];
      float e1 = fexp_(c - d);
      float e2 = fexp_(d - c);
      ktv[u] = knv[u] * e1;
      khv[u] = knv[u] * e2;
      qtv[u] = qnv[u] * e1;
    }
    *(uint4*)&KtU[tTh][kb] = pk8_(&ktv[0]);
    *(uint4*)&KtU[tTh][kb + 8] = pk8_(&ktv[8]);
    *(uint4*)&KhU[tTh][kb] = pk8_(&khv[0]);
    *(uint4*)&KhU[tTh][kb + 8] = pk8_(&khv[8]);
    *(uint4*)&QtU[tTh][kb] = pk8_(&qtv[0]);
    *(uint4*)&QtU[tTh][kb + 8] = pk8_(&qtv[8]);
  }
  __syncthreads();
  // ---- PH6: Wq/WkB/bv/ge outputs + Mqk-upper zeroing + M-build ----
  {
    const int P = tTh >> 2;
    float bt = betaL[tTh];
    float qtv[16], ktv[16];
    ub8_(*(const uint4*)&QtU[tTh][kb], &qtv[0]);
    ub8_(*(const uint4*)&QtU[tTh][kb + 8], &qtv[8]);
    ub8_(*(const uint4*)&KtU[tTh][kb], &ktv[0]);
    ub8_(*(const uint4*)&KtU[tTh][kb + 8], &ktv[8]);
    float tq[16], tk[16];
    #pragma unroll
    for (int u = 0; u < 16; u++) {
      int k = kb + u;
      float e = fexp_(dlog[P][k]);
      tq[u] = qtv[u] * e;
      tk[u] = bt * ktv[u] * e;
    }
    ushort* pq = mWqBv + (size_t)i * 8192 + tTh * 64 + kb;
    ushort* pk = mWkB + (size_t)i * 4096 + tTh * 64 + kb;
    *(uint4*)&pq[0] = pk8_(&tq[0]);
    *(uint4*)&pq[8] = pk8_(&tq[8]);
    *(uint4*)&pk[0] = pk8_(&tk[0]);
    *(uint4*)&pk[8] = pk8_(&tk[8]);

    {
      const uint4 z4 = make_uint4(0, 0, 0, 0);
      uint4 x[8];
      #pragma unroll
      for (int tap = 0; tap < 4; tap++) {
        int tr = t0 + tTh - 3 + tap;
        if (tr >= 0) {
          const uint4* p = (const uint4*)(qkv + (size_t)(b * T_ + tr) * 3072 + 2048 + c0);
          x[tap * 2] = p[0]; x[tap * 2 + 1] = p[1];
        } else { x[tap * 2] = z4; x[tap * 2 + 1] = z4; }
      }
      float av[16];
      #pragma unroll
      for (int u = 0; u < 16; u++) {
        float4 w = ((const float4*)vcw)[c0 + u];
        float a = vcb[c0 + u];
        #pragma unroll
        for (int tap = 0; tap < 4; tap++) a += XROW(x, tap, u) * TAPW(w, tap);
        av[u] = bt * siluf_(a);
      }
      ushort* pb = mWqBv + (size_t)i * 8192 + 4096 + tTh * 64 + kb;
      *(uint4*)&pb[0] = pk8_(&av[0]);
      *(uint4*)&pb[8] = pk8_(&av[8]);
    }

    if (tid < 64) geG[(size_t)i * 64 + tid] = fexp_(dlog[16][tid]);

    for (int idx = tid; idx < 64 * 72; idx += 256) {
      int t = idx / 72, s = idx - t * 72;
      if (s >= 64 || (s >> 2) > (t >> 2)) MqkRM[t][s] = 0;
    }

    for (int tile = tid; tile < 272; tile += 256) {
      int mq = (tile >= 136) ? 1 : 0;
      int f = tile - mq * 136;
      int rem = f, P2 = 0;
      while (rem >= P2 + 1) { rem -= P2 + 1; ++P2; }
      int J = rem;
      const ushort (*Xr)[72] = mq ? QtU : KtU;
      float acc[4][4] = {};
      for (int kc = 0; kc < 16; kc++) {
        float av0[4], av1[4], av2[4], av3[4];
        ub4_(*(const uint2*)&Xr[4 * P2 + 0][kc * 4], av0);
        ub4_(*(const uint2*)&Xr[4 * P2 + 1][kc * 4], av1);
        ub4_(*(const uint2*)&Xr[4 * P2 + 2][kc * 4], av2);
        ub4_(*(const uint2*)&Xr[4 * P2 + 3][kc * 4], av3);
        float4 dp = *(const float4*)&dlog[P2][kc * 4];
        float4 dj = *(const float4*)&dlog[J][kc * 4];
        float rv[4] = {fexp_(dp.x - dj.x), fexp_(dp.y - dj.y),
                       fexp_(dp.z - dj.z), fexp_(dp.w - dj.w)};
        #pragma unroll
        for (int c = 0; c < 4; c++) {
          float kv[4];
          ub4_(*(const uint2*)&KhU[4 * J + c][kc * 4], kv);
          float bx = kv[0] * rv[0], by = kv[1] * rv[1], bz = kv[2] * rv[2], bw = kv[3] * rv[3];
          acc[0][c] += av0[0] * bx + av0[1] * by + av0[2] * bz + av0[3] * bw;
          acc[1][c] += av1[0] * bx + av1[1] * by + av1[2] * bz + av1[3] * bw;
          acc[2][c] += av2[0] * bx + av2[1] * by + av2[2] * bz + av2[3] * bw;
          acc[3][c] += av3[0] * bx + av3[1] * by + av3[2] * bz + av3[3] * bw;
        }
      }
      if (mq && P2 == J) {
        #pragma unroll
        for (int c = 0; c < 4; c++)
          #pragma unroll
          for (int r = 0; r < 4; r++)
            if (c > r) acc[r][c] = 0.f;
      }
      if (mq) {
        #pragma unroll
        for (int r = 0; r < 4; r++)
          *(uint2*)&MqkRM[4 * P2 + r][4 * J] =
              pk4_(acc[r][0], acc[r][1], acc[r][2], acc[r][3]);
      } else {
        #pragma unroll
        for (int c = 0; c < 4; c++) {
          uint2 w;
          w.x = (uint)f2bf(acc[0][c]) | ((uint)f2bf(acc[1][c]) << 16);
          w.y = (uint)f2bf(acc[2][c]) | ((uint)f2bf(acc[3][c]) << 16);
          *(uint2*)&MkkT[4 * J + c][4 * P2] = w;
        }
      }
    }
  }
  __syncthreads();
  // ---- PH7: KhET + G-solve -> Gt ----
  for (int idx = tid; idx < 4096; idx += 256) {
    int k = idx >> 6, s = idx & 63;
    KhET[k][s] = f2bf(bf2f(KhU[s][k]) * fexp_(dlog[16][k] - dlog[s >> 2][k]));
  }
  {
    const int j = tTh, q = c4;
    float acc[16], gsv[16];
    #pragma unroll
    for (int u = 0; u < 16; u++) { acc[u] = 0.f; gsv[u] = 0.f; }
    for (int s = 0; s < 64; s++) {
      int q0 = s >> 4;
      float g = 0.f;
      if (q == q0) {
        g = ((s == j) ? 1.f : 0.f) - betaL[s] * acc[s & 15];
        gsv[s & 15] = g;
      }
      g = __shfl(g, 4 * (j & 15) + q0, 64);
      #pragma unroll
      for (int u = 0; u < 4; u++) {
        uint2 m2 = *(const uint2*)&MkkT[s][q * 16 + u * 4];
        acc[u * 4 + 0] += bf2f((ushort)m2.x) * g;
        acc[u * 4 + 1] += bf2f((ushort)(m2.x >> 16)) * g;
        acc[u * 4 + 2] += bf2f((ushort)m2.y) * g;
        acc[u * 4 + 3] += bf2f((ushort)(m2.y >> 16)) * g;
      }
    }
    *(uint4*)&Gt[j][q * 16] = pk8_(&gsv[0]);
    *(uint4*)&Gt[j][q * 16 + 8] = pk8_(&gsv[8]);
  }
  __syncthreads();
  // ---- PH8 (MFMA): MG = tril(Mqk)@G, SG = KhET@G ----
  {
    const int wid = tid >> 6, lane = tid & 63;
    const int fr = lane & 15, fq = lane >> 4;
    const int wrow = wid * 16;
    bf16x8 aM[2], aS[2];
    #pragma unroll
    for (int kt = 0; kt < 2; kt++) {
      aM[kt] = *(const bf16x8*)&MqkRM[wrow + fr][kt * 32 + fq * 8];
      aS[kt] = *(const bf16x8*)&KhET[wrow + fr][kt * 32 + fq * 8];
    }
    #pragma unroll
    for (int jt = 0; jt < 4; jt++) {
      bf16x8 bG[2];
      #pragma unroll
      for (int kt = 0; kt < 2; kt++)
        bG[kt] = *(const bf16x8*)&Gt[jt * 16 + fr][kt * 32 + fq * 8];
      f32x4 accM = {}, accS = {};
      #pragma unroll
      for (int kt = 0; kt < 2; kt++) {
        accM = __builtin_amdgcn_mfma_f32_16x16x32_bf16(aM[kt], bG[kt], accM, 0, 0, 0);
        accS = __builtin_amdgcn_mfma_f32_16x16x32_bf16(aS[kt], bG[kt], accS, 0, 0, 0);
      }
      #pragma unroll
      for (int r = 0; r < 4; r++) {
        int row = wrow + fq * 4 + r, col = jt * 16 + fr;
        mMGSG[(size_t)i * 8192 + row * 64 + col] = f2bf(accM[r]);
        mMGSG[(size_t)i * 8192 + 4096 + row * 64 + col] = f2bf(accS[r]);
      }
    }
  }
}

// ---------------------------------------------------------------------------
// scan v2 (unchanged from R13): 512 threads, 2 v-cols/thread.
// ---------------------------------------------------------------------------
__global__ __launch_bounds__(512) void scan(
    const ushort* __restrict__ mMGSG, const ushort* __restrict__ mWkB,
    const ushort* __restrict__ mWqBv, const float* __restrict__ geG,
    ushort* __restrict__ oG) {
  const int bh = blockIdx.x, vq = blockIdx.y;
  const int tid = threadIdx.x;
  const int tTh = tid >> 3, c8 = tid & 7, lvi = c8 * 2;
  const int r0 = tid >> 3, cc = (tid & 7) * 8;

  __shared__ ushort MGs[64][72], SGs[64][72], WkBs[64][72], Wqs[64][72];
  __shared__ __align__(16) float Sl[64][20], rl[64][20];
  __shared__ float geL[64];

  Sl[tTh][lvi] = 0.f; Sl[tTh][lvi + 1] = 0.f;

  const size_t i0 = (size_t)bh * 32;
  {
    uint4 a0 = *(const uint4*)&mMGSG[i0 * 8192 + tid * 8];
    uint4 b0 = *(const uint4*)&mMGSG[i0 * 8192 + 4096 + tid * 8];
    uint4 c0 = *(const uint4*)&mWkB[i0 * 4096 + (tid & 511) * 8];
    uint4 d0 = *(const uint4*)&mWqBv[i0 * 8192 + tid * 8];
    *(uint4*)&MGs[r0][cc] = a0;
    *(uint4*)&SGs[r0][cc] = b0;
    *(uint4*)&WkBs[r0][cc] = c0;
    *(uint4*)&Wqs[r0][cc] = d0;
    if (tid < 64) geL[tid] = geG[i0 * 64 + tid];
  }
  uint bvCur = *(const uint*)&mWqBv[i0 * 8192 + 4096 + tTh * 64 + vq * 16 + lvi];
  __syncthreads();

  for (int ch = 0; ch < 32; ch++) {
    const size_t i = i0 + ch;
    uint4 p0, p1, p2, p3;
    uint pbv;
    float pge = 0.f;
    if (ch < 31) {
      const size_t i2 = i + 1;
      p0 = *(const uint4*)&mMGSG[i2 * 8192 + tid * 8];
      p1 = *(const uint4*)&mMGSG[i2 * 8192 + 4096 + tid * 8];
      p2 = *(const uint4*)&mWkB[i2 * 4096 + tid * 8];
      p3 = *(const uint4*)&mWqBv[i2 * 8192 + tid * 8];
      pbv = *(const uint*)&mWqBv[i2 * 8192 + 4096 + tTh * 64 + vq * 16 + lvi];
      if (tid < 64) pge = geG[i2 * 64 + tid];
    }
    float rv0, rv1;
    {
      float b2[2]; ub2_(bvCur, b2); rv0 = b2[0]; rv1 = b2[1];
    }
    #pragma unroll
    for (int kc = 0; kc < 16; kc++) {
      float w4[4];
      ub4_(*(const uint2*)&WkBs[tTh][kc * 4], w4);
      #pragma unroll
      for (int jj = 0; jj < 4; jj++) {
        float2 s2 = *(const float2*)&Sl[kc * 4 + jj][lvi];
        rv0 -= w4[jj] * s2.x; rv1 -= w4[jj] * s2.y;
      }
    }
    rl[tTh][lvi] = rv0; rl[tTh][lvi + 1] = rv1;
    __syncthreads();
    {
      float ov0 = 0.f, ov1 = 0.f;
      #pragma unroll
      for (int sc = 0; sc < 16; sc++) {
        float m4[4];
        ub4_(*(const uint2*)&MGs[tTh][sc * 4], m4);
        #pragma unroll
        for (int jj = 0; jj < 4; jj++) {
          float2 r2 = *(const float2*)&rl[sc * 4 + jj][lvi];
          ov0 += m4[jj] * r2.x; ov1 += m4[jj] * r2.y;
        }
      }
      #pragma unroll
      for (int kc = 0; kc < 16; kc++) {
        float q4[4];
        ub4_(*(const uint2*)&Wqs[tTh][kc * 4], q4);
        #pragma unroll
        for (int jj = 0; jj < 4; jj++) {
          float2 s2 = *(const float2*)&Sl[kc * 4 + jj][lvi];
          ov0 += q4[jj] * s2.x; ov1 += q4[jj] * s2.y;
        }
      }
      *(uint*)&oG[i * 4096 + tTh * 64 + vq * 16 + lvi] = pk2_(ov0, ov1);
    }
    __syncthreads();
    {
      float ge = geL[tTh];
      float sv0 = ge * Sl[tTh][lvi], sv1 = ge * Sl[tTh][lvi + 1];
      #pragma unroll
      for (int sc = 0; sc < 16; sc++) {
        float g4[4];
        ub4_(*(const uint2*)&SGs[tTh][sc * 4], g4);
        #pragma unroll
        for (int jj = 0; jj < 4; jj++) {
          float2 r2 = *(const float2*)&rl[sc * 4 + jj][lvi];
          sv0 += g4[jj] * r2.x; sv1 += g4[jj] * r2.y;
        }
      }
      Sl[tTh][lvi] = sv0; Sl[tTh][lvi + 1] = sv1;
    }
    __syncthreads();
    if (ch < 31) {
      *(uint4*)&MGs[r0][cc] = p0;
      *(uint4*)&SGs[r0][cc] = p1;
      *(uint4*)&WkBs[r0][cc] = p2;
      *(uint4*)&Wqs[r0][cc] = p3;
      if (tid < 64) geL[tid] = pge;
      bvCur = pbv;
      __syncthreads();
    }
  }
}

// ---------------------------------------------------------------------------
// RMS-norm + gate (bf16) -> single bf16 [M,1024] GEMM operand.
// ---------------------------------------------------------------------------
__global__ __launch_bounds__(256) void onorm_pack(
    const ushort* __restrict__ o, const ushort* __restrict__ gate,
    const float* __restrict__ onw, ushort* __restrict__ out1) {
  int gi = blockIdx.x * 4 + (threadIdx.x >> 6);
  int lane = threadIdx.x & 63;
  int b = gi >> 15, h = (gi >> 11) & 15, t = gi & 2047;
  float ov = bf2f(o[(size_t)gi * 64 + lane]);
  float ms = wave_sum64(ov * ov) * (1.f / 64.f);
  float r = rsqrtf(ms + 1e-5f);
  float gv = bf2f(gate[(size_t)(b * T_ + t) * 1024 + h * 64 + lane]);
  float val = ov * r * onw[lane] * sigmoidf_(gv);
  out1[(size_t)(b * T_ + t) * 1024 + h * 64 + lane] = f2bf(val);
}

extern "C" void kernel_launch(void* const* d_in, const int* in_sizes, int n_in,
                              void* d_out, int out_size, void* d_ws, size_t ws_size,
                              hipStream_t stream) {
  const float* hs    = (const float*)d_in[0];
  const float* Wq    = (const float*)d_in[1];
  const float* Wk    = (const float*)d_in[2];
  const float* Wv    = (const float*)d_in[3];
  const float* qcw   = (const float*)d_in[4];
  const float* qcb   = (const float*)d_in[5];
  const float* kcw   = (const float*)d_in[6];
  const float* kcb   = (const float*)d_in[7];
  const float* vcw   = (const float*)d_in[8];
  const float* vcb   = (const float*)d_in[9];
  const float* Wf1   = (const float*)d_in[10];
  const float* Wf2   = (const float*)d_in[11];
  const float* Wb    = (const float*)d_in[12];
  const float* A_log = (const float*)d_in[13];
  const float* dtb   = (const float*)d_in[14];
  const float* Wg1   = (const float*)d_in[15];
  const float* Wg2   = (const float*)d_in[16];
  const float* bg2   = (const float*)d_in[17];
  const float* onw   = (const float*)d_in[18];
  const float* Wo    = (const float*)d_in[19];
  float* out = (float*)d_out;

  char* ws = (char*)d_ws;
  // [0,32M): hs1 [0,16M) (dead after fgb GEMM) -> mMGSG -> obuf1 [0,16M)
  // [32,48M): mWkB
  // [48,96M): qkvhat (alive thru prep) -> gate bf16 [48,64M) ; oG [80,96M)
  // [96,112M): grawB (alive thru prep)
  // [112,144.5M): geG + mWqBv
  // [144.5M+): R4 pool
  ushort* hs1    = (ushort*)(ws);
  ushort* mMGSG  = (ushort*)(ws);
  ushort* obuf1  = (ushort*)(ws);
  ushort* mWkB   = (ushort*)(ws + 33554432);
  ushort* qkvhat = (ushort*)(ws + 50331648);
  ushort* gate   = qkvhat;
  ushort* oG     = (ushort*)(ws + 83886080);
  ushort* grawB  = (ushort*)(ws + 100663296);
  float*  geG    = (float*)(ws + 117440512);
  ushort* mWqBv  = (ushort*)(ws + 117964800);
  char*   R4     = ws + 151519232;
  ushort* Wqkv1  = (ushort*)R4;                      // [3072,1024] 6MB
  ushort* Wfgb1  = (ushort*)R4;                      // [256,1024] (after qkv GEMM)
  float*  f1g1b  = (float*)(R4 + 6291456);           // [8192,256] f32 8MB
  ushort* f1_1   = (ushort*)(R4 + 14680064);         // [8192,64] 1MB
  ushort* g1_1   = (ushort*)(R4 + 15728640);         // [8192,64] 1MB
  ushort* Wf2_1  = (ushort*)(R4 + 16777216);         // [1024,64] 128KB
  ushort* Wg2_1  = (ushort*)(R4 + 16908288);         // [1024,64] 128KB
  ushort* Wo1    = (ushort*)R4;                      // [1024,1024] 2MB (after gate GEMM)

  dim3 blk(256);
  const int PK = 1024 * 1024;

  pack_bf16<<<dim3((M_ * 1024) / 256), blk, 0, stream>>>(hs, 1024, 1024, M_, hs1);
  pack_wt<<<dim3(PK / 256), blk, 0, stream>>>(Wq, 1024, 1024, Wqkv1, 1024);
  pack_wt<<<dim3(PK / 256), blk, 0, stream>>>(Wk, 1024, 1024, Wqkv1 + (size_t)1024 * 1024, 1024);
  pack_wt<<<dim3(PK / 256), blk, 0, stream>>>(Wv, 1024, 1024, Wqkv1 + (size_t)2048 * 1024, 1024);
  gemm_glds<ushort><<<dim3(M_ / 128, 3072 / 128), blk, 0, stream>>>(
      hs1, Wqkv1, nullptr, qkvhat, M_, 3072, 1024);
  hipMemsetAsync(Wfgb1, 0, (size_t)256 * 1024 * 2, stream);
  pack_wt<<<dim3((1024 * 64) / 256), blk, 0, stream>>>(Wf1, 1024, 64, Wfgb1, 1024);
  pack_wt<<<dim3((1024 * 64) / 256), blk, 0, stream>>>(Wg1, 1024, 64, Wfgb1 + (size_t)64 * 1024, 1024);
  pack_wt<<<dim3((1024 * 16) / 256), blk, 0, stream>>>(Wb, 1024, 16, Wfgb1 + (size_t)128 * 1024, 1024);
  gemm_glds<float><<<dim3(M_ / 128, 2), blk, 0, stream>>>(
      hs1, Wfgb1, nullptr, f1g1b, M_, 256, 1024);
  pack_bf16<<<dim3((M_ * 64) / 256), blk, 0, stream>>>(f1g1b, 256, 64, M_, f1_1);
  pack_bf16<<<dim3((M_ * 64) / 256), blk, 0, stream>>>(f1g1b + 64, 256, 64, M_, g1_1);
  pack_wt<<<dim3((64 * 1024) / 256), blk, 0, stream>>>(Wf2, 64, 1024, Wf2_1, 64);
  gemm_glds<ushort><<<dim3(M_ / 128, 1024 / 128), blk, 0, stream>>>(
      f1_1, Wf2_1, nullptr, grawB, M_, 1024, 64);

  prep<<<dim3(64, 32), blk, 0, stream>>>(qkvhat, grawB, f1g1b,
                                         qcw, qcb, kcw, kcb, vcw, vcb,
                                         A_log, dtb, mMGSG, mWkB, mWqBv, geG);
  pack_wt<<<dim3((64 * 1024) / 256), blk, 0, stream>>>(Wg2, 64, 1024, Wg2_1, 64);
  gemm_glds<ushort><<<dim3(M_ / 128, 1024 / 128), blk, 0, stream>>>(
      g1_1, Wg2_1, bg2, gate, M_, 1024, 64);

  scan<<<dim3(64, 4), dim3(512), 0, stream>>>(mMGSG, mWkB, mWqBv, geG, oG);

  onorm_pack<<<dim3((M_ * H_) / 4), blk, 0, stream>>>(oG, gate, onw, obuf1);
  pack_wt<<<dim3(PK / 256), blk, 0, stream>>>(Wo, 1024, 1024, Wo1, 1024);
  gemm_glds<float><<<dim3(M_ / 128, 1024 / 128), blk, 0, stream>>>(
      obuf1, Wo1, nullptr, out, M_, 1024, 1024);
}